// Round 7
// baseline (519.819 us; speedup 1.0000x reference)
//
#include <hip/hip_runtime.h>
#include <hip/hip_bf16.h>

typedef __hip_bfloat16 bf16;
__device__ __forceinline__ float b2f(bf16 v){ return __bfloat162float(v); }
__device__ __forceinline__ bf16 f2b(float v){ return __float2bfloat16(v); }

#define LLEN 3136
#define BATCH 2
#define NCHUNK 49
#define LC 64

// ---------------- dwconv 3x3 + gelu ----------------
__global__ void k_dwconv_gelu(const float* __restrict__ x, const float* __restrict__ dww,
                              const float* __restrict__ dwb, bf16* __restrict__ tmp){
  int bc = blockIdx.x;            // b*128 + c
  int c = bc & 127;
  const float* xp = x + (size_t)bc*LLEN;
  float w[9];
  #pragma unroll
  for (int i=0;i<9;i++) w[i] = dww[c*9+i];
  float bias = dwb[c];
  for (int p = threadIdx.x; p < LLEN; p += blockDim.x){
    int i = p/56, j = p%56;
    float acc = bias;
    #pragma unroll
    for (int a=0;a<3;a++){
      int ii = i + a - 1;
      if (ii < 0 || ii >= 56) continue;
      #pragma unroll
      for (int bb=0;bb<3;bb++){
        int jj = j + bb - 1;
        if (jj < 0 || jj >= 56) continue;
        acc += w[a*3+bb] * xp[ii*56+jj];
      }
    }
    float g = 0.5f*acc*(1.0f + erff(acc*0.70710678118654752f));
    tmp[(size_t)bc*LLEN + p] = f2b(g);
  }
}

// ---------------- pointwise conv GEMM: 32x64 tiles, register-pipelined ----------------
__global__ void k_pw_gemm(const bf16* __restrict__ tmp, const float* __restrict__ pww,
                          const float* __restrict__ pwb, float* __restrict__ fused){
  int b = blockIdx.z;
  int p0 = blockIdx.x * 32;
  int n0 = blockIdx.y * 64;
  const bf16* A = tmp + (size_t)b*128*LLEN;
  __shared__ __align__(16) float As[16][36];
  __shared__ __align__(16) float Ws[16][68];
  int tid = threadIdx.x, tx = tid & 15, ty = tid >> 4;
  float acc[2][4] = {};
  float a_r[2], w_r[4];
  #pragma unroll
  for (int r=0;r<2;r++){ int idx = tid + r*256; a_r[r] = b2f(A[(size_t)(idx>>5)*LLEN + p0 + (idx&31)]); }
  #pragma unroll
  for (int r=0;r<4;r++){ int idx = tid + r*256; w_r[r] = pww[(n0 + (idx>>4))*128 + (idx&15)]; }
  for (int k0 = 0; k0 < 128; k0 += 16){
    __syncthreads();
    #pragma unroll
    for (int r=0;r<2;r++){ int idx = tid + r*256; As[idx>>5][idx&31] = a_r[r]; }
    #pragma unroll
    for (int r=0;r<4;r++){ int idx = tid + r*256; Ws[idx&15][idx>>4] = w_r[r]; }
    __syncthreads();
    if (k0 + 16 < 128){
      int kn = k0 + 16;
      #pragma unroll
      for (int r=0;r<2;r++){ int idx = tid + r*256; a_r[r] = b2f(A[(size_t)(kn + (idx>>5))*LLEN + p0 + (idx&31)]); }
      #pragma unroll
      for (int r=0;r<4;r++){ int idx = tid + r*256; w_r[r] = pww[(n0 + (idx>>4))*128 + kn + (idx&15)]; }
    }
    #pragma unroll
    for (int kk=0;kk<16;kk++){
      float2 av = *reinterpret_cast<const float2*>(&As[kk][ty*2]);
      float4 wv = *reinterpret_cast<const float4*>(&Ws[kk][tx*4]);
      float a2[2] = {av.x, av.y};
      float w4[4] = {wv.x, wv.y, wv.z, wv.w};
      #pragma unroll
      for (int i=0;i<2;i++)
        #pragma unroll
        for (int j=0;j<4;j++) acc[i][j] += a2[i]*w4[j];
    }
  }
  #pragma unroll
  for (int j=0;j<4;j++){
    int n = n0 + tx*4 + j;
    float bias = pwb[n];
    #pragma unroll
    for (int i=0;i<2;i++)
      fused[((size_t)b*128 + n)*LLEN + p0 + ty*2 + i] = acc[i][j] + bias;
  }
}

// ---------------- LayerNorm over C, write both direction orderings (bf16) ----------------
__global__ void k_ln(const float* __restrict__ x, const float* nhw_, const float* nhb_,
                     const float* nvw_, const float* nvb_, bf16* __restrict__ xln){
  __shared__ float sx[128][57];
  __shared__ float smean[56], srstd[56];
  __shared__ float wh[128], bh[128], wv_[128], bv_[128];
  int h = blockIdx.x; int b = blockIdx.y;
  int tid = threadIdx.x;
  if (tid < 128){ wh[tid]=nhw_[tid]; bh[tid]=nhb_[tid];
                  wv_[tid]=nvw_[tid]; bv_[tid]=nvb_[tid]; }
  for (int idx = tid; idx < 128*56; idx += 256){
    int c = idx / 56, w = idx % 56;
    sx[c][w] = x[((size_t)(b*128+c))*LLEN + h*56 + w];
  }
  __syncthreads();
  if (tid < 56){
    float s=0.f, s2=0.f;
    for (int c=0;c<128;c++){ float v = sx[c][tid]; s+=v; s2+=v*v; }
    float m = s*(1.f/128.f);
    float var = s2*(1.f/128.f) - m*m;
    smean[tid]=m; srstd[tid]=rsqrtf(var+1e-5f);
  }
  __syncthreads();
  bf16* outh = xln;
  bf16* outv = xln + (size_t)BATCH*LLEN*128;
  for (int idx = tid; idx < 56*128; idx += 256){
    int w = idx >> 7, c = idx & 127;
    float v = (sx[c][w]-smean[w])*srstd[w];
    outh[((size_t)b*LLEN + h*56 + w)*128 + c] = f2b(v*wh[c]+bh[c]);
    outv[((size_t)b*LLEN + w*56 + h)*128 + c] = f2b(v*wv_[c]+bv_[c]);
  }
}

// ---------------- in_proj GEMM ----------------
__global__ void k_inproj(const bf16* __restrict__ xln, const float* __restrict__ hw,
                         const float* __restrict__ vw, bf16* __restrict__ XI, bf16* __restrict__ Z){
  int dir = blockIdx.z;
  const bf16* A = xln + (size_t)dir*BATCH*LLEN*128;
  const float* W = dir ? vw : hw;
  int m0 = blockIdx.x*64, n0 = blockIdx.y*64;
  __shared__ __align__(16) float As[16][68];
  __shared__ __align__(16) float Ws[16][68];
  int tid = threadIdx.x, tx = tid&15, ty = tid>>4;
  float acc[4][4] = {};
  for (int k0=0;k0<128;k0+=16){
    #pragma unroll
    for (int r=0;r<4;r++){
      int idx = tid + r*256;
      int row = idx >> 4, k = idx & 15;
      As[k][row] = b2f(A[(size_t)(m0+row)*128 + k0 + k]);
      Ws[k][row] = W[(size_t)(n0+row)*128 + k0 + k];
    }
    __syncthreads();
    #pragma unroll
    for (int kk=0;kk<16;kk++){
      float4 av = *reinterpret_cast<const float4*>(&As[kk][ty*4]);
      float4 wv = *reinterpret_cast<const float4*>(&Ws[kk][tx*4]);
      float a4[4] = {av.x,av.y,av.z,av.w};
      float w4[4] = {wv.x,wv.y,wv.z,wv.w};
      #pragma unroll
      for (int i=0;i<4;i++)
        #pragma unroll
        for (int j=0;j<4;j++) acc[i][j] += a4[i]*w4[j];
    }
    __syncthreads();
  }
  bf16* dst = (n0 < 256) ? XI : Z;
  int nbase = n0 & 255;
  size_t dslab = (size_t)dir*BATCH*LLEN*256;
  #pragma unroll
  for (int i=0;i<4;i++)
    #pragma unroll
    for (int j=0;j<4;j++)
      dst[dslab + (size_t)(m0+ty*4+i)*256 + nbase + tx*4 + j] = f2b(acc[i][j]);
}

// ---------------- causal depthwise conv1d(k=4) + silu ----------------
__global__ void k_conv(const bf16* __restrict__ XI, const float* hw, const float* hb,
                       const float* vw, const float* vb, bf16* __restrict__ XS){
  int dir = blockIdx.z;
  int b = blockIdx.y;
  int l0 = blockIdx.x * 32;
  const bf16* XId = XI + ((size_t)dir*BATCH + b)*LLEN*256;
  bf16* XSd = XS + ((size_t)dir*BATCH + b)*LLEN*256;
  const float* cw = dir ? vw : hw;
  const float* cb = dir ? vb : hb;
  __shared__ float sxi[35][256];
  int tid = threadIdx.x;
  for (int r = 0; r < 35; r++){
    int l = l0 - 3 + r;
    sxi[r][tid] = (l >= 0) ? b2f(XId[(size_t)l*256 + tid]) : 0.f;
  }
  __syncthreads();
  float w0=cw[tid*4], w1=cw[tid*4+1], w2=cw[tid*4+2], w3=cw[tid*4+3];
  float bias = cb[tid];
  for (int ll=0; ll<32; ll++){
    float acc = bias + w0*sxi[ll][tid] + w1*sxi[ll+1][tid] + w2*sxi[ll+2][tid] + w3*sxi[ll+3][tid];
    float s = acc / (1.f + __expf(-acc));
    XSd[(size_t)(l0+ll)*256 + tid] = f2b(s);
  }
}

// ---------------- xproj stage 1: DBL[row][40] = XS[row][:] @ xw^T  (GEMM, M=12544,N=40,K=256) ----------------
__global__ void k_dbl(const bf16* __restrict__ XS, const float* __restrict__ hx,
                      const float* __restrict__ vx, float* __restrict__ DBL){
  int m0 = blockIdx.x*64;                      // 196 tiles; dir boundary at row 6272 = 98*64
  const float* W = (m0 >= 2*LLEN) ? vx : hx;
  __shared__ __align__(16) float As[16][68];
  __shared__ float Ws[16][42];
  int tid = threadIdx.x;
  int tx = tid & 7, ty = tid >> 3;             // tx: 8 groups of 5 cols, ty: 32 groups of 2 rows
  float acc[2][5] = {};
  for (int k0=0;k0<256;k0+=16){
    __syncthreads();
    #pragma unroll
    for (int r=0;r<4;r++){
      int idx = tid + r*256;
      int row = idx >> 4, k = idx & 15;
      As[k][row] = b2f(XS[(size_t)(m0+row)*256 + k0 + k]);
    }
    #pragma unroll
    for (int r=0;r<3;r++){
      int idx = tid + r*256;
      if (idx < 640){
        int o = idx >> 4, k = idx & 15;
        Ws[k][o] = W[o*256 + k0 + k];
      }
    }
    __syncthreads();
    #pragma unroll
    for (int kk=0;kk<16;kk++){
      float a0 = As[kk][ty*2], a1 = As[kk][ty*2+1];
      #pragma unroll
      for (int j=0;j<5;j++){
        float wv = Ws[kk][tx*5+j];
        acc[0][j] += a0*wv;
        acc[1][j] += a1*wv;
      }
    }
  }
  #pragma unroll
  for (int i=0;i<2;i++)
    #pragma unroll
    for (int j=0;j<5;j++)
      DBL[(size_t)(m0+ty*2+i)*40 + tx*5 + j] = acc[i][j];
}

// ---------------- xproj stage 2: dt = softplus(dbl[:8]@dtw^T + dtb); B,C extract ----------------
__global__ void k_dtbc(const float* __restrict__ DBL, const float* hdw, const float* vdw,
                       const float* hdb, const float* vdb,
                       bf16* __restrict__ DT, float* __restrict__ Bf, float* __restrict__ Cf){
  int r0 = blockIdx.x*32;                      // 392 blocks; dir boundary clean (6272/32=196)
  int dirq = (r0 >= 2*LLEN);
  const float* dtw = dirq ? vdw : hdw;
  const float* dtb = dirq ? vdb : hdb;
  __shared__ float sdbl[32][40];
  int tid = threadIdx.x;
  #pragma unroll
  for (int r=0;r<5;r++){
    int idx = tid + r*256;                     // 1280 = 32*40 exact
    sdbl[idx/40][idx%40] = DBL[(size_t)r0*40 + idx];
  }
  __syncthreads();
  float w8[8];
  #pragma unroll
  for (int r=0;r<8;r++) w8[r] = dtw[tid*8+r];
  float bias = dtb[tid];
  for (int row=0; row<32; row++){
    float a = bias;
    #pragma unroll
    for (int r=0;r<8;r++) a += sdbl[row][r]*w8[r];
    float sv = (a > 20.f) ? a : __logf(1.f + __expf(a));
    DT[(size_t)(r0+row)*256 + tid] = f2b(sv);
  }
  #pragma unroll
  for (int r=0;r<4;r++){
    int idx = tid + r*256;                     // 1024 = 32 rows * 32 vals
    int row = idx >> 5, o = idx & 31;
    float v = sdbl[row][8+o];                  // B at 8+o (o<16), C at 24+(o-16)=8+o
    if (o < 16) Bf[(size_t)(r0+row)*16 + o] = v;
    else        Cf[(size_t)(r0+row)*16 + (o-16)] = v;
  }
}

// ---------------- chunked selective scan: pass 1 (local scan, P & h_end) ----------------
__global__ void k_scan1(const bf16* __restrict__ dt, const bf16* __restrict__ xs,
                        const float* __restrict__ Bc, const float* hA, const float* vA,
                        float* __restrict__ Pbuf, float* __restrict__ Hbuf){
  int bd = blockIdx.z;           // dir*2+b
  int g  = blockIdx.y;           // channel group 0..15
  int ck = blockIdx.x;           // chunk 0..48
  int l0 = ck*LC;
  const bf16* dtd = dt + (size_t)bd*LLEN*256;
  const bf16* xsd = xs + (size_t)bd*LLEN*256;
  const float* Bd = Bc + (size_t)bd*LLEN*16;
  const float* Alog = (bd >> 1) ? vA : hA;
  int tid = threadIdx.x;
  int dl = tid >> 4, n = tid & 15;
  int d = g*16 + dl;
  float A = -__expf(Alog[d*16+n]);
  __shared__ float sdt[LC][16], sxs[LC][16], sB[LC][16];
  #pragma unroll
  for (int r=0;r<4;r++){
    int idx = tid + r*256;
    int i = idx >> 4, j = idx & 15;
    sdt[i][j] = b2f(dtd[(size_t)(l0+i)*256 + g*16 + j]);
    sxs[i][j] = b2f(xsd[(size_t)(l0+i)*256 + g*16 + j]);
    (&sB[0][0])[idx] = Bd[(size_t)l0*16 + idx];
  }
  __syncthreads();
  float h = 0.f, P = 1.f;
  #pragma unroll 8
  for (int i=0;i<LC;i++){
    float a = sdt[i][dl];
    float u = sxs[i][dl];
    float dA = __expf(a * A);
    h = dA*h + (a*u)*sB[i][n];
    P *= dA;
  }
  size_t sidx = (((size_t)bd*16 + g)*NCHUNK + ck)*256 + tid;
  Pbuf[sidx] = P;
  Hbuf[sidx] = h;
}

// ---------------- pass 2: sequential combine over chunks (in-place h_end -> h_init) ----------------
__global__ void k_scan2(const float* __restrict__ Pbuf, float* __restrict__ Hbuf){
  int q = blockIdx.x;            // bd*16+g, 0..63
  int tid = threadIdx.x;
  float carry = 0.f;
  for (int k=0;k<NCHUNK;k++){
    size_t idx = ((size_t)q*NCHUNK + k)*256 + tid;
    float Pv = Pbuf[idx];
    float He = Hbuf[idx];
    Hbuf[idx] = carry;           // h_init for chunk k
    carry = Pv*carry + He;
  }
}

// ---------------- pass 3: local scan from h_init, shfl-reduce over n, emit y ----------------
__global__ void k_scan3(const bf16* __restrict__ dt, const bf16* __restrict__ xs,
                        const float* __restrict__ Bc, const float* __restrict__ Cc,
                        const float* hA, const float* vA,
                        const float* __restrict__ Hbuf, bf16* __restrict__ ys){
  int bd = blockIdx.z;
  int g  = blockIdx.y;
  int ck = blockIdx.x;
  int l0 = ck*LC;
  const bf16* dtd = dt + (size_t)bd*LLEN*256;
  const bf16* xsd = xs + (size_t)bd*LLEN*256;
  const float* Bd = Bc + (size_t)bd*LLEN*16;
  const float* Cd = Cc + (size_t)bd*LLEN*16;
  bf16* yd = ys + (size_t)bd*LLEN*256;
  const float* Alog = (bd >> 1) ? vA : hA;
  int tid = threadIdx.x;
  int dl = tid >> 4, n = tid & 15;
  int d = g*16 + dl;
  float A = -__expf(Alog[d*16+n]);
  __shared__ float sdt[LC][16], sxs[LC][16], sB[LC][16], sC[LC][16];
  #pragma unroll
  for (int r=0;r<4;r++){
    int idx = tid + r*256;
    int i = idx >> 4, j = idx & 15;
    sdt[i][j] = b2f(dtd[(size_t)(l0+i)*256 + g*16 + j]);
    sxs[i][j] = b2f(xsd[(size_t)(l0+i)*256 + g*16 + j]);
    (&sB[0][0])[idx] = Bd[(size_t)l0*16 + idx];
    (&sC[0][0])[idx] = Cd[(size_t)l0*16 + idx];
  }
  size_t sidx = (((size_t)bd*16 + g)*NCHUNK + ck)*256 + tid;
  float h = Hbuf[sidx];
  __syncthreads();
  float pr[LC];
  #pragma unroll
  for (int i=0;i<LC;i++){
    float a = sdt[i][dl];
    float u = sxs[i][dl];
    float dA = __expf(a * A);
    h = dA*h + (a*u)*sB[i][n];
    pr[i] = h * sC[i][n];
  }
  #pragma unroll
  for (int i=0;i<LC;i++){
    float p = pr[i];
    p += __shfl_xor(p, 1, 16);
    p += __shfl_xor(p, 2, 16);
    p += __shfl_xor(p, 4, 16);
    p += __shfl_xor(p, 8, 16);
    if (n == (i & 15)) yd[(size_t)(l0+i)*256 + d] = f2b(p);
  }
}

// ---------------- YF = (ys + xs*D) * silu(z), bf16 ----------------
__global__ void k_yf(const bf16* __restrict__ ys, const bf16* __restrict__ xs,
                     const bf16* __restrict__ Z, const float* __restrict__ hD,
                     const float* __restrict__ vD, bf16* __restrict__ YF){
  size_t e = (size_t)blockIdx.x*256 + threadIdx.x;   // < 4*LLEN*256
  int d = (int)(e & 255);
  int dir = (e >= (size_t)2*LLEN*256) ? 1 : 0;
  float Dv = dir ? vD[d] : hD[d];
  float yv = b2f(ys[e]) + b2f(xs[e])*Dv;
  float zv = b2f(Z[e]);
  YF[e] = f2b(yv * (zv/(1.f+__expf(-zv))));
}

// ---------------- out_proj GEMM: 32x64 tiles, register-pipelined, coalesced OD stores ----------------
__global__ void k_outgemm(const bf16* __restrict__ YF, const float* __restrict__ how,
                          const float* __restrict__ vow, bf16* __restrict__ OD){
  int dir = blockIdx.z;
  const bf16* A = YF + (size_t)dir*BATCH*LLEN*256;
  const float* W = dir ? vow : how;
  bf16* od = OD + (size_t)dir*BATCH*LLEN*128;
  int m0 = blockIdx.x*32, n0 = blockIdx.y*64;
  __shared__ __align__(16) float As[16][36];
  __shared__ __align__(16) float Ws[16][68];
  int tid = threadIdx.x, tx = tid&15, ty = tid>>4;
  float acc[2][4] = {};
  float a_r[2], w_r[4];
  #pragma unroll
  for (int r=0;r<2;r++){ int idx = tid + r*256; a_r[r] = b2f(A[(size_t)(m0 + (idx>>4))*256 + (idx&15)]); }
  #pragma unroll
  for (int r=0;r<4;r++){ int idx = tid + r*256; w_r[r] = W[(size_t)(n0 + (idx>>4))*256 + (idx&15)]; }
  for (int k0=0;k0<256;k0+=16){
    __syncthreads();
    #pragma unroll
    for (int r=0;r<2;r++){ int idx = tid + r*256; As[idx&15][idx>>4] = a_r[r]; }
    #pragma unroll
    for (int r=0;r<4;r++){ int idx = tid + r*256; Ws[idx&15][idx>>4] = w_r[r]; }
    __syncthreads();
    if (k0 + 16 < 256){
      int kn = k0 + 16;
      #pragma unroll
      for (int r=0;r<2;r++){ int idx = tid + r*256; a_r[r] = b2f(A[(size_t)(m0 + (idx>>4))*256 + kn + (idx&15)]); }
      #pragma unroll
      for (int r=0;r<4;r++){ int idx = tid + r*256; w_r[r] = W[(size_t)(n0 + (idx>>4))*256 + kn + (idx&15)]; }
    }
    #pragma unroll
    for (int kk=0;kk<16;kk++){
      float2 av = *reinterpret_cast<const float2*>(&As[kk][ty*2]);
      float4 wv = *reinterpret_cast<const float4*>(&Ws[kk][tx*4]);
      float a2[2] = {av.x, av.y};
      float w4[4] = {wv.x, wv.y, wv.z, wv.w};
      #pragma unroll
      for (int i=0;i<2;i++)
        #pragma unroll
        for (int j=0;j<4;j++) acc[i][j] += a2[i]*w4[j];
    }
  }
  #pragma unroll
  for (int i=0;i<2;i++){
    int m = m0 + ty*2 + i;
    #pragma unroll
    for (int j=0;j<4;j++)
      od[(size_t)m*128 + n0 + tx*4 + j] = f2b(acc[i][j]);
  }
}

// ---------------- combine: fused += OH + OV^T  (per h-row LDS tile) ----------------
__global__ void k_combine(const bf16* __restrict__ OD, float* __restrict__ fused){
  int h = blockIdx.x;            // 0..55
  int b = blockIdx.y;
  __shared__ float sfu[56][129];
  int tid = threadIdx.x;
  const bf16* od0 = OD + (size_t)b*LLEN*128;
  const bf16* od1 = OD + (size_t)(BATCH + b)*LLEN*128;
  #pragma unroll 4
  for (int it=0; it<28; it++){
    int idx = it*256 + tid;      // 0..7167
    int sp = idx >> 7, c = idx & 127;
    float v = b2f(od0[(size_t)(h*56+sp)*128 + c]) + b2f(od1[(size_t)(sp*56+h)*128 + c]);
    sfu[sp][c] = v;
  }
  __syncthreads();
  #pragma unroll 4
  for (int it=0; it<28; it++){
    int lin = it*256 + tid;      // 0..7167 = 128c * 56sp
    int c = lin / 56, sp = lin % 56;
    size_t gi = ((size_t)b*128 + c)*LLEN + h*56 + sp;
    fused[gi] += sfu[sp][c];
  }
}

// ---------------- mean over spatial ----------------
__global__ void k_mean(const float* __restrict__ fused, float* __restrict__ ymean){
  int bc = blockIdx.x;
  const float* f = fused + (size_t)bc*LLEN;
  float s = 0.f;
  for (int i = threadIdx.x; i < LLEN; i += 256) s += f[i];
  __shared__ float red[256];
  red[threadIdx.x] = s; __syncthreads();
  for (int off=128; off>0; off>>=1){
    if (threadIdx.x < off) red[threadIdx.x] += red[threadIdx.x+off];
    __syncthreads();
  }
  if (threadIdx.x==0) ymean[bc] = red[0]*(1.f/(float)LLEN);
}

// ---------------- channel attention gate ----------------
__global__ void k_gate(const float* __restrict__ ymean, const float* fc1, const float* fc2,
                       float* __restrict__ gate){
  int b = blockIdx.x;
  __shared__ float ym[128], s1[32];
  int tid = threadIdx.x;
  ym[tid] = ymean[b*128+tid];
  __syncthreads();
  if (tid < 32){
    float a = 0.f;
    for (int c=0;c<128;c++) a += ym[c]*fc1[tid*128+c];
    s1[tid] = fmaxf(a, 0.f);
  }
  __syncthreads();
  float a = 0.f;
  #pragma unroll
  for (int j=0;j<32;j++) a += s1[j]*fc2[tid*32+j];
  gate[b*128+tid] = 1.f/(1.f+__expf(-a));
}

// ---------------- final: out = fused * gate + x  (in-place over fused) ----------------
__global__ void k_final(float* __restrict__ fused, const float* __restrict__ gate,
                        const float* __restrict__ x, float* __restrict__ out){
  int i = blockIdx.x*256 + threadIdx.x;
  if (i >= BATCH*128*LLEN) return;
  int bc = i / LLEN;
  float v = fused[i]*gate[bc] + x[i];
  out[i] = v;
}

extern "C" void kernel_launch(void* const* d_in, const int* in_sizes, int n_in,
                              void* d_out, int out_size, void* d_ws, size_t ws_size,
                              hipStream_t stream) {
  const float* x      = (const float*)d_in[0];
  const float* nhw    = (const float*)d_in[1];
  const float* nhb    = (const float*)d_in[2];
  const float* nvw    = (const float*)d_in[3];
  const float* nvb    = (const float*)d_in[4];
  const float* dww    = (const float*)d_in[5];
  const float* dwb    = (const float*)d_in[6];
  const float* pww    = (const float*)d_in[7];
  const float* pwb    = (const float*)d_in[8];
  const float* h_inw  = (const float*)d_in[9];
  const float* h_cw   = (const float*)d_in[10];
  const float* h_cb   = (const float*)d_in[11];
  const float* h_xw   = (const float*)d_in[12];
  const float* h_dtw  = (const float*)d_in[13];
  const float* h_dtb  = (const float*)d_in[14];
  const float* h_Al   = (const float*)d_in[15];
  const float* h_D    = (const float*)d_in[16];
  const float* h_ow   = (const float*)d_in[17];
  const float* v_inw  = (const float*)d_in[18];
  const float* v_cw   = (const float*)d_in[19];
  const float* v_cb   = (const float*)d_in[20];
  const float* v_xw   = (const float*)d_in[21];
  const float* v_dtw  = (const float*)d_in[22];
  const float* v_dtb  = (const float*)d_in[23];
  const float* v_Al   = (const float*)d_in[24];
  const float* v_D    = (const float*)d_in[25];
  const float* v_ow   = (const float*)d_in[26];
  const float* fc1    = (const float*)d_in[27];
  const float* fc2    = (const float*)d_in[28];

  float* FUSED = (float*)d_out;   // FUSED lives in d_out; k_final is in-place elementwise
  float* out   = (float*)d_out;

  // Workspace layout (bytes), high-water ~30.5 MB. Stream-ordered-safe aliases:
  //  DT overlays TMP+XLN (dead after k_inproj);  YF overlays DT (dead after k_scan3)
  //  YS overlays XI (dead after k_conv);  Pbuf overlays YS head (dead before k_scan3 writes)
  //  OD overlays YS region (YS dead after k_yf)
  //  DBL overlays Hbuf region (DBL dead after k_dtbc, before k_scan1 writes Hbuf)
  char* base = (char*)d_ws;
  bf16*  TMP   = (bf16*)(base + 0);           // 1,605,632 B
  bf16*  XLN   = (bf16*)(base + 1605632);     // 3,211,264 B
  bf16*  DT    = (bf16*)(base + 0);           // 6,422,528 B  [alias TMP+XLN]
  bf16*  YF    = (bf16*)(base + 0);           // 6,422,528 B  [alias DT]
  bf16*  XI    = (bf16*)(base + 6422528);     // 6,422,528 B
  bf16*  YS    = (bf16*)(base + 6422528);     // 6,422,528 B  [alias XI]
  float* Pbuf  = (float*)(base + 6422528);    // 3,211,264 B  [alias XI/YS head]
  bf16*  OD    = (bf16*)(base + 6422528);     // 3,211,264 B  [alias YS; live after k_yf]
  bf16*  Z     = (bf16*)(base + 12845056);    // 6,422,528 B
  bf16*  XS    = (bf16*)(base + 19267584);    // 6,422,528 B
  float* Bf    = (float*)(base + 25690112);   //   802,816 B
  float* Cf    = (float*)(base + 26492928);   //   802,816 B
  float* Hbuf  = (float*)(base + 27295744);   // 3,211,264 B
  float* DBL   = (float*)(base + 27295744);   // 2,007,040 B  [alias Hbuf head]
  float* YMEAN = (float*)(base + 30507008);   //     1,024 B
  float* GATE  = (float*)(base + 30508032);   //     1,024 B

  k_dwconv_gelu<<<dim3(BATCH*128), dim3(256), 0, stream>>>(x, dww, dwb, TMP);
  k_pw_gemm<<<dim3(98,2,BATCH), dim3(256), 0, stream>>>(TMP, pww, pwb, FUSED);
  k_ln<<<dim3(56,BATCH), dim3(256), 0, stream>>>(x, nhw, nhb, nvw, nvb, XLN);
  k_inproj<<<dim3(98,8,2), dim3(256), 0, stream>>>(XLN, h_inw, v_inw, XI, Z);
  k_conv<<<dim3(98,BATCH,2), dim3(256), 0, stream>>>(XI, h_cw, h_cb, v_cw, v_cb, XS);
  k_dbl<<<dim3(196), dim3(256), 0, stream>>>(XS, h_xw, v_xw, DBL);
  k_dtbc<<<dim3(392), dim3(256), 0, stream>>>(DBL, h_dtw, v_dtw, h_dtb, v_dtb, DT, Bf, Cf);
  k_scan1<<<dim3(NCHUNK,16,4), dim3(256), 0, stream>>>(DT, XS, Bf, h_Al, v_Al, Pbuf, Hbuf);
  k_scan2<<<dim3(64), dim3(256), 0, stream>>>(Pbuf, Hbuf);
  k_scan3<<<dim3(NCHUNK,16,4), dim3(256), 0, stream>>>(DT, XS, Bf, Cf, h_Al, v_Al, Hbuf, YS);
  k_yf<<<dim3(4*LLEN), dim3(256), 0, stream>>>(YS, XS, Z, h_D, v_D, YF);
  k_outgemm<<<dim3(196,2,2), dim3(256), 0, stream>>>(YF, h_ow, v_ow, OD);
  k_combine<<<dim3(56,BATCH), dim3(256), 0, stream>>>(OD, FUSED);
  k_mean<<<dim3(BATCH*128), dim3(256), 0, stream>>>(FUSED, YMEAN);
  k_gate<<<dim3(BATCH), dim3(128), 0, stream>>>(YMEAN, fc1, fc2, GATE);
  k_final<<<dim3((BATCH*128*LLEN+255)/256), dim3(256), 0, stream>>>(FUSED, GATE, x, out);
}

// Round 8
// 366.073 us; speedup vs baseline: 1.4200x; 1.4200x over previous
//
#include <hip/hip_runtime.h>
#include <hip/hip_bf16.h>

typedef __hip_bfloat16 bf16;
__device__ __forceinline__ float b2f(bf16 v){ return __bfloat162float(v); }
__device__ __forceinline__ bf16 f2b(float v){ return __float2bfloat16(v); }

#define LLEN 3136
#define BATCH 2
#define NCHUNK 49
#define LC 64

// ---------------- dwconv 3x3 + gelu ----------------
__global__ void k_dwconv_gelu(const float* __restrict__ x, const float* __restrict__ dww,
                              const float* __restrict__ dwb, bf16* __restrict__ tmp){
  int bc = blockIdx.x;            // b*128 + c
  int c = bc & 127;
  const float* xp = x + (size_t)bc*LLEN;
  float w[9];
  #pragma unroll
  for (int i=0;i<9;i++) w[i] = dww[c*9+i];
  float bias = dwb[c];
  for (int p = threadIdx.x; p < LLEN; p += blockDim.x){
    int i = p/56, j = p%56;
    float acc = bias;
    #pragma unroll
    for (int a=0;a<3;a++){
      int ii = i + a - 1;
      if (ii < 0 || ii >= 56) continue;
      #pragma unroll
      for (int bb=0;bb<3;bb++){
        int jj = j + bb - 1;
        if (jj < 0 || jj >= 56) continue;
        acc += w[a*3+bb] * xp[ii*56+jj];
      }
    }
    float g = 0.5f*acc*(1.0f + erff(acc*0.70710678118654752f));
    tmp[(size_t)bc*LLEN + p] = f2b(g);
  }
}

// ---------------- pointwise conv GEMM: 32x64 tiles, register-pipelined ----------------
__global__ void k_pw_gemm(const bf16* __restrict__ tmp, const float* __restrict__ pww,
                          const float* __restrict__ pwb, float* __restrict__ fused){
  int b = blockIdx.z;
  int p0 = blockIdx.x * 32;
  int n0 = blockIdx.y * 64;
  const bf16* A = tmp + (size_t)b*128*LLEN;
  __shared__ __align__(16) float As[16][36];
  __shared__ __align__(16) float Ws[16][68];
  int tid = threadIdx.x, tx = tid & 15, ty = tid >> 4;
  float acc[2][4] = {};
  float a_r[2], w_r[4];
  #pragma unroll
  for (int r=0;r<2;r++){ int idx = tid + r*256; a_r[r] = b2f(A[(size_t)(idx>>5)*LLEN + p0 + (idx&31)]); }
  #pragma unroll
  for (int r=0;r<4;r++){ int idx = tid + r*256; w_r[r] = pww[(n0 + (idx>>4))*128 + (idx&15)]; }
  for (int k0 = 0; k0 < 128; k0 += 16){
    __syncthreads();
    #pragma unroll
    for (int r=0;r<2;r++){ int idx = tid + r*256; As[idx>>5][idx&31] = a_r[r]; }
    #pragma unroll
    for (int r=0;r<4;r++){ int idx = tid + r*256; Ws[idx&15][idx>>4] = w_r[r]; }
    __syncthreads();
    if (k0 + 16 < 128){
      int kn = k0 + 16;
      #pragma unroll
      for (int r=0;r<2;r++){ int idx = tid + r*256; a_r[r] = b2f(A[(size_t)(kn + (idx>>5))*LLEN + p0 + (idx&31)]); }
      #pragma unroll
      for (int r=0;r<4;r++){ int idx = tid + r*256; w_r[r] = pww[(n0 + (idx>>4))*128 + kn + (idx&15)]; }
    }
    #pragma unroll
    for (int kk=0;kk<16;kk++){
      float2 av = *reinterpret_cast<const float2*>(&As[kk][ty*2]);
      float4 wv = *reinterpret_cast<const float4*>(&Ws[kk][tx*4]);
      float a2[2] = {av.x, av.y};
      float w4[4] = {wv.x, wv.y, wv.z, wv.w};
      #pragma unroll
      for (int i=0;i<2;i++)
        #pragma unroll
        for (int j=0;j<4;j++) acc[i][j] += a2[i]*w4[j];
    }
  }
  #pragma unroll
  for (int j=0;j<4;j++){
    int n = n0 + tx*4 + j;
    float bias = pwb[n];
    #pragma unroll
    for (int i=0;i<2;i++)
      fused[((size_t)b*128 + n)*LLEN + p0 + ty*2 + i] = acc[i][j] + bias;
  }
}

// ---------------- LayerNorm over C, write both direction orderings (bf16) ----------------
__global__ void k_ln(const float* __restrict__ x, const float* nhw_, const float* nhb_,
                     const float* nvw_, const float* nvb_, bf16* __restrict__ xln){
  __shared__ float sx[128][57];
  __shared__ float smean[56], srstd[56];
  __shared__ float wh[128], bh[128], wv_[128], bv_[128];
  int h = blockIdx.x; int b = blockIdx.y;
  int tid = threadIdx.x;
  if (tid < 128){ wh[tid]=nhw_[tid]; bh[tid]=nhb_[tid];
                  wv_[tid]=nvw_[tid]; bv_[tid]=nvb_[tid]; }
  for (int idx = tid; idx < 128*56; idx += 256){
    int c = idx / 56, w = idx % 56;
    sx[c][w] = x[((size_t)(b*128+c))*LLEN + h*56 + w];
  }
  __syncthreads();
  if (tid < 56){
    float s=0.f, s2=0.f;
    for (int c=0;c<128;c++){ float v = sx[c][tid]; s+=v; s2+=v*v; }
    float m = s*(1.f/128.f);
    float var = s2*(1.f/128.f) - m*m;
    smean[tid]=m; srstd[tid]=rsqrtf(var+1e-5f);
  }
  __syncthreads();
  bf16* outh = xln;
  bf16* outv = xln + (size_t)BATCH*LLEN*128;
  for (int idx = tid; idx < 56*128; idx += 256){
    int w = idx >> 7, c = idx & 127;
    float v = (sx[c][w]-smean[w])*srstd[w];
    outh[((size_t)b*LLEN + h*56 + w)*128 + c] = f2b(v*wh[c]+bh[c]);
    outv[((size_t)b*LLEN + w*56 + h)*128 + c] = f2b(v*wv_[c]+bv_[c]);
  }
}

// ---------------- in_proj GEMM ----------------
__global__ void k_inproj(const bf16* __restrict__ xln, const float* __restrict__ hw,
                         const float* __restrict__ vw, bf16* __restrict__ XI, bf16* __restrict__ Z){
  int dir = blockIdx.z;
  const bf16* A = xln + (size_t)dir*BATCH*LLEN*128;
  const float* W = dir ? vw : hw;
  int m0 = blockIdx.x*64, n0 = blockIdx.y*64;
  __shared__ __align__(16) float As[16][68];
  __shared__ __align__(16) float Ws[16][68];
  int tid = threadIdx.x, tx = tid&15, ty = tid>>4;
  float acc[4][4] = {};
  for (int k0=0;k0<128;k0+=16){
    #pragma unroll
    for (int r=0;r<4;r++){
      int idx = tid + r*256;
      int row = idx >> 4, k = idx & 15;
      As[k][row] = b2f(A[(size_t)(m0+row)*128 + k0 + k]);
      Ws[k][row] = W[(size_t)(n0+row)*128 + k0 + k];
    }
    __syncthreads();
    #pragma unroll
    for (int kk=0;kk<16;kk++){
      float4 av = *reinterpret_cast<const float4*>(&As[kk][ty*4]);
      float4 wv = *reinterpret_cast<const float4*>(&Ws[kk][tx*4]);
      float a4[4] = {av.x,av.y,av.z,av.w};
      float w4[4] = {wv.x,wv.y,wv.z,wv.w};
      #pragma unroll
      for (int i=0;i<4;i++)
        #pragma unroll
        for (int j=0;j<4;j++) acc[i][j] += a4[i]*w4[j];
    }
    __syncthreads();
  }
  bf16* dst = (n0 < 256) ? XI : Z;
  int nbase = n0 & 255;
  size_t dslab = (size_t)dir*BATCH*LLEN*256;
  #pragma unroll
  for (int i=0;i<4;i++)
    #pragma unroll
    for (int j=0;j<4;j++)
      dst[dslab + (size_t)(m0+ty*4+i)*256 + nbase + tx*4 + j] = f2b(acc[i][j]);
}

// ---------------- causal depthwise conv1d(k=4) + silu ----------------
__global__ void k_conv(const bf16* __restrict__ XI, const float* hw, const float* hb,
                       const float* vw, const float* vb, bf16* __restrict__ XS){
  int dir = blockIdx.z;
  int b = blockIdx.y;
  int l0 = blockIdx.x * 32;
  const bf16* XId = XI + ((size_t)dir*BATCH + b)*LLEN*256;
  bf16* XSd = XS + ((size_t)dir*BATCH + b)*LLEN*256;
  const float* cw = dir ? vw : hw;
  const float* cb = dir ? vb : hb;
  __shared__ float sxi[35][256];
  int tid = threadIdx.x;
  for (int r = 0; r < 35; r++){
    int l = l0 - 3 + r;
    sxi[r][tid] = (l >= 0) ? b2f(XId[(size_t)l*256 + tid]) : 0.f;
  }
  __syncthreads();
  float w0=cw[tid*4], w1=cw[tid*4+1], w2=cw[tid*4+2], w3=cw[tid*4+3];
  float bias = cb[tid];
  for (int ll=0; ll<32; ll++){
    float acc = bias + w0*sxi[ll][tid] + w1*sxi[ll+1][tid] + w2*sxi[ll+2][tid] + w3*sxi[ll+3][tid];
    float s = acc / (1.f + __expf(-acc));
    XSd[(size_t)(l0+ll)*256 + tid] = f2b(s);
  }
}

// ---------------- xproj stage 1: DBL[row][40] = XS[row][:] @ xw^T ----------------
__global__ void k_dbl(const bf16* __restrict__ XS, const float* __restrict__ hx,
                      const float* __restrict__ vx, float* __restrict__ DBL){
  int m0 = blockIdx.x*64;                      // 196 tiles; dir boundary at row 6272 = 98*64
  const float* W = (m0 >= 2*LLEN) ? vx : hx;
  __shared__ __align__(16) float As[16][68];
  __shared__ float Ws[16][42];
  int tid = threadIdx.x;
  int tx = tid & 7, ty = tid >> 3;             // tx: 8 groups of 5 cols, ty: 32 groups of 2 rows
  float acc[2][5] = {};
  for (int k0=0;k0<256;k0+=16){
    __syncthreads();
    #pragma unroll
    for (int r=0;r<4;r++){
      int idx = tid + r*256;
      int row = idx >> 4, k = idx & 15;
      As[k][row] = b2f(XS[(size_t)(m0+row)*256 + k0 + k]);
    }
    #pragma unroll
    for (int r=0;r<3;r++){
      int idx = tid + r*256;
      if (idx < 640){
        int o = idx >> 4, k = idx & 15;
        Ws[k][o] = W[o*256 + k0 + k];
      }
    }
    __syncthreads();
    #pragma unroll
    for (int kk=0;kk<16;kk++){
      float a0 = As[kk][ty*2], a1 = As[kk][ty*2+1];
      #pragma unroll
      for (int j=0;j<5;j++){
        float wv = Ws[kk][tx*5+j];
        acc[0][j] += a0*wv;
        acc[1][j] += a1*wv;
      }
    }
  }
  #pragma unroll
  for (int i=0;i<2;i++)
    #pragma unroll
    for (int j=0;j<5;j++)
      DBL[(size_t)(m0+ty*2+i)*40 + tx*5 + j] = acc[i][j];
}

// ---------------- xproj stage 2: dt = softplus(dbl[:8]@dtw^T + dtb); B,C extract ----------------
__global__ void k_dtbc(const float* __restrict__ DBL, const float* hdw, const float* vdw,
                       const float* hdb, const float* vdb,
                       bf16* __restrict__ DT, float* __restrict__ Bf, float* __restrict__ Cf){
  int r0 = blockIdx.x*32;                      // 392 blocks; dir boundary clean (6272/32=196)
  int dirq = (r0 >= 2*LLEN);
  const float* dtw = dirq ? vdw : hdw;
  const float* dtb = dirq ? vdb : hdb;
  __shared__ float sdbl[32][40];
  int tid = threadIdx.x;
  #pragma unroll
  for (int r=0;r<5;r++){
    int idx = tid + r*256;                     // 1280 = 32*40 exact
    sdbl[idx/40][idx%40] = DBL[(size_t)r0*40 + idx];
  }
  __syncthreads();
  float w8[8];
  #pragma unroll
  for (int r=0;r<8;r++) w8[r] = dtw[tid*8+r];
  float bias = dtb[tid];
  for (int row=0; row<32; row++){
    float a = bias;
    #pragma unroll
    for (int r=0;r<8;r++) a += sdbl[row][r]*w8[r];
    float sv = (a > 20.f) ? a : __logf(1.f + __expf(a));
    DT[(size_t)(r0+row)*256 + tid] = f2b(sv);
  }
  #pragma unroll
  for (int r=0;r<4;r++){
    int idx = tid + r*256;                     // 1024 = 32 rows * 32 vals
    int row = idx >> 5, o = idx & 31;
    float v = sdbl[row][8+o];
    if (o < 16) Bf[(size_t)(r0+row)*16 + o] = v;
    else        Cf[(size_t)(r0+row)*16 + (o-16)] = v;
  }
}

// ---------------- chunked selective scan: pass 1 (local scan, P & h_end) ----------------
__global__ void k_scan1(const bf16* __restrict__ dt, const bf16* __restrict__ xs,
                        const float* __restrict__ Bc, const float* hA, const float* vA,
                        float* __restrict__ Pbuf, float* __restrict__ Hbuf){
  int bd = blockIdx.z;           // dir*2+b
  int g  = blockIdx.y;           // channel group 0..15
  int ck = blockIdx.x;           // chunk 0..48
  int l0 = ck*LC;
  const bf16* dtd = dt + (size_t)bd*LLEN*256;
  const bf16* xsd = xs + (size_t)bd*LLEN*256;
  const float* Bd = Bc + (size_t)bd*LLEN*16;
  const float* Alog = (bd >> 1) ? vA : hA;
  int tid = threadIdx.x;
  int dl = tid >> 4, n = tid & 15;
  int d = g*16 + dl;
  float A = -__expf(Alog[d*16+n]);
  __shared__ float sdt[LC][16], sxs[LC][16], sB[LC][16];
  #pragma unroll
  for (int r=0;r<4;r++){
    int idx = tid + r*256;
    int i = idx >> 4, j = idx & 15;
    sdt[i][j] = b2f(dtd[(size_t)(l0+i)*256 + g*16 + j]);
    sxs[i][j] = b2f(xsd[(size_t)(l0+i)*256 + g*16 + j]);
    (&sB[0][0])[idx] = Bd[(size_t)l0*16 + idx];
  }
  __syncthreads();
  float h = 0.f, P = 1.f;
  #pragma unroll 8
  for (int i=0;i<LC;i++){
    float a = sdt[i][dl];
    float u = sxs[i][dl];
    float dA = __expf(a * A);
    h = dA*h + (a*u)*sB[i][n];
    P *= dA;
  }
  size_t sidx = (((size_t)bd*16 + g)*NCHUNK + ck)*256 + tid;
  Pbuf[sidx] = P;
  Hbuf[sidx] = h;
}

// ---------------- pass 2: sequential combine over chunks (in-place h_end -> h_init) ----------------
__global__ void k_scan2(const float* __restrict__ Pbuf, float* __restrict__ Hbuf){
  int q = blockIdx.x;            // bd*16+g, 0..63
  int tid = threadIdx.x;
  float carry = 0.f;
  for (int k=0;k<NCHUNK;k++){
    size_t idx = ((size_t)q*NCHUNK + k)*256 + tid;
    float Pv = Pbuf[idx];
    float He = Hbuf[idx];
    Hbuf[idx] = carry;           // h_init for chunk k
    carry = Pv*carry + He;
  }
}

// ---------------- pass 3: local scan from h_init, sub-chunked shfl reduce (pr[8] stays in regs) ----------------
__global__ void k_scan3(const bf16* __restrict__ dt, const bf16* __restrict__ xs,
                        const float* __restrict__ Bc, const float* __restrict__ Cc,
                        const float* hA, const float* vA,
                        const float* __restrict__ Hbuf, bf16* __restrict__ ys){
  int bd = blockIdx.z;
  int g  = blockIdx.y;
  int ck = blockIdx.x;
  int l0 = ck*LC;
  const bf16* dtd = dt + (size_t)bd*LLEN*256;
  const bf16* xsd = xs + (size_t)bd*LLEN*256;
  const float* Bd = Bc + (size_t)bd*LLEN*16;
  const float* Cd = Cc + (size_t)bd*LLEN*16;
  bf16* yd = ys + (size_t)bd*LLEN*256;
  const float* Alog = (bd >> 1) ? vA : hA;
  int tid = threadIdx.x;
  int dl = tid >> 4, n = tid & 15;
  int d = g*16 + dl;
  float A = -__expf(Alog[d*16+n]);
  __shared__ float sdt[LC][16], sxs[LC][16], sB[LC][16], sC[LC][16];
  #pragma unroll
  for (int r=0;r<4;r++){
    int idx = tid + r*256;
    int i = idx >> 4, j = idx & 15;
    sdt[i][j] = b2f(dtd[(size_t)(l0+i)*256 + g*16 + j]);
    sxs[i][j] = b2f(xsd[(size_t)(l0+i)*256 + g*16 + j]);
    (&sB[0][0])[idx] = Bd[(size_t)l0*16 + idx];
    (&sC[0][0])[idx] = Cd[(size_t)l0*16 + idx];
  }
  size_t sidx = (((size_t)bd*16 + g)*NCHUNK + ck)*256 + tid;
  float h = Hbuf[sidx];
  __syncthreads();
  float pr[8];                   // bounded live array -> stays in VGPRs (r7 spill fix)
  for (int i0=0; i0<LC; i0+=8){
    #pragma unroll
    for (int ii=0;ii<8;ii++){
      int i = i0 + ii;
      float a = sdt[i][dl];
      float u = sxs[i][dl];
      float dA = __expf(a * A);
      h = dA*h + (a*u)*sB[i][n];
      pr[ii] = h * sC[i][n];
    }
    #pragma unroll
    for (int ii=0;ii<8;ii++){
      float p = pr[ii];
      p += __shfl_xor(p, 1, 16);
      p += __shfl_xor(p, 2, 16);
      p += __shfl_xor(p, 4, 16);
      p += __shfl_xor(p, 8, 16);
      if (n == ((i0+ii) & 15)) yd[(size_t)(l0+i0+ii)*256 + d] = f2b(p);
    }
  }
}

// ---------------- YF = (ys + xs*D) * silu(z), bf16 ----------------
__global__ void k_yf(const bf16* __restrict__ ys, const bf16* __restrict__ xs,
                     const bf16* __restrict__ Z, const float* __restrict__ hD,
                     const float* __restrict__ vD, bf16* __restrict__ YF){
  size_t e = (size_t)blockIdx.x*256 + threadIdx.x;   // < 4*LLEN*256
  int d = (int)(e & 255);
  int dir = (e >= (size_t)2*LLEN*256) ? 1 : 0;
  float Dv = dir ? vD[d] : hD[d];
  float yv = b2f(ys[e]) + b2f(xs[e])*Dv;
  float zv = b2f(Z[e]);
  YF[e] = f2b(yv * (zv/(1.f+__expf(-zv))));
}

// ---------------- out_proj GEMM: 32x64 tiles, register-pipelined, coalesced OD stores ----------------
__global__ void k_outgemm(const bf16* __restrict__ YF, const float* __restrict__ how,
                          const float* __restrict__ vow, bf16* __restrict__ OD){
  int dir = blockIdx.z;
  const bf16* A = YF + (size_t)dir*BATCH*LLEN*256;
  const float* W = dir ? vow : how;
  bf16* od = OD + (size_t)dir*BATCH*LLEN*128;
  int m0 = blockIdx.x*32, n0 = blockIdx.y*64;
  __shared__ __align__(16) float As[16][36];
  __shared__ __align__(16) float Ws[16][68];
  int tid = threadIdx.x, tx = tid&15, ty = tid>>4;
  float acc[2][4] = {};
  float a_r[2], w_r[4];
  #pragma unroll
  for (int r=0;r<2;r++){ int idx = tid + r*256; a_r[r] = b2f(A[(size_t)(m0 + (idx>>4))*256 + (idx&15)]); }
  #pragma unroll
  for (int r=0;r<4;r++){ int idx = tid + r*256; w_r[r] = W[(size_t)(n0 + (idx>>4))*256 + (idx&15)]; }
  for (int k0=0;k0<256;k0+=16){
    __syncthreads();
    #pragma unroll
    for (int r=0;r<2;r++){ int idx = tid + r*256; As[idx&15][idx>>4] = a_r[r]; }
    #pragma unroll
    for (int r=0;r<4;r++){ int idx = tid + r*256; Ws[idx&15][idx>>4] = w_r[r]; }
    __syncthreads();
    if (k0 + 16 < 256){
      int kn = k0 + 16;
      #pragma unroll
      for (int r=0;r<2;r++){ int idx = tid + r*256; a_r[r] = b2f(A[(size_t)(m0 + (idx>>4))*256 + kn + (idx&15)]); }
      #pragma unroll
      for (int r=0;r<4;r++){ int idx = tid + r*256; w_r[r] = W[(size_t)(n0 + (idx>>4))*256 + kn + (idx&15)]; }
    }
    #pragma unroll
    for (int kk=0;kk<16;kk++){
      float2 av = *reinterpret_cast<const float2*>(&As[kk][ty*2]);
      float4 wv = *reinterpret_cast<const float4*>(&Ws[kk][tx*4]);
      float a2[2] = {av.x, av.y};
      float w4[4] = {wv.x, wv.y, wv.z, wv.w};
      #pragma unroll
      for (int i=0;i<2;i++)
        #pragma unroll
        for (int j=0;j<4;j++) acc[i][j] += a2[i]*w4[j];
    }
  }
  #pragma unroll
  for (int i=0;i<2;i++){
    int m = m0 + ty*2 + i;
    #pragma unroll
    for (int j=0;j<4;j++)
      od[(size_t)m*128 + n0 + tx*4 + j] = f2b(acc[i][j]);
  }
}

// ---------------- combine: fused += OH + OV^T  (per h-row LDS tile) ----------------
__global__ void k_combine(const bf16* __restrict__ OD, float* __restrict__ fused){
  int h = blockIdx.x;            // 0..55
  int b = blockIdx.y;
  __shared__ float sfu[56][129];
  int tid = threadIdx.x;
  const bf16* od0 = OD + (size_t)b*LLEN*128;
  const bf16* od1 = OD + (size_t)(BATCH + b)*LLEN*128;
  #pragma unroll 4
  for (int it=0; it<28; it++){
    int idx = it*256 + tid;      // 0..7167
    int sp = idx >> 7, c = idx & 127;
    float v = b2f(od0[(size_t)(h*56+sp)*128 + c]) + b2f(od1[(size_t)(sp*56+h)*128 + c]);
    sfu[sp][c] = v;
  }
  __syncthreads();
  #pragma unroll 4
  for (int it=0; it<28; it++){
    int lin = it*256 + tid;      // 0..7167 = 128c * 56sp
    int c = lin / 56, sp = lin % 56;
    size_t gi = ((size_t)b*128 + c)*LLEN + h*56 + sp;
    fused[gi] += sfu[sp][c];
  }
}

// ---------------- mean over spatial ----------------
__global__ void k_mean(const float* __restrict__ fused, float* __restrict__ ymean){
  int bc = blockIdx.x;
  const float* f = fused + (size_t)bc*LLEN;
  float s = 0.f;
  for (int i = threadIdx.x; i < LLEN; i += 256) s += f[i];
  __shared__ float red[256];
  red[threadIdx.x] = s; __syncthreads();
  for (int off=128; off>0; off>>=1){
    if (threadIdx.x < off) red[threadIdx.x] += red[threadIdx.x+off];
    __syncthreads();
  }
  if (threadIdx.x==0) ymean[bc] = red[0]*(1.f/(float)LLEN);
}

// ---------------- channel attention gate ----------------
__global__ void k_gate(const float* __restrict__ ymean, const float* fc1, const float* fc2,
                       float* __restrict__ gate){
  int b = blockIdx.x;
  __shared__ float ym[128], s1[32];
  int tid = threadIdx.x;
  ym[tid] = ymean[b*128+tid];
  __syncthreads();
  if (tid < 32){
    float a = 0.f;
    for (int c=0;c<128;c++) a += ym[c]*fc1[tid*128+c];
    s1[tid] = fmaxf(a, 0.f);
  }
  __syncthreads();
  float a = 0.f;
  #pragma unroll
  for (int j=0;j<32;j++) a += s1[j]*fc2[tid*32+j];
  gate[b*128+tid] = 1.f/(1.f+__expf(-a));
}

// ---------------- final: out = fused * gate + x  (in-place over fused) ----------------
__global__ void k_final(float* __restrict__ fused, const float* __restrict__ gate,
                        const float* __restrict__ x, float* __restrict__ out){
  int i = blockIdx.x*256 + threadIdx.x;
  if (i >= BATCH*128*LLEN) return;
  int bc = i / LLEN;
  float v = fused[i]*gate[bc] + x[i];
  out[i] = v;
}

extern "C" void kernel_launch(void* const* d_in, const int* in_sizes, int n_in,
                              void* d_out, int out_size, void* d_ws, size_t ws_size,
                              hipStream_t stream) {
  const float* x      = (const float*)d_in[0];
  const float* nhw    = (const float*)d_in[1];
  const float* nhb    = (const float*)d_in[2];
  const float* nvw    = (const float*)d_in[3];
  const float* nvb    = (const float*)d_in[4];
  const float* dww    = (const float*)d_in[5];
  const float* dwb    = (const float*)d_in[6];
  const float* pww    = (const float*)d_in[7];
  const float* pwb    = (const float*)d_in[8];
  const float* h_inw  = (const float*)d_in[9];
  const float* h_cw   = (const float*)d_in[10];
  const float* h_cb   = (const float*)d_in[11];
  const float* h_xw   = (const float*)d_in[12];
  const float* h_dtw  = (const float*)d_in[13];
  const float* h_dtb  = (const float*)d_in[14];
  const float* h_Al   = (const float*)d_in[15];
  const float* h_D    = (const float*)d_in[16];
  const float* h_ow   = (const float*)d_in[17];
  const float* v_inw  = (const float*)d_in[18];
  const float* v_cw   = (const float*)d_in[19];
  const float* v_cb   = (const float*)d_in[20];
  const float* v_xw   = (const float*)d_in[21];
  const float* v_dtw  = (const float*)d_in[22];
  const float* v_dtb  = (const float*)d_in[23];
  const float* v_Al   = (const float*)d_in[24];
  const float* v_D    = (const float*)d_in[25];
  const float* v_ow   = (const float*)d_in[26];
  const float* fc1    = (const float*)d_in[27];
  const float* fc2    = (const float*)d_in[28];

  float* FUSED = (float*)d_out;   // FUSED lives in d_out; k_final is in-place elementwise
  float* out   = (float*)d_out;

  // Workspace layout (bytes), high-water ~30.5 MB. Stream-ordered-safe aliases:
  //  DT overlays TMP+XLN (dead after k_inproj);  YF overlays DT (dead after k_scan3)
  //  YS overlays XI (dead after k_conv);  Pbuf overlays YS head (dead before k_scan3 writes)
  //  OD overlays YS region (YS dead after k_yf)
  //  DBL overlays Hbuf region (DBL dead after k_dtbc, before k_scan1 writes Hbuf)
  char* base = (char*)d_ws;
  bf16*  TMP   = (bf16*)(base + 0);           // 1,605,632 B
  bf16*  XLN   = (bf16*)(base + 1605632);     // 3,211,264 B
  bf16*  DT    = (bf16*)(base + 0);           // 6,422,528 B  [alias TMP+XLN]
  bf16*  YF    = (bf16*)(base + 0);           // 6,422,528 B  [alias DT]
  bf16*  XI    = (bf16*)(base + 6422528);     // 6,422,528 B
  bf16*  YS    = (bf16*)(base + 6422528);     // 6,422,528 B  [alias XI]
  float* Pbuf  = (float*)(base + 6422528);    // 3,211,264 B  [alias XI/YS head]
  bf16*  OD    = (bf16*)(base + 6422528);     // 3,211,264 B  [alias YS; live after k_yf]
  bf16*  Z     = (bf16*)(base + 12845056);    // 6,422,528 B
  bf16*  XS    = (bf16*)(base + 19267584);    // 6,422,528 B
  float* Bf    = (float*)(base + 25690112);   //   802,816 B
  float* Cf    = (float*)(base + 26492928);   //   802,816 B
  float* Hbuf  = (float*)(base + 27295744);   // 3,211,264 B
  float* DBL   = (float*)(base + 27295744);   // 2,007,040 B  [alias Hbuf head]
  float* YMEAN = (float*)(base + 30507008);   //     1,024 B
  float* GATE  = (float*)(base + 30508032);   //     1,024 B

  k_dwconv_gelu<<<dim3(BATCH*128), dim3(256), 0, stream>>>(x, dww, dwb, TMP);
  k_pw_gemm<<<dim3(98,2,BATCH), dim3(256), 0, stream>>>(TMP, pww, pwb, FUSED);
  k_ln<<<dim3(56,BATCH), dim3(256), 0, stream>>>(x, nhw, nhb, nvw, nvb, XLN);
  k_inproj<<<dim3(98,8,2), dim3(256), 0, stream>>>(XLN, h_inw, v_inw, XI, Z);
  k_conv<<<dim3(98,BATCH,2), dim3(256), 0, stream>>>(XI, h_cw, h_cb, v_cw, v_cb, XS);
  k_dbl<<<dim3(196), dim3(256), 0, stream>>>(XS, h_xw, v_xw, DBL);
  k_dtbc<<<dim3(392), dim3(256), 0, stream>>>(DBL, h_dtw, v_dtw, h_dtb, v_dtb, DT, Bf, Cf);
  k_scan1<<<dim3(NCHUNK,16,4), dim3(256), 0, stream>>>(DT, XS, Bf, h_Al, v_Al, Pbuf, Hbuf);
  k_scan2<<<dim3(64), dim3(256), 0, stream>>>(Pbuf, Hbuf);
  k_scan3<<<dim3(NCHUNK,16,4), dim3(256), 0, stream>>>(DT, XS, Bf, Cf, h_Al, v_Al, Hbuf, YS);
  k_yf<<<dim3(4*LLEN), dim3(256), 0, stream>>>(YS, XS, Z, h_D, v_D, YF);
  k_outgemm<<<dim3(196,2,2), dim3(256), 0, stream>>>(YF, h_ow, v_ow, OD);
  k_combine<<<dim3(56,BATCH), dim3(256), 0, stream>>>(OD, FUSED);
  k_mean<<<dim3(BATCH*128), dim3(256), 0, stream>>>(FUSED, YMEAN);
  k_gate<<<dim3(BATCH), dim3(128), 0, stream>>>(YMEAN, fc1, fc2, GATE);
  k_final<<<dim3((BATCH*128*LLEN+255)/256), dim3(256), 0, stream>>>(FUSED, GATE, x, out);
}

// Round 9
// 340.665 us; speedup vs baseline: 1.5259x; 1.0746x over previous
//
#include <hip/hip_runtime.h>
#include <hip/hip_bf16.h>

typedef __hip_bfloat16 bf16;
__device__ __forceinline__ float b2f(bf16 v){ return __bfloat162float(v); }
__device__ __forceinline__ bf16 f2b(float v){ return __float2bfloat16(v); }

#define LLEN 3136
#define BATCH 2
#define NCHUNK 49
#define LC 64

// ---------------- dwconv 3x3 + gelu ----------------
__global__ void k_dwconv_gelu(const float* __restrict__ x, const float* __restrict__ dww,
                              const float* __restrict__ dwb, bf16* __restrict__ tmp){
  int bc = blockIdx.x;            // b*128 + c
  int c = bc & 127;
  const float* xp = x + (size_t)bc*LLEN;
  float w[9];
  #pragma unroll
  for (int i=0;i<9;i++) w[i] = dww[c*9+i];
  float bias = dwb[c];
  for (int p = threadIdx.x; p < LLEN; p += blockDim.x){
    int i = p/56, j = p%56;
    float acc = bias;
    #pragma unroll
    for (int a=0;a<3;a++){
      int ii = i + a - 1;
      if (ii < 0 || ii >= 56) continue;
      #pragma unroll
      for (int bb=0;bb<3;bb++){
        int jj = j + bb - 1;
        if (jj < 0 || jj >= 56) continue;
        acc += w[a*3+bb] * xp[ii*56+jj];
      }
    }
    float g = 0.5f*acc*(1.0f + erff(acc*0.70710678118654752f));
    tmp[(size_t)bc*LLEN + p] = f2b(g);
  }
}

// ---------------- pointwise conv GEMM: 32x64 tiles, register-pipelined ----------------
__global__ void k_pw_gemm(const bf16* __restrict__ tmp, const float* __restrict__ pww,
                          const float* __restrict__ pwb, float* __restrict__ fused){
  int b = blockIdx.z;
  int p0 = blockIdx.x * 32;
  int n0 = blockIdx.y * 64;
  const bf16* A = tmp + (size_t)b*128*LLEN;
  __shared__ __align__(16) float As[16][36];
  __shared__ __align__(16) float Ws[16][68];
  int tid = threadIdx.x, tx = tid & 15, ty = tid >> 4;
  float acc[2][4] = {};
  float a_r[2], w_r[4];
  #pragma unroll
  for (int r=0;r<2;r++){ int idx = tid + r*256; a_r[r] = b2f(A[(size_t)(idx>>5)*LLEN + p0 + (idx&31)]); }
  #pragma unroll
  for (int r=0;r<4;r++){ int idx = tid + r*256; w_r[r] = pww[(n0 + (idx>>4))*128 + (idx&15)]; }
  for (int k0 = 0; k0 < 128; k0 += 16){
    __syncthreads();
    #pragma unroll
    for (int r=0;r<2;r++){ int idx = tid + r*256; As[idx>>5][idx&31] = a_r[r]; }
    #pragma unroll
    for (int r=0;r<4;r++){ int idx = tid + r*256; Ws[idx&15][idx>>4] = w_r[r]; }
    __syncthreads();
    if (k0 + 16 < 128){
      int kn = k0 + 16;
      #pragma unroll
      for (int r=0;r<2;r++){ int idx = tid + r*256; a_r[r] = b2f(A[(size_t)(kn + (idx>>5))*LLEN + p0 + (idx&31)]); }
      #pragma unroll
      for (int r=0;r<4;r++){ int idx = tid + r*256; w_r[r] = pww[(n0 + (idx>>4))*128 + kn + (idx&15)]; }
    }
    #pragma unroll
    for (int kk=0;kk<16;kk++){
      float2 av = *reinterpret_cast<const float2*>(&As[kk][ty*2]);
      float4 wv = *reinterpret_cast<const float4*>(&Ws[kk][tx*4]);
      float a2[2] = {av.x, av.y};
      float w4[4] = {wv.x, wv.y, wv.z, wv.w};
      #pragma unroll
      for (int i=0;i<2;i++)
        #pragma unroll
        for (int j=0;j<4;j++) acc[i][j] += a2[i]*w4[j];
    }
  }
  #pragma unroll
  for (int j=0;j<4;j++){
    int n = n0 + tx*4 + j;
    float bias = pwb[n];
    #pragma unroll
    for (int i=0;i<2;i++)
      fused[((size_t)b*128 + n)*LLEN + p0 + ty*2 + i] = acc[i][j] + bias;
  }
}

// ---------------- LayerNorm over C, write both direction orderings (bf16) ----------------
__global__ void k_ln(const float* __restrict__ x, const float* nhw_, const float* nhb_,
                     const float* nvw_, const float* nvb_, bf16* __restrict__ xln){
  __shared__ float sx[128][57];
  __shared__ float smean[56], srstd[56];
  __shared__ float wh[128], bh[128], wv_[128], bv_[128];
  int h = blockIdx.x; int b = blockIdx.y;
  int tid = threadIdx.x;
  if (tid < 128){ wh[tid]=nhw_[tid]; bh[tid]=nhb_[tid];
                  wv_[tid]=nvw_[tid]; bv_[tid]=nvb_[tid]; }
  for (int idx = tid; idx < 128*56; idx += 256){
    int c = idx / 56, w = idx % 56;
    sx[c][w] = x[((size_t)(b*128+c))*LLEN + h*56 + w];
  }
  __syncthreads();
  if (tid < 56){
    float s=0.f, s2=0.f;
    for (int c=0;c<128;c++){ float v = sx[c][tid]; s+=v; s2+=v*v; }
    float m = s*(1.f/128.f);
    float var = s2*(1.f/128.f) - m*m;
    smean[tid]=m; srstd[tid]=rsqrtf(var+1e-5f);
  }
  __syncthreads();
  bf16* outh = xln;
  bf16* outv = xln + (size_t)BATCH*LLEN*128;
  for (int idx = tid; idx < 56*128; idx += 256){
    int w = idx >> 7, c = idx & 127;
    float v = (sx[c][w]-smean[w])*srstd[w];
    outh[((size_t)b*LLEN + h*56 + w)*128 + c] = f2b(v*wh[c]+bh[c]);
    outv[((size_t)b*LLEN + w*56 + h)*128 + c] = f2b(v*wv_[c]+bv_[c]);
  }
}

// ---------------- in_proj GEMM: 32x64 tiles, register-pipelined ----------------
__global__ void k_inproj(const bf16* __restrict__ xln, const float* __restrict__ hw,
                         const float* __restrict__ vw, bf16* __restrict__ XI, bf16* __restrict__ Z){
  int dir = blockIdx.z;
  const bf16* A = xln + (size_t)dir*BATCH*LLEN*128;
  const float* W = dir ? vw : hw;
  int m0 = blockIdx.x*32, n0 = blockIdx.y*64;
  __shared__ __align__(16) float As[16][36];
  __shared__ __align__(16) float Ws[16][68];
  int tid = threadIdx.x, tx = tid&15, ty = tid>>4;
  float acc[2][4] = {};
  float a_r[2], w_r[4];
  #pragma unroll
  for (int r=0;r<2;r++){ int idx = tid + r*256; a_r[r] = b2f(A[(size_t)(m0 + (idx>>4))*128 + (idx&15)]); }
  #pragma unroll
  for (int r=0;r<4;r++){ int idx = tid + r*256; w_r[r] = W[(size_t)(n0 + (idx>>4))*128 + (idx&15)]; }
  for (int k0=0;k0<128;k0+=16){
    __syncthreads();
    #pragma unroll
    for (int r=0;r<2;r++){ int idx = tid + r*256; As[idx&15][idx>>4] = a_r[r]; }
    #pragma unroll
    for (int r=0;r<4;r++){ int idx = tid + r*256; Ws[idx&15][idx>>4] = w_r[r]; }
    __syncthreads();
    if (k0 + 16 < 128){
      int kn = k0 + 16;
      #pragma unroll
      for (int r=0;r<2;r++){ int idx = tid + r*256; a_r[r] = b2f(A[(size_t)(m0 + (idx>>4))*128 + kn + (idx&15)]); }
      #pragma unroll
      for (int r=0;r<4;r++){ int idx = tid + r*256; w_r[r] = W[(size_t)(n0 + (idx>>4))*128 + kn + (idx&15)]; }
    }
    #pragma unroll
    for (int kk=0;kk<16;kk++){
      float2 av = *reinterpret_cast<const float2*>(&As[kk][ty*2]);
      float4 wv = *reinterpret_cast<const float4*>(&Ws[kk][tx*4]);
      float a2[2] = {av.x, av.y};
      float w4[4] = {wv.x, wv.y, wv.z, wv.w};
      #pragma unroll
      for (int i=0;i<2;i++)
        #pragma unroll
        for (int j=0;j<4;j++) acc[i][j] += a2[i]*w4[j];
    }
  }
  bf16* dst = (n0 < 256) ? XI : Z;
  int nbase = n0 & 255;
  size_t dslab = (size_t)dir*BATCH*LLEN*256;
  #pragma unroll
  for (int i=0;i<2;i++){
    int m = m0 + ty*2 + i;
    #pragma unroll
    for (int j=0;j<4;j++)
      dst[dslab + (size_t)m*256 + nbase + tx*4 + j] = f2b(acc[i][j]);
  }
}

// ---------------- causal depthwise conv1d(k=4) + silu; writes XS (row-major) + XS2 (scan layout) ----------------
__global__ void k_conv(const bf16* __restrict__ XI, const float* hw, const float* hb,
                       const float* vw, const float* vb, bf16* __restrict__ XS,
                       bf16* __restrict__ XS2){
  int dir = blockIdx.z;
  int b = blockIdx.y;
  int bd = dir*BATCH + b;
  int l0 = blockIdx.x * 32;
  const bf16* XId = XI + (size_t)bd*LLEN*256;
  bf16* XSd = XS + (size_t)bd*LLEN*256;
  const float* cw = dir ? vw : hw;
  const float* cb = dir ? vb : hb;
  __shared__ float sxi[35][256];
  int tid = threadIdx.x;
  for (int r = 0; r < 35; r++){
    int l = l0 - 3 + r;
    sxi[r][tid] = (l >= 0) ? b2f(XId[(size_t)l*256 + tid]) : 0.f;
  }
  __syncthreads();
  float w0=cw[tid*4], w1=cw[tid*4+1], w2=cw[tid*4+2], w3=cw[tid*4+3];
  float bias = cb[tid];
  size_t x2base = ((size_t)bd*16 + (tid>>4))*LLEN;
  int c16 = tid & 15;
  for (int ll=0; ll<32; ll++){
    float acc = bias + w0*sxi[ll][tid] + w1*sxi[ll+1][tid] + w2*sxi[ll+2][tid] + w3*sxi[ll+3][tid];
    float s = acc / (1.f + __expf(-acc));
    bf16 sv = f2b(s);
    XSd[(size_t)(l0+ll)*256 + tid] = sv;
    XS2[(x2base + l0 + ll)*16 + c16] = sv;
  }
}

// ---------------- xproj stage 1: DBL[row][40] = XS[row][:] @ xw^T ----------------
__global__ void k_dbl(const bf16* __restrict__ XS, const float* __restrict__ hx,
                      const float* __restrict__ vx, float* __restrict__ DBL){
  int m0 = blockIdx.x*64;                      // 196 tiles; dir boundary at row 6272 = 98*64
  const float* W = (m0 >= 2*LLEN) ? vx : hx;
  __shared__ __align__(16) float As[16][68];
  __shared__ float Ws[16][42];
  int tid = threadIdx.x;
  int tx = tid & 7, ty = tid >> 3;             // tx: 8 groups of 5 cols, ty: 32 groups of 2 rows
  float acc[2][5] = {};
  for (int k0=0;k0<256;k0+=16){
    __syncthreads();
    #pragma unroll
    for (int r=0;r<4;r++){
      int idx = tid + r*256;
      int row = idx >> 4, k = idx & 15;
      As[k][row] = b2f(XS[(size_t)(m0+row)*256 + k0 + k]);
    }
    #pragma unroll
    for (int r=0;r<3;r++){
      int idx = tid + r*256;
      if (idx < 640){
        int o = idx >> 4, k = idx & 15;
        Ws[k][o] = W[o*256 + k0 + k];
      }
    }
    __syncthreads();
    #pragma unroll
    for (int kk=0;kk<16;kk++){
      float a0 = As[kk][ty*2], a1 = As[kk][ty*2+1];
      #pragma unroll
      for (int j=0;j<5;j++){
        float wv = Ws[kk][tx*5+j];
        acc[0][j] += a0*wv;
        acc[1][j] += a1*wv;
      }
    }
  }
  #pragma unroll
  for (int i=0;i<2;i++)
    #pragma unroll
    for (int j=0;j<5;j++)
      DBL[(size_t)(m0+ty*2+i)*40 + tx*5 + j] = acc[i][j];
}

// ---------------- xproj stage 2: dt = softplus(...) -> DT2 (scan layout); B,C extract ----------------
__global__ void k_dtbc(const float* __restrict__ DBL, const float* hdw, const float* vdw,
                       const float* hdb, const float* vdb,
                       bf16* __restrict__ DT2, float* __restrict__ Bf, float* __restrict__ Cf){
  int r0 = blockIdx.x*32;                      // 392 blocks; bd boundary clean (3136/32=98)
  int bd = r0 / LLEN;                          // dir*2+b
  int l0 = r0 % LLEN;
  int dirq = (bd >> 1);
  const float* dtw = dirq ? vdw : hdw;
  const float* dtb = dirq ? vdb : hdb;
  __shared__ float sdbl[32][40];
  int tid = threadIdx.x;
  #pragma unroll
  for (int r=0;r<5;r++){
    int idx = tid + r*256;                     // 1280 = 32*40 exact
    sdbl[idx/40][idx%40] = DBL[(size_t)r0*40 + idx];
  }
  __syncthreads();
  float w8[8];
  #pragma unroll
  for (int r=0;r<8;r++) w8[r] = dtw[tid*8+r];
  float bias = dtb[tid];
  size_t d2base = ((size_t)bd*16 + (tid>>4))*LLEN;
  int c16 = tid & 15;
  for (int row=0; row<32; row++){
    float a = bias;
    #pragma unroll
    for (int r=0;r<8;r++) a += sdbl[row][r]*w8[r];
    float sv = (a > 20.f) ? a : __logf(1.f + __expf(a));
    DT2[(d2base + l0 + row)*16 + c16] = f2b(sv);
  }
  #pragma unroll
  for (int r=0;r<4;r++){
    int idx = tid + r*256;                     // 1024 = 32 rows * 32 vals
    int row = idx >> 5, o = idx & 31;
    float v = sdbl[row][8+o];
    if (o < 16) Bf[(size_t)(r0+row)*16 + o] = v;
    else        Cf[(size_t)(r0+row)*16 + (o-16)] = v;
  }
}

// ---------------- chunked selective scan: pass 1 (local scan, P & h_end) ----------------
__global__ void k_scan1(const bf16* __restrict__ DT2, const bf16* __restrict__ XS2,
                        const float* __restrict__ Bc, const float* hA, const float* vA,
                        float* __restrict__ Pbuf, float* __restrict__ Hbuf){
  int bd = blockIdx.z;           // dir*2+b
  int g  = blockIdx.y;           // channel group 0..15
  int ck = blockIdx.x;           // chunk 0..48
  int l0 = ck*LC;
  const float* Bd = Bc + (size_t)bd*LLEN*16;
  const float* Alog = (bd >> 1) ? vA : hA;
  int tid = threadIdx.x;
  int dl = tid >> 4, n = tid & 15;
  int d = g*16 + dl;
  float A = -__expf(Alog[d*16+n]);
  __shared__ float sdt[LC][16], sxs[LC][16], sB[LC][16];
  size_t base2 = (((size_t)bd*16 + g)*LLEN + l0)*16;
  #pragma unroll
  for (int r=0;r<4;r++){
    int idx = tid + r*256;
    sdt[idx>>4][idx&15] = b2f(DT2[base2 + idx]);
    sxs[idx>>4][idx&15] = b2f(XS2[base2 + idx]);
    (&sB[0][0])[idx] = Bd[(size_t)l0*16 + idx];
  }
  __syncthreads();
  float h = 0.f, P = 1.f;
  #pragma unroll 8
  for (int i=0;i<LC;i++){
    float a = sdt[i][dl];
    float u = sxs[i][dl];
    float dA = __expf(a * A);
    h = dA*h + (a*u)*sB[i][n];
    P *= dA;
  }
  size_t sidx = (((size_t)bd*16 + g)*NCHUNK + ck)*256 + tid;
  Pbuf[sidx] = P;
  Hbuf[sidx] = h;
}

// ---------------- pass 2: sequential combine over chunks (in-place h_end -> h_init) ----------------
__global__ void k_scan2(const float* __restrict__ Pbuf, float* __restrict__ Hbuf){
  int q = blockIdx.x;            // bd*16+g, 0..63
  int tid = threadIdx.x;
  float carry = 0.f;
  for (int k=0;k<NCHUNK;k++){
    size_t idx = ((size_t)q*NCHUNK + k)*256 + tid;
    float Pv = Pbuf[idx];
    float He = Hbuf[idx];
    Hbuf[idx] = carry;           // h_init for chunk k
    carry = Pv*carry + He;
  }
}

// ---------------- pass 3: local scan from h_init, subchunked LDS reduce, emit y ----------------
__global__ void k_scan3(const bf16* __restrict__ DT2, const bf16* __restrict__ XS2,
                        const float* __restrict__ Bc, const float* __restrict__ Cc,
                        const float* hA, const float* vA,
                        const float* __restrict__ Hbuf, bf16* __restrict__ ys){
  int bd = blockIdx.z;
  int g  = blockIdx.y;
  int ck = blockIdx.x;
  int l0 = ck*LC;
  const float* Bd = Bc + (size_t)bd*LLEN*16;
  const float* Cd = Cc + (size_t)bd*LLEN*16;
  bf16* yd = ys + (size_t)bd*LLEN*256;
  const float* Alog = (bd >> 1) ? vA : hA;
  int tid = threadIdx.x;
  int dl = tid >> 4, n = tid & 15;
  float A = -__expf(Alog[(g*16+dl)*16+n]);
  __shared__ float sdt[LC][16], sxs[LC][16], sB[LC][16], sC[LC][16];
  __shared__ __align__(16) float sp2[16][276];   // 17.7 KB; subchunk partial products
  size_t base2 = (((size_t)bd*16 + g)*LLEN + l0)*16;
  #pragma unroll
  for (int r=0;r<4;r++){
    int idx = tid + r*256;
    sdt[idx>>4][idx&15] = b2f(DT2[base2 + idx]);
    sxs[idx>>4][idx&15] = b2f(XS2[base2 + idx]);
    (&sB[0][0])[idx] = Bd[(size_t)l0*16 + idx];
    (&sC[0][0])[idx] = Cd[(size_t)l0*16 + idx];
  }
  size_t sidx = (((size_t)bd*16 + g)*NCHUNK + ck)*256 + tid;
  float h = Hbuf[sidx];
  __syncthreads();
  int i_local = tid >> 4;        // reduce-phase: step within subchunk
  int c16 = tid & 15;            // reduce-phase: channel-in-group
  for (int i0=0; i0<LC; i0+=16){
    #pragma unroll
    for (int ii=0;ii<16;ii++){
      int i = i0 + ii;
      float a = sdt[i][dl];
      float u = sxs[i][dl];
      float dA = __expf(a * A);
      h = dA*h + (a*u)*sB[i][n];
      sp2[ii][tid] = h * sC[i][n];
    }
    __syncthreads();
    const float* row = &sp2[i_local][c16*16];
    float s = 0.f;
    #pragma unroll
    for (int k=0;k<4;k++){
      float4 v = *reinterpret_cast<const float4*>(row + k*4);
      s += v.x + v.y + v.z + v.w;
    }
    yd[(size_t)(l0+i0+i_local)*256 + g*16 + c16] = f2b(s);
    __syncthreads();
  }
}

// ---------------- YF = (ys + xs*D) * silu(z), bf16 ----------------
__global__ void k_yf(const bf16* __restrict__ ys, const bf16* __restrict__ xs,
                     const bf16* __restrict__ Z, const float* __restrict__ hD,
                     const float* __restrict__ vD, bf16* __restrict__ YF){
  size_t e = (size_t)blockIdx.x*256 + threadIdx.x;   // < 4*LLEN*256
  int d = (int)(e & 255);
  int dir = (e >= (size_t)2*LLEN*256) ? 1 : 0;
  float Dv = dir ? vD[d] : hD[d];
  float yv = b2f(ys[e]) + b2f(xs[e])*Dv;
  float zv = b2f(Z[e]);
  YF[e] = f2b(yv * (zv/(1.f+__expf(-zv))));
}

// ---------------- out_proj GEMM: 32x64 tiles, register-pipelined, coalesced OD stores ----------------
__global__ void k_outgemm(const bf16* __restrict__ YF, const float* __restrict__ how,
                          const float* __restrict__ vow, bf16* __restrict__ OD){
  int dir = blockIdx.z;
  const bf16* A = YF + (size_t)dir*BATCH*LLEN*256;
  const float* W = dir ? vow : how;
  bf16* od = OD + (size_t)dir*BATCH*LLEN*128;
  int m0 = blockIdx.x*32, n0 = blockIdx.y*64;
  __shared__ __align__(16) float As[16][36];
  __shared__ __align__(16) float Ws[16][68];
  int tid = threadIdx.x, tx = tid&15, ty = tid>>4;
  float acc[2][4] = {};
  float a_r[2], w_r[4];
  #pragma unroll
  for (int r=0;r<2;r++){ int idx = tid + r*256; a_r[r] = b2f(A[(size_t)(m0 + (idx>>4))*256 + (idx&15)]); }
  #pragma unroll
  for (int r=0;r<4;r++){ int idx = tid + r*256; w_r[r] = W[(size_t)(n0 + (idx>>4))*256 + (idx&15)]; }
  for (int k0=0;k0<256;k0+=16){
    __syncthreads();
    #pragma unroll
    for (int r=0;r<2;r++){ int idx = tid + r*256; As[idx&15][idx>>4] = a_r[r]; }
    #pragma unroll
    for (int r=0;r<4;r++){ int idx = tid + r*256; Ws[idx&15][idx>>4] = w_r[r]; }
    __syncthreads();
    if (k0 + 16 < 256){
      int kn = k0 + 16;
      #pragma unroll
      for (int r=0;r<2;r++){ int idx = tid + r*256; a_r[r] = b2f(A[(size_t)(m0 + (idx>>4))*256 + kn + (idx&15)]); }
      #pragma unroll
      for (int r=0;r<4;r++){ int idx = tid + r*256; w_r[r] = W[(size_t)(n0 + (idx>>4))*256 + kn + (idx&15)]; }
    }
    #pragma unroll
    for (int kk=0;kk<16;kk++){
      float2 av = *reinterpret_cast<const float2*>(&As[kk][ty*2]);
      float4 wv = *reinterpret_cast<const float4*>(&Ws[kk][tx*4]);
      float a2[2] = {av.x, av.y};
      float w4[4] = {wv.x, wv.y, wv.z, wv.w};
      #pragma unroll
      for (int i=0;i<2;i++)
        #pragma unroll
        for (int j=0;j<4;j++) acc[i][j] += a2[i]*w4[j];
    }
  }
  #pragma unroll
  for (int i=0;i<2;i++){
    int m = m0 + ty*2 + i;
    #pragma unroll
    for (int j=0;j<4;j++)
      od[(size_t)m*128 + n0 + tx*4 + j] = f2b(acc[i][j]);
  }
}

// ---------------- combine: fused += OH + OV^T  (per h-row LDS tile) ----------------
__global__ void k_combine(const bf16* __restrict__ OD, float* __restrict__ fused){
  int h = blockIdx.x;            // 0..55
  int b = blockIdx.y;
  __shared__ float sfu[56][129];
  int tid = threadIdx.x;
  const bf16* od0 = OD + (size_t)b*LLEN*128;
  const bf16* od1 = OD + (size_t)(BATCH + b)*LLEN*128;
  #pragma unroll 4
  for (int it=0; it<28; it++){
    int idx = it*256 + tid;      // 0..7167
    int sp = idx >> 7, c = idx & 127;
    float v = b2f(od0[(size_t)(h*56+sp)*128 + c]) + b2f(od1[(size_t)(sp*56+h)*128 + c]);
    sfu[sp][c] = v;
  }
  __syncthreads();
  #pragma unroll 4
  for (int it=0; it<28; it++){
    int lin = it*256 + tid;      // 0..7167 = 128c * 56sp
    int c = lin / 56, sp = lin % 56;
    size_t gi = ((size_t)b*128 + c)*LLEN + h*56 + sp;
    fused[gi] += sfu[sp][c];
  }
}

// ---------------- mean over spatial ----------------
__global__ void k_mean(const float* __restrict__ fused, float* __restrict__ ymean){
  int bc = blockIdx.x;
  const float* f = fused + (size_t)bc*LLEN;
  float s = 0.f;
  for (int i = threadIdx.x; i < LLEN; i += 256) s += f[i];
  __shared__ float red[256];
  red[threadIdx.x] = s; __syncthreads();
  for (int off=128; off>0; off>>=1){
    if (threadIdx.x < off) red[threadIdx.x] += red[threadIdx.x+off];
    __syncthreads();
  }
  if (threadIdx.x==0) ymean[bc] = red[0]*(1.f/(float)LLEN);
}

// ---------------- channel attention gate ----------------
__global__ void k_gate(const float* __restrict__ ymean, const float* fc1, const float* fc2,
                       float* __restrict__ gate){
  int b = blockIdx.x;
  __shared__ float ym[128], s1[32];
  int tid = threadIdx.x;
  ym[tid] = ymean[b*128+tid];
  __syncthreads();
  if (tid < 32){
    float a = 0.f;
    for (int c=0;c<128;c++) a += ym[c]*fc1[tid*128+c];
    s1[tid] = fmaxf(a, 0.f);
  }
  __syncthreads();
  float a = 0.f;
  #pragma unroll
  for (int j=0;j<32;j++) a += s1[j]*fc2[tid*32+j];
  gate[b*128+tid] = 1.f/(1.f+__expf(-a));
}

// ---------------- final: out = fused * gate + x  (in-place over fused) ----------------
__global__ void k_final(float* __restrict__ fused, const float* __restrict__ gate,
                        const float* __restrict__ x, float* __restrict__ out){
  int i = blockIdx.x*256 + threadIdx.x;
  if (i >= BATCH*128*LLEN) return;
  int bc = i / LLEN;
  float v = fused[i]*gate[bc] + x[i];
  out[i] = v;
}

extern "C" void kernel_launch(void* const* d_in, const int* in_sizes, int n_in,
                              void* d_out, int out_size, void* d_ws, size_t ws_size,
                              hipStream_t stream) {
  const float* x      = (const float*)d_in[0];
  const float* nhw    = (const float*)d_in[1];
  const float* nhb    = (const float*)d_in[2];
  const float* nvw    = (const float*)d_in[3];
  const float* nvb    = (const float*)d_in[4];
  const float* dww    = (const float*)d_in[5];
  const float* dwb    = (const float*)d_in[6];
  const float* pww    = (const float*)d_in[7];
  const float* pwb    = (const float*)d_in[8];
  const float* h_inw  = (const float*)d_in[9];
  const float* h_cw   = (const float*)d_in[10];
  const float* h_cb   = (const float*)d_in[11];
  const float* h_xw   = (const float*)d_in[12];
  const float* h_dtw  = (const float*)d_in[13];
  const float* h_dtb  = (const float*)d_in[14];
  const float* h_Al   = (const float*)d_in[15];
  const float* h_D    = (const float*)d_in[16];
  const float* h_ow   = (const float*)d_in[17];
  const float* v_inw  = (const float*)d_in[18];
  const float* v_cw   = (const float*)d_in[19];
  const float* v_cb   = (const float*)d_in[20];
  const float* v_xw   = (const float*)d_in[21];
  const float* v_dtw  = (const float*)d_in[22];
  const float* v_dtb  = (const float*)d_in[23];
  const float* v_Al   = (const float*)d_in[24];
  const float* v_D    = (const float*)d_in[25];
  const float* v_ow   = (const float*)d_in[26];
  const float* fc1    = (const float*)d_in[27];
  const float* fc2    = (const float*)d_in[28];

  float* FUSED = (float*)d_out;   // FUSED lives in d_out; k_final is in-place elementwise
  float* out   = (float*)d_out;

  // Workspace layout (bytes), high-water ~36.9 MB. Stream-ordered-safe aliases:
  //  DT2 overlays TMP+XLN (dead after k_inproj);  YF overlays DT2 (dead after k_scan3)
  //  YS overlays XI (dead after k_conv);  Pbuf overlays YS head (dead before k_scan3 writes)
  //  OD overlays YS region (YS dead after k_yf)
  //  DBL overlays Hbuf region (DBL dead after k_dtbc, before k_scan1 writes Hbuf)
  char* base = (char*)d_ws;
  bf16*  TMP   = (bf16*)(base + 0);           // 1,605,632 B
  bf16*  XLN   = (bf16*)(base + 1605632);     // 3,211,264 B
  bf16*  DT2   = (bf16*)(base + 0);           // 6,422,528 B  [alias TMP+XLN; scan layout]
  bf16*  YF    = (bf16*)(base + 0);           // 6,422,528 B  [alias DT2]
  bf16*  XI    = (bf16*)(base + 6422528);     // 6,422,528 B
  bf16*  YS    = (bf16*)(base + 6422528);     // 6,422,528 B  [alias XI]
  float* Pbuf  = (float*)(base + 6422528);    // 3,211,264 B  [alias XI/YS head]
  bf16*  OD    = (bf16*)(base + 6422528);     // 3,211,264 B  [alias YS; live after k_yf]
  bf16*  Z     = (bf16*)(base + 12845056);    // 6,422,528 B
  bf16*  XS    = (bf16*)(base + 19267584);    // 6,422,528 B
  float* Bf    = (float*)(base + 25690112);   //   802,816 B
  float* Cf    = (float*)(base + 26492928);   //   802,816 B
  float* Hbuf  = (float*)(base + 27295744);   // 3,211,264 B
  float* DBL   = (float*)(base + 27295744);   // 2,007,040 B  [alias Hbuf head]
  float* YMEAN = (float*)(base + 30507008);   //     1,024 B
  float* GATE  = (float*)(base + 30508032);   //     1,024 B
  bf16*  XS2   = (bf16*)(base + 30509056);    // 6,422,528 B  [scan layout copy of XS]

  k_dwconv_gelu<<<dim3(BATCH*128), dim3(256), 0, stream>>>(x, dww, dwb, TMP);
  k_pw_gemm<<<dim3(98,2,BATCH), dim3(256), 0, stream>>>(TMP, pww, pwb, FUSED);
  k_ln<<<dim3(56,BATCH), dim3(256), 0, stream>>>(x, nhw, nhb, nvw, nvb, XLN);
  k_inproj<<<dim3(196,8,2), dim3(256), 0, stream>>>(XLN, h_inw, v_inw, XI, Z);
  k_conv<<<dim3(98,BATCH,2), dim3(256), 0, stream>>>(XI, h_cw, h_cb, v_cw, v_cb, XS, XS2);
  k_dbl<<<dim3(196), dim3(256), 0, stream>>>(XS, h_xw, v_xw, DBL);
  k_dtbc<<<dim3(392), dim3(256), 0, stream>>>(DBL, h_dtw, v_dtw, h_dtb, v_dtb, DT2, Bf, Cf);
  k_scan1<<<dim3(NCHUNK,16,4), dim3(256), 0, stream>>>(DT2, XS2, Bf, h_Al, v_Al, Pbuf, Hbuf);
  k_scan2<<<dim3(64), dim3(256), 0, stream>>>(Pbuf, Hbuf);
  k_scan3<<<dim3(NCHUNK,16,4), dim3(256), 0, stream>>>(DT2, XS2, Bf, Cf, h_Al, v_Al, Hbuf, YS);
  k_yf<<<dim3(4*LLEN), dim3(256), 0, stream>>>(YS, XS, Z, h_D, v_D, YF);
  k_outgemm<<<dim3(196,2,2), dim3(256), 0, stream>>>(YF, h_ow, v_ow, OD);
  k_combine<<<dim3(56,BATCH), dim3(256), 0, stream>>>(OD, FUSED);
  k_mean<<<dim3(BATCH*128), dim3(256), 0, stream>>>(FUSED, YMEAN);
  k_gate<<<dim3(BATCH), dim3(128), 0, stream>>>(YMEAN, fc1, fc2, GATE);
  k_final<<<dim3((BATCH*128*LLEN+255)/256), dim3(256), 0, stream>>>(FUSED, GATE, x, out);
}

// Round 10
// 316.110 us; speedup vs baseline: 1.6444x; 1.0777x over previous
//
#include <hip/hip_runtime.h>
#include <hip/hip_bf16.h>

typedef __hip_bfloat16 bf16;
__device__ __forceinline__ float b2f(bf16 v){ return __bfloat162float(v); }
__device__ __forceinline__ bf16 f2b(float v){ return __float2bfloat16(v); }

#define LLEN 3136
#define BATCH 2
#define NCHUNK 49
#define LC 64

// ---------------- dwconv 3x3 + gelu ----------------
__global__ void k_dwconv_gelu(const float* __restrict__ x, const float* __restrict__ dww,
                              const float* __restrict__ dwb, bf16* __restrict__ tmp){
  int bc = blockIdx.x;            // b*128 + c
  int c = bc & 127;
  const float* xp = x + (size_t)bc*LLEN;
  float w[9];
  #pragma unroll
  for (int i=0;i<9;i++) w[i] = dww[c*9+i];
  float bias = dwb[c];
  for (int p = threadIdx.x; p < LLEN; p += blockDim.x){
    int i = p/56, j = p%56;
    float acc = bias;
    #pragma unroll
    for (int a=0;a<3;a++){
      int ii = i + a - 1;
      if (ii < 0 || ii >= 56) continue;
      #pragma unroll
      for (int bb=0;bb<3;bb++){
        int jj = j + bb - 1;
        if (jj < 0 || jj >= 56) continue;
        acc += w[a*3+bb] * xp[ii*56+jj];
      }
    }
    float g = 0.5f*acc*(1.0f + erff(acc*0.70710678118654752f));
    tmp[(size_t)bc*LLEN + p] = f2b(g);
  }
}

// ---------------- pointwise conv GEMM: 32x64 tiles, register-pipelined ----------------
__global__ void k_pw_gemm(const bf16* __restrict__ tmp, const float* __restrict__ pww,
                          const float* __restrict__ pwb, float* __restrict__ fused){
  int b = blockIdx.z;
  int p0 = blockIdx.x * 32;
  int n0 = blockIdx.y * 64;
  const bf16* A = tmp + (size_t)b*128*LLEN;
  __shared__ __align__(16) float As[16][36];
  __shared__ __align__(16) float Ws[16][68];
  int tid = threadIdx.x, tx = tid & 15, ty = tid >> 4;
  float acc[2][4] = {};
  float a_r[2], w_r[4];
  #pragma unroll
  for (int r=0;r<2;r++){ int idx = tid + r*256; a_r[r] = b2f(A[(size_t)(idx>>5)*LLEN + p0 + (idx&31)]); }
  #pragma unroll
  for (int r=0;r<4;r++){ int idx = tid + r*256; w_r[r] = pww[(n0 + (idx>>4))*128 + (idx&15)]; }
  for (int k0 = 0; k0 < 128; k0 += 16){
    __syncthreads();
    #pragma unroll
    for (int r=0;r<2;r++){ int idx = tid + r*256; As[idx>>5][idx&31] = a_r[r]; }
    #pragma unroll
    for (int r=0;r<4;r++){ int idx = tid + r*256; Ws[idx&15][idx>>4] = w_r[r]; }
    __syncthreads();
    if (k0 + 16 < 128){
      int kn = k0 + 16;
      #pragma unroll
      for (int r=0;r<2;r++){ int idx = tid + r*256; a_r[r] = b2f(A[(size_t)(kn + (idx>>5))*LLEN + p0 + (idx&31)]); }
      #pragma unroll
      for (int r=0;r<4;r++){ int idx = tid + r*256; w_r[r] = pww[(n0 + (idx>>4))*128 + kn + (idx&15)]; }
    }
    #pragma unroll
    for (int kk=0;kk<16;kk++){
      float2 av = *reinterpret_cast<const float2*>(&As[kk][ty*2]);
      float4 wv = *reinterpret_cast<const float4*>(&Ws[kk][tx*4]);
      float a2[2] = {av.x, av.y};
      float w4[4] = {wv.x, wv.y, wv.z, wv.w};
      #pragma unroll
      for (int i=0;i<2;i++)
        #pragma unroll
        for (int j=0;j<4;j++) acc[i][j] += a2[i]*w4[j];
    }
  }
  #pragma unroll
  for (int j=0;j<4;j++){
    int n = n0 + tx*4 + j;
    float bias = pwb[n];
    #pragma unroll
    for (int i=0;i<2;i++)
      fused[((size_t)b*128 + n)*LLEN + p0 + ty*2 + i] = acc[i][j] + bias;
  }
}

// ---------------- LayerNorm over C, write both direction orderings (bf16) ----------------
__global__ void k_ln(const float* __restrict__ x, const float* nhw_, const float* nhb_,
                     const float* nvw_, const float* nvb_, bf16* __restrict__ xln){
  __shared__ float sx[128][57];
  __shared__ float smean[56], srstd[56];
  __shared__ float wh[128], bh[128], wv_[128], bv_[128];
  int h = blockIdx.x; int b = blockIdx.y;
  int tid = threadIdx.x;
  if (tid < 128){ wh[tid]=nhw_[tid]; bh[tid]=nhb_[tid];
                  wv_[tid]=nvw_[tid]; bv_[tid]=nvb_[tid]; }
  for (int idx = tid; idx < 128*56; idx += 256){
    int c = idx / 56, w = idx % 56;
    sx[c][w] = x[((size_t)(b*128+c))*LLEN + h*56 + w];
  }
  __syncthreads();
  if (tid < 56){
    float s=0.f, s2=0.f;
    for (int c=0;c<128;c++){ float v = sx[c][tid]; s+=v; s2+=v*v; }
    float m = s*(1.f/128.f);
    float var = s2*(1.f/128.f) - m*m;
    smean[tid]=m; srstd[tid]=rsqrtf(var+1e-5f);
  }
  __syncthreads();
  bf16* outh = xln;
  bf16* outv = xln + (size_t)BATCH*LLEN*128;
  for (int idx = tid; idx < 56*128; idx += 256){
    int w = idx >> 7, c = idx & 127;
    float v = (sx[c][w]-smean[w])*srstd[w];
    outh[((size_t)b*LLEN + h*56 + w)*128 + c] = f2b(v*wh[c]+bh[c]);
    outv[((size_t)b*LLEN + w*56 + h)*128 + c] = f2b(v*wv_[c]+bv_[c]);
  }
}

// ---------------- in_proj GEMM: 32x64 tiles, register-pipelined ----------------
__global__ void k_inproj(const bf16* __restrict__ xln, const float* __restrict__ hw,
                         const float* __restrict__ vw, bf16* __restrict__ XI, bf16* __restrict__ Z){
  int dir = blockIdx.z;
  const bf16* A = xln + (size_t)dir*BATCH*LLEN*128;
  const float* W = dir ? vw : hw;
  int m0 = blockIdx.x*32, n0 = blockIdx.y*64;
  __shared__ __align__(16) float As[16][36];
  __shared__ __align__(16) float Ws[16][68];
  int tid = threadIdx.x, tx = tid&15, ty = tid>>4;
  float acc[2][4] = {};
  float a_r[2], w_r[4];
  #pragma unroll
  for (int r=0;r<2;r++){ int idx = tid + r*256; a_r[r] = b2f(A[(size_t)(m0 + (idx>>4))*128 + (idx&15)]); }
  #pragma unroll
  for (int r=0;r<4;r++){ int idx = tid + r*256; w_r[r] = W[(size_t)(n0 + (idx>>4))*128 + (idx&15)]; }
  for (int k0=0;k0<128;k0+=16){
    __syncthreads();
    #pragma unroll
    for (int r=0;r<2;r++){ int idx = tid + r*256; As[idx&15][idx>>4] = a_r[r]; }
    #pragma unroll
    for (int r=0;r<4;r++){ int idx = tid + r*256; Ws[idx&15][idx>>4] = w_r[r]; }
    __syncthreads();
    if (k0 + 16 < 128){
      int kn = k0 + 16;
      #pragma unroll
      for (int r=0;r<2;r++){ int idx = tid + r*256; a_r[r] = b2f(A[(size_t)(m0 + (idx>>4))*128 + kn + (idx&15)]); }
      #pragma unroll
      for (int r=0;r<4;r++){ int idx = tid + r*256; w_r[r] = W[(size_t)(n0 + (idx>>4))*128 + kn + (idx&15)]; }
    }
    #pragma unroll
    for (int kk=0;kk<16;kk++){
      float2 av = *reinterpret_cast<const float2*>(&As[kk][ty*2]);
      float4 wv = *reinterpret_cast<const float4*>(&Ws[kk][tx*4]);
      float a2[2] = {av.x, av.y};
      float w4[4] = {wv.x, wv.y, wv.z, wv.w};
      #pragma unroll
      for (int i=0;i<2;i++)
        #pragma unroll
        for (int j=0;j<4;j++) acc[i][j] += a2[i]*w4[j];
    }
  }
  bf16* dst = (n0 < 256) ? XI : Z;
  int nbase = n0 & 255;
  size_t dslab = (size_t)dir*BATCH*LLEN*256;
  #pragma unroll
  for (int i=0;i<2;i++){
    int m = m0 + ty*2 + i;
    #pragma unroll
    for (int j=0;j<4;j++)
      dst[dslab + (size_t)m*256 + nbase + tx*4 + j] = f2b(acc[i][j]);
  }
}

// ---------------- causal depthwise conv1d(k=4) + silu; writes XS (row-major) + XS2 (scan layout) ----------------
__global__ void k_conv(const bf16* __restrict__ XI, const float* hw, const float* hb,
                       const float* vw, const float* vb, bf16* __restrict__ XS,
                       bf16* __restrict__ XS2){
  int dir = blockIdx.z;
  int b = blockIdx.y;
  int bd = dir*BATCH + b;
  int l0 = blockIdx.x * 32;
  const bf16* XId = XI + (size_t)bd*LLEN*256;
  bf16* XSd = XS + (size_t)bd*LLEN*256;
  const float* cw = dir ? vw : hw;
  const float* cb = dir ? vb : hb;
  __shared__ float sxi[35][256];
  int tid = threadIdx.x;
  for (int r = 0; r < 35; r++){
    int l = l0 - 3 + r;
    sxi[r][tid] = (l >= 0) ? b2f(XId[(size_t)l*256 + tid]) : 0.f;
  }
  __syncthreads();
  float w0=cw[tid*4], w1=cw[tid*4+1], w2=cw[tid*4+2], w3=cw[tid*4+3];
  float bias = cb[tid];
  size_t x2base = ((size_t)bd*16 + (tid>>4))*LLEN;
  int c16 = tid & 15;
  for (int ll=0; ll<32; ll++){
    float acc = bias + w0*sxi[ll][tid] + w1*sxi[ll+1][tid] + w2*sxi[ll+2][tid] + w3*sxi[ll+3][tid];
    float s = acc / (1.f + __expf(-acc));
    bf16 sv = f2b(s);
    XSd[(size_t)(l0+ll)*256 + tid] = sv;
    XS2[(x2base + l0 + ll)*16 + c16] = sv;
  }
}

// ---------------- xproj fused: DBL tile in LDS -> dt(softplus)->DT2, B/C extract ----------------
__global__ void k_dbl(const bf16* __restrict__ XS, const float* __restrict__ hx,
                      const float* __restrict__ vx,
                      const float* hdw, const float* vdw, const float* hdb, const float* vdb,
                      bf16* __restrict__ DT2, float* __restrict__ Bf, float* __restrict__ Cf){
  int m0 = blockIdx.x*64;                      // 196 tiles; tile never crosses bd boundary (3136%64==0)
  int bd = m0 / LLEN;
  int l0m = m0 % LLEN;
  int dirq = bd >> 1;
  const float* W = dirq ? vx : hx;
  __shared__ __align__(16) float As[16][68];
  __shared__ float Ws[16][42];
  __shared__ float sdbl[64][41];
  int tid = threadIdx.x;
  int tx = tid & 7, ty = tid >> 3;             // tx: 8 groups of 5 cols, ty: 32 groups of 2 rows
  float acc[2][5] = {};
  for (int k0=0;k0<256;k0+=16){
    __syncthreads();
    #pragma unroll
    for (int r=0;r<4;r++){
      int idx = tid + r*256;
      int row = idx >> 4, k = idx & 15;
      As[k][row] = b2f(XS[(size_t)(m0+row)*256 + k0 + k]);
    }
    #pragma unroll
    for (int r=0;r<3;r++){
      int idx = tid + r*256;
      if (idx < 640){
        int o = idx >> 4, k = idx & 15;
        Ws[k][o] = W[o*256 + k0 + k];
      }
    }
    __syncthreads();
    #pragma unroll
    for (int kk=0;kk<16;kk++){
      float a0 = As[kk][ty*2], a1 = As[kk][ty*2+1];
      #pragma unroll
      for (int j=0;j<5;j++){
        float wv = Ws[kk][tx*5+j];
        acc[0][j] += a0*wv;
        acc[1][j] += a1*wv;
      }
    }
  }
  #pragma unroll
  for (int i=0;i<2;i++)
    #pragma unroll
    for (int j=0;j<5;j++)
      sdbl[ty*2+i][tx*5+j] = acc[i][j];
  __syncthreads();
  // dt = softplus(dbl[:8] @ dtw^T + dtb) -> DT2 scan layout
  const float* dtw = dirq ? vdw : hdw;
  const float* dtb = dirq ? vdb : hdb;
  float w8[8];
  #pragma unroll
  for (int r=0;r<8;r++) w8[r] = dtw[tid*8+r];
  float biasv = dtb[tid];
  size_t d2base = ((size_t)bd*16 + (tid>>4))*LLEN + l0m;
  int c16 = tid & 15;
  for (int row=0; row<64; row++){
    float a = biasv;
    #pragma unroll
    for (int r=0;r<8;r++) a += sdbl[row][r]*w8[r];
    float sv = (a > 20.f) ? a : __logf(1.f + __expf(a));
    DT2[(d2base + row)*16 + c16] = f2b(sv);
  }
  // B, C extraction (row-major [global row][16])
  #pragma unroll
  for (int r=0;r<8;r++){
    int idx = tid + r*256;                     // 2048 = 64 rows * 32 vals
    int row = idx >> 5, o = idx & 31;
    float v = sdbl[row][8+o];
    size_t rr = (size_t)(m0+row)*16;
    if (o < 16) Bf[rr + o] = v;
    else        Cf[rr + (o-16)] = v;
  }
}

// ---------------- chunked selective scan: pass 1 (local scan, P & h_end) ----------------
__global__ void k_scan1(const bf16* __restrict__ DT2, const bf16* __restrict__ XS2,
                        const float* __restrict__ Bc, const float* hA, const float* vA,
                        float* __restrict__ Pbuf, float* __restrict__ Hbuf){
  int bd = blockIdx.z;           // dir*2+b
  int g  = blockIdx.y;           // channel group 0..15
  int ck = blockIdx.x;           // chunk 0..48
  int l0 = ck*LC;
  const float* Bd = Bc + (size_t)bd*LLEN*16;
  const float* Alog = (bd >> 1) ? vA : hA;
  int tid = threadIdx.x;
  int dl = tid >> 4, n = tid & 15;
  int d = g*16 + dl;
  float A = -__expf(Alog[d*16+n]);
  __shared__ float sdt[LC][16], sxs[LC][16], sB[LC][16];
  size_t base2 = (((size_t)bd*16 + g)*LLEN + l0)*16;
  #pragma unroll
  for (int r=0;r<4;r++){
    int idx = tid + r*256;
    sdt[idx>>4][idx&15] = b2f(DT2[base2 + idx]);
    sxs[idx>>4][idx&15] = b2f(XS2[base2 + idx]);
    (&sB[0][0])[idx] = Bd[(size_t)l0*16 + idx];
  }
  __syncthreads();
  float h = 0.f, P = 1.f;
  #pragma unroll 8
  for (int i=0;i<LC;i++){
    float a = sdt[i][dl];
    float u = sxs[i][dl];
    float dA = __expf(a * A);
    h = dA*h + (a*u)*sB[i][n];
    P *= dA;
  }
  size_t sidx = (((size_t)bd*16 + g)*NCHUNK + ck)*256 + tid;
  Pbuf[sidx] = P;
  Hbuf[sidx] = h;
}

// ---------------- pass 2: sequential combine over chunks (in-place h_end -> h_init) ----------------
__global__ void k_scan2(const float* __restrict__ Pbuf, float* __restrict__ Hbuf){
  int q = blockIdx.x;            // bd*16+g, 0..63
  int tid = threadIdx.x;
  float carry = 0.f;
  for (int k=0;k<NCHUNK;k++){
    size_t idx = ((size_t)q*NCHUNK + k)*256 + tid;
    float Pv = Pbuf[idx];
    float He = Hbuf[idx];
    Hbuf[idx] = carry;           // h_init for chunk k
    carry = Pv*carry + He;
  }
}

// ---------------- pass 3: local scan from h_init, subchunked LDS reduce, emit y ----------------
__global__ void k_scan3(const bf16* __restrict__ DT2, const bf16* __restrict__ XS2,
                        const float* __restrict__ Bc, const float* __restrict__ Cc,
                        const float* hA, const float* vA,
                        const float* __restrict__ Hbuf, bf16* __restrict__ ys){
  int bd = blockIdx.z;
  int g  = blockIdx.y;
  int ck = blockIdx.x;
  int l0 = ck*LC;
  const float* Bd = Bc + (size_t)bd*LLEN*16;
  const float* Cd = Cc + (size_t)bd*LLEN*16;
  bf16* yd = ys + (size_t)bd*LLEN*256;
  const float* Alog = (bd >> 1) ? vA : hA;
  int tid = threadIdx.x;
  int dl = tid >> 4, n = tid & 15;
  float A = -__expf(Alog[(g*16+dl)*16+n]);
  __shared__ float sdt[LC][16], sxs[LC][16], sB[LC][16], sC[LC][16];
  __shared__ __align__(16) float sp2[16][276];   // 17.7 KB; subchunk partial products
  size_t base2 = (((size_t)bd*16 + g)*LLEN + l0)*16;
  #pragma unroll
  for (int r=0;r<4;r++){
    int idx = tid + r*256;
    sdt[idx>>4][idx&15] = b2f(DT2[base2 + idx]);
    sxs[idx>>4][idx&15] = b2f(XS2[base2 + idx]);
    (&sB[0][0])[idx] = Bd[(size_t)l0*16 + idx];
    (&sC[0][0])[idx] = Cd[(size_t)l0*16 + idx];
  }
  size_t sidx = (((size_t)bd*16 + g)*NCHUNK + ck)*256 + tid;
  float h = Hbuf[sidx];
  __syncthreads();
  int i_local = tid >> 4;        // reduce-phase: step within subchunk
  int c16 = tid & 15;            // reduce-phase: channel-in-group
  for (int i0=0; i0<LC; i0+=16){
    #pragma unroll
    for (int ii=0;ii<16;ii++){
      int i = i0 + ii;
      float a = sdt[i][dl];
      float u = sxs[i][dl];
      float dA = __expf(a * A);
      h = dA*h + (a*u)*sB[i][n];
      sp2[ii][tid] = h * sC[i][n];
    }
    __syncthreads();
    const float* row = &sp2[i_local][c16*16];
    float s = 0.f;
    #pragma unroll
    for (int k=0;k<4;k++){
      float4 v = *reinterpret_cast<const float4*>(row + k*4);
      s += v.x + v.y + v.z + v.w;
    }
    yd[(size_t)(l0+i0+i_local)*256 + g*16 + c16] = f2b(s);
    __syncthreads();
  }
}

// ---------------- out_proj GEMM with fused YF = (ys + xs*D)*silu(z) on A-load ----------------
__global__ void k_outgemm(const bf16* __restrict__ ys, const bf16* __restrict__ xs,
                          const bf16* __restrict__ Z, const float* __restrict__ hD,
                          const float* __restrict__ vD, const float* __restrict__ how,
                          const float* __restrict__ vow, bf16* __restrict__ OD){
  int dir = blockIdx.z;
  size_t slab = (size_t)dir*BATCH*LLEN*256;
  const float* W = dir ? vow : how;
  const float* Dw = dir ? vD : hD;
  bf16* od = OD + (size_t)dir*BATCH*LLEN*128;
  int m0 = blockIdx.x*32, n0 = blockIdx.y*64;
  __shared__ __align__(16) float As[16][36];
  __shared__ __align__(16) float Ws[16][68];
  int tid = threadIdx.x, tx = tid&15, ty = tid>>4;
  int kme = tid & 15;
  float acc[2][4] = {};
  float a_r[2], w_r[4];
  {
    float Dv = Dw[kme];
    #pragma unroll
    for (int r=0;r<2;r++){
      int idx = tid + r*256;
      size_t e = slab + (size_t)(m0 + (idx>>4))*256 + (idx&15);
      float yv = b2f(ys[e]) + b2f(xs[e])*Dv;
      float zv = b2f(Z[e]);
      a_r[r] = yv * (zv/(1.f+__expf(-zv)));
    }
  }
  #pragma unroll
  for (int r=0;r<4;r++){ int idx = tid + r*256; w_r[r] = W[(size_t)(n0 + (idx>>4))*256 + (idx&15)]; }
  for (int k0=0;k0<256;k0+=16){
    __syncthreads();
    #pragma unroll
    for (int r=0;r<2;r++){ int idx = tid + r*256; As[idx&15][idx>>4] = a_r[r]; }
    #pragma unroll
    for (int r=0;r<4;r++){ int idx = tid + r*256; Ws[idx&15][idx>>4] = w_r[r]; }
    __syncthreads();
    if (k0 + 16 < 256){
      int kn = k0 + 16;
      float Dv = Dw[kn + kme];
      #pragma unroll
      for (int r=0;r<2;r++){
        int idx = tid + r*256;
        size_t e = slab + (size_t)(m0 + (idx>>4))*256 + kn + (idx&15);
        float yv = b2f(ys[e]) + b2f(xs[e])*Dv;
        float zv = b2f(Z[e]);
        a_r[r] = yv * (zv/(1.f+__expf(-zv)));
      }
      #pragma unroll
      for (int r=0;r<4;r++){ int idx = tid + r*256; w_r[r] = W[(size_t)(n0 + (idx>>4))*256 + kn + (idx&15)]; }
    }
    #pragma unroll
    for (int kk=0;kk<16;kk++){
      float2 av = *reinterpret_cast<const float2*>(&As[kk][ty*2]);
      float4 wv = *reinterpret_cast<const float4*>(&Ws[kk][tx*4]);
      float a2[2] = {av.x, av.y};
      float w4[4] = {wv.x, wv.y, wv.z, wv.w};
      #pragma unroll
      for (int i=0;i<2;i++)
        #pragma unroll
        for (int j=0;j<4;j++) acc[i][j] += a2[i]*w4[j];
    }
  }
  #pragma unroll
  for (int i=0;i<2;i++){
    int m = m0 + ty*2 + i;
    #pragma unroll
    for (int j=0;j<4;j++)
      od[(size_t)m*128 + n0 + tx*4 + j] = f2b(acc[i][j]);
  }
}

// ---------------- combine: fused += OH + OV^T; also emit per-(b,h,c) partial sums ----------------
__global__ void k_combine(const bf16* __restrict__ OD, float* __restrict__ fused,
                          float* __restrict__ BSUM){
  int h = blockIdx.x;            // 0..55
  int b = blockIdx.y;
  __shared__ float sfu[56][129];
  int tid = threadIdx.x;
  const bf16* od0 = OD + (size_t)b*LLEN*128;
  const bf16* od1 = OD + (size_t)(BATCH + b)*LLEN*128;
  #pragma unroll 4
  for (int it=0; it<28; it++){
    int idx = it*256 + tid;      // 0..7167
    int sp = idx >> 7, c = idx & 127;
    sfu[sp][c] = b2f(od0[(size_t)(h*56+sp)*128 + c]) + b2f(od1[(size_t)(sp*56+h)*128 + c]);
  }
  __syncthreads();
  int c = tid >> 1, half = tid & 1;
  float s = 0.f;
  size_t gbase = ((size_t)b*128 + c)*LLEN + h*56 + half*28;
  #pragma unroll
  for (int i=0;i<28;i++){
    float tot = fused[gbase+i] + sfu[half*28+i][c];
    fused[gbase+i] = tot;
    s += tot;
  }
  s += __shfl_xor(s, 1, 64);
  if (half == 0) BSUM[((size_t)b*56 + h)*128 + c] = s;
}

// ---------------- channel attention gate (reduces BSUM over h) ----------------
__global__ void k_gate(const float* __restrict__ BSUM, const float* fc1, const float* fc2,
                       float* __restrict__ gate){
  int b = blockIdx.x;
  __shared__ float ym[128], s1[32];
  int tid = threadIdx.x;         // 128 threads
  float s = 0.f;
  for (int h=0; h<56; h++) s += BSUM[((size_t)b*56 + h)*128 + tid];
  ym[tid] = s * (1.f/(float)LLEN);
  __syncthreads();
  if (tid < 32){
    float a = 0.f;
    for (int c=0;c<128;c++) a += ym[c]*fc1[tid*128+c];
    s1[tid] = fmaxf(a, 0.f);
  }
  __syncthreads();
  float a = 0.f;
  #pragma unroll
  for (int j=0;j<32;j++) a += s1[j]*fc2[tid*32+j];
  gate[b*128+tid] = 1.f/(1.f+__expf(-a));
}

// ---------------- final: out = fused * gate + x  (in-place over fused) ----------------
__global__ void k_final(float* __restrict__ fused, const float* __restrict__ gate,
                        const float* __restrict__ x, float* __restrict__ out){
  int i = blockIdx.x*256 + threadIdx.x;
  if (i >= BATCH*128*LLEN) return;
  int bc = i / LLEN;
  float v = fused[i]*gate[bc] + x[i];
  out[i] = v;
}

extern "C" void kernel_launch(void* const* d_in, const int* in_sizes, int n_in,
                              void* d_out, int out_size, void* d_ws, size_t ws_size,
                              hipStream_t stream) {
  const float* x      = (const float*)d_in[0];
  const float* nhw    = (const float*)d_in[1];
  const float* nhb    = (const float*)d_in[2];
  const float* nvw    = (const float*)d_in[3];
  const float* nvb    = (const float*)d_in[4];
  const float* dww    = (const float*)d_in[5];
  const float* dwb    = (const float*)d_in[6];
  const float* pww    = (const float*)d_in[7];
  const float* pwb    = (const float*)d_in[8];
  const float* h_inw  = (const float*)d_in[9];
  const float* h_cw   = (const float*)d_in[10];
  const float* h_cb   = (const float*)d_in[11];
  const float* h_xw   = (const float*)d_in[12];
  const float* h_dtw  = (const float*)d_in[13];
  const float* h_dtb  = (const float*)d_in[14];
  const float* h_Al   = (const float*)d_in[15];
  const float* h_D    = (const float*)d_in[16];
  const float* h_ow   = (const float*)d_in[17];
  const float* v_inw  = (const float*)d_in[18];
  const float* v_cw   = (const float*)d_in[19];
  const float* v_cb   = (const float*)d_in[20];
  const float* v_xw   = (const float*)d_in[21];
  const float* v_dtw  = (const float*)d_in[22];
  const float* v_dtb  = (const float*)d_in[23];
  const float* v_Al   = (const float*)d_in[24];
  const float* v_D    = (const float*)d_in[25];
  const float* v_ow   = (const float*)d_in[26];
  const float* fc1    = (const float*)d_in[27];
  const float* fc2    = (const float*)d_in[28];

  float* FUSED = (float*)d_out;   // FUSED lives in d_out; k_final is in-place elementwise
  float* out   = (float*)d_out;

  // Workspace layout (bytes), high-water ~37 MB. Stream-ordered-safe aliases:
  //  DT2 overlays TMP+XLN (both dead after k_inproj); OD overlays DT2 (dead after k_scan3)
  //  YS overlays XI (dead after k_conv);  Pbuf overlays YS head (dead before k_scan3 writes)
  char* base = (char*)d_ws;
  bf16*  TMP   = (bf16*)(base + 0);           // 1,605,632 B
  bf16*  XLN   = (bf16*)(base + 1605632);     // 3,211,264 B
  bf16*  DT2   = (bf16*)(base + 0);           // 6,422,528 B  [alias TMP+XLN; scan layout]
  bf16*  OD    = (bf16*)(base + 0);           // 3,211,264 B  [alias DT2; live after k_scan3]
  bf16*  XI    = (bf16*)(base + 6422528);     // 6,422,528 B
  bf16*  YS    = (bf16*)(base + 6422528);     // 6,422,528 B  [alias XI]
  float* Pbuf  = (float*)(base + 6422528);    // 3,211,264 B  [alias XI/YS head]
  bf16*  Z     = (bf16*)(base + 12845056);    // 6,422,528 B
  bf16*  XS    = (bf16*)(base + 19267584);    // 6,422,528 B
  float* Bf    = (float*)(base + 25690112);   //   802,816 B
  float* Cf    = (float*)(base + 26492928);   //   802,816 B
  float* Hbuf  = (float*)(base + 27295744);   // 3,211,264 B
  float* BSUM  = (float*)(base + 30507008);   //    57,344 B
  float* GATE  = (float*)(base + 30564352);   //     1,024 B
  bf16*  XS2   = (bf16*)(base + 30565376);    // 6,422,528 B  [scan layout copy of XS]

  k_dwconv_gelu<<<dim3(BATCH*128), dim3(256), 0, stream>>>(x, dww, dwb, TMP);
  k_pw_gemm<<<dim3(98,2,BATCH), dim3(256), 0, stream>>>(TMP, pww, pwb, FUSED);
  k_ln<<<dim3(56,BATCH), dim3(256), 0, stream>>>(x, nhw, nhb, nvw, nvb, XLN);
  k_inproj<<<dim3(196,8,2), dim3(256), 0, stream>>>(XLN, h_inw, v_inw, XI, Z);
  k_conv<<<dim3(98,BATCH,2), dim3(256), 0, stream>>>(XI, h_cw, h_cb, v_cw, v_cb, XS, XS2);
  k_dbl<<<dim3(196), dim3(256), 0, stream>>>(XS, h_xw, v_xw, h_dtw, v_dtw, h_dtb, v_dtb,
                                             DT2, Bf, Cf);
  k_scan1<<<dim3(NCHUNK,16,4), dim3(256), 0, stream>>>(DT2, XS2, Bf, h_Al, v_Al, Pbuf, Hbuf);
  k_scan2<<<dim3(64), dim3(256), 0, stream>>>(Pbuf, Hbuf);
  k_scan3<<<dim3(NCHUNK,16,4), dim3(256), 0, stream>>>(DT2, XS2, Bf, Cf, h_Al, v_Al, Hbuf, YS);
  k_outgemm<<<dim3(196,2,2), dim3(256), 0, stream>>>(YS, XS, Z, h_D, v_D, h_ow, v_ow, OD);
  k_combine<<<dim3(56,BATCH), dim3(256), 0, stream>>>(OD, FUSED, BSUM);
  k_gate<<<dim3(BATCH), dim3(128), 0, stream>>>(BSUM, fc1, fc2, GATE);
  k_final<<<dim3((BATCH*128*LLEN+255)/256), dim3(256), 0, stream>>>(FUSED, GATE, x, out);
}

// Round 11
// 279.337 us; speedup vs baseline: 1.8609x; 1.1316x over previous
//
#include <hip/hip_runtime.h>
#include <hip/hip_bf16.h>

typedef __hip_bfloat16 bf16;
__device__ __forceinline__ float b2f(bf16 v){ return __bfloat162float(v); }
__device__ __forceinline__ bf16 f2b(float v){ return __float2bfloat16(v); }

typedef __attribute__((ext_vector_type(8))) short frag_ab;   // 8 bf16 (4 VGPRs)
typedef __attribute__((ext_vector_type(4))) float frag_cd;   // 4 fp32 acc

#define LLEN 3136
#define BATCH 2
#define NCHUNK 49
#define LC 64

// ---------------- dwconv 3x3 + gelu ----------------
__global__ void k_dwconv_gelu(const float* __restrict__ x, const float* __restrict__ dww,
                              const float* __restrict__ dwb, bf16* __restrict__ tmp){
  int bc = blockIdx.x;            // b*128 + c
  int c = bc & 127;
  const float* xp = x + (size_t)bc*LLEN;
  float w[9];
  #pragma unroll
  for (int i=0;i<9;i++) w[i] = dww[c*9+i];
  float bias = dwb[c];
  for (int p = threadIdx.x; p < LLEN; p += blockDim.x){
    int i = p/56, j = p%56;
    float acc = bias;
    #pragma unroll
    for (int a=0;a<3;a++){
      int ii = i + a - 1;
      if (ii < 0 || ii >= 56) continue;
      #pragma unroll
      for (int bb=0;bb<3;bb++){
        int jj = j + bb - 1;
        if (jj < 0 || jj >= 56) continue;
        acc += w[a*3+bb] * xp[ii*56+jj];
      }
    }
    float g = 0.5f*acc*(1.0f + erff(acc*0.70710678118654752f));
    tmp[(size_t)bc*LLEN + p] = f2b(g);
  }
}

// ---------------- pointwise conv GEMM: 32x64 tiles, register-pipelined ----------------
__global__ void k_pw_gemm(const bf16* __restrict__ tmp, const float* __restrict__ pww,
                          const float* __restrict__ pwb, float* __restrict__ fused){
  int b = blockIdx.z;
  int p0 = blockIdx.x * 32;
  int n0 = blockIdx.y * 64;
  const bf16* A = tmp + (size_t)b*128*LLEN;
  __shared__ __align__(16) float As[16][36];
  __shared__ __align__(16) float Ws[16][68];
  int tid = threadIdx.x, tx = tid & 15, ty = tid >> 4;
  float acc[2][4] = {};
  float a_r[2], w_r[4];
  #pragma unroll
  for (int r=0;r<2;r++){ int idx = tid + r*256; a_r[r] = b2f(A[(size_t)(idx>>5)*LLEN + p0 + (idx&31)]); }
  #pragma unroll
  for (int r=0;r<4;r++){ int idx = tid + r*256; w_r[r] = pww[(n0 + (idx>>4))*128 + (idx&15)]; }
  for (int k0 = 0; k0 < 128; k0 += 16){
    __syncthreads();
    #pragma unroll
    for (int r=0;r<2;r++){ int idx = tid + r*256; As[idx>>5][idx&31] = a_r[r]; }
    #pragma unroll
    for (int r=0;r<4;r++){ int idx = tid + r*256; Ws[idx&15][idx>>4] = w_r[r]; }
    __syncthreads();
    if (k0 + 16 < 128){
      int kn = k0 + 16;
      #pragma unroll
      for (int r=0;r<2;r++){ int idx = tid + r*256; a_r[r] = b2f(A[(size_t)(kn + (idx>>5))*LLEN + p0 + (idx&31)]); }
      #pragma unroll
      for (int r=0;r<4;r++){ int idx = tid + r*256; w_r[r] = pww[(n0 + (idx>>4))*128 + kn + (idx&15)]; }
    }
    #pragma unroll
    for (int kk=0;kk<16;kk++){
      float2 av = *reinterpret_cast<const float2*>(&As[kk][ty*2]);
      float4 wv = *reinterpret_cast<const float4*>(&Ws[kk][tx*4]);
      float a2[2] = {av.x, av.y};
      float w4[4] = {wv.x, wv.y, wv.z, wv.w};
      #pragma unroll
      for (int i=0;i<2;i++)
        #pragma unroll
        for (int j=0;j<4;j++) acc[i][j] += a2[i]*w4[j];
    }
  }
  #pragma unroll
  for (int j=0;j<4;j++){
    int n = n0 + tx*4 + j;
    float bias = pwb[n];
    #pragma unroll
    for (int i=0;i<2;i++)
      fused[((size_t)b*128 + n)*LLEN + p0 + ty*2 + i] = acc[i][j] + bias;
  }
}

// ---------------- LayerNorm over C, write both direction orderings (bf16) ----------------
__global__ void k_ln(const float* __restrict__ x, const float* nhw_, const float* nhb_,
                     const float* nvw_, const float* nvb_, bf16* __restrict__ xln){
  __shared__ float sx[128][57];
  __shared__ float smean[56], srstd[56];
  __shared__ float wh[128], bh[128], wv_[128], bv_[128];
  int h = blockIdx.x; int b = blockIdx.y;
  int tid = threadIdx.x;
  if (tid < 128){ wh[tid]=nhw_[tid]; bh[tid]=nhb_[tid];
                  wv_[tid]=nvw_[tid]; bv_[tid]=nvb_[tid]; }
  for (int idx = tid; idx < 128*56; idx += 256){
    int c = idx / 56, w = idx % 56;
    sx[c][w] = x[((size_t)(b*128+c))*LLEN + h*56 + w];
  }
  __syncthreads();
  if (tid < 56){
    float s=0.f, s2=0.f;
    for (int c=0;c<128;c++){ float v = sx[c][tid]; s+=v; s2+=v*v; }
    float m = s*(1.f/128.f);
    float var = s2*(1.f/128.f) - m*m;
    smean[tid]=m; srstd[tid]=rsqrtf(var+1e-5f);
  }
  __syncthreads();
  bf16* outh = xln;
  bf16* outv = xln + (size_t)BATCH*LLEN*128;
  for (int idx = tid; idx < 56*128; idx += 256){
    int w = idx >> 7, c = idx & 127;
    float v = (sx[c][w]-smean[w])*srstd[w];
    outh[((size_t)b*LLEN + h*56 + w)*128 + c] = f2b(v*wh[c]+bh[c]);
    outv[((size_t)b*LLEN + w*56 + h)*128 + c] = f2b(v*wv_[c]+bv_[c]);
  }
}

// ---------------- in_proj GEMM (MFMA bf16): 64x64 tile, K=128 fully LDS-resident ----------------
__global__ void k_inproj(const bf16* __restrict__ xln, const float* __restrict__ hw,
                         const float* __restrict__ vw, bf16* __restrict__ XI, bf16* __restrict__ Z){
  int dir = blockIdx.z;
  const bf16* A = xln + (size_t)dir*BATCH*LLEN*128;
  const float* W = dir ? vw : hw;
  int m0 = blockIdx.x*64, n0 = blockIdx.y*64;
  __shared__ __align__(16) bf16 sA[64][136];
  __shared__ __align__(16) bf16 sW[64][136];
  int tid = threadIdx.x;
  // stage A: 64 rows x 128 bf16 (16B chunks)
  #pragma unroll
  for (int r=0;r<4;r++){
    int idx = tid + r*256;
    int row = idx >> 4, c8 = (idx & 15)*8;
    *reinterpret_cast<float4*>(&sA[row][c8]) =
        *reinterpret_cast<const float4*>(&A[(size_t)(m0+row)*128 + c8]);
  }
  // stage W: 64 rows x 128 fp32 -> bf16
  #pragma unroll
  for (int r=0;r<8;r++){
    int idx = tid + r*256;
    int row = idx >> 5, c4 = (idx & 31)*4;
    float4 w4 = *reinterpret_cast<const float4*>(&W[(size_t)(n0+row)*128 + c4]);
    bf16 t4[4] = {f2b(w4.x), f2b(w4.y), f2b(w4.z), f2b(w4.w)};
    *reinterpret_cast<double*>(&sW[row][c4]) = *reinterpret_cast<double*>(t4);
  }
  __syncthreads();
  int wv2 = tid >> 6, lane = tid & 63;
  int qd = lane >> 4, mr = lane & 15;
  frag_cd acc[4] = {};
  #pragma unroll
  for (int k0=0;k0<128;k0+=32){
    frag_ab af = *reinterpret_cast<frag_ab*>(&sA[wv2*16+mr][k0+qd*8]);
    #pragma unroll
    for (int t=0;t<4;t++){
      frag_ab bfr = *reinterpret_cast<frag_ab*>(&sW[t*16+mr][k0+qd*8]);
      acc[t] = __builtin_amdgcn_mfma_f32_16x16x32_bf16(af, bfr, acc[t], 0, 0, 0);
    }
  }
  bf16* dst = (n0 < 256) ? XI : Z;
  int nb = n0 & 255;
  size_t dslab = (size_t)dir*BATCH*LLEN*256;
  #pragma unroll
  for (int t=0;t<4;t++)
    #pragma unroll
    for (int r=0;r<4;r++){
      int row = m0 + wv2*16 + qd*4 + r;
      int col = nb + t*16 + mr;
      dst[dslab + (size_t)row*256 + col] = f2b(acc[t][r]);
    }
}

// ---------------- causal depthwise conv1d(k=4) + silu; writes XS (row-major) + XS2 (scan layout) ----------------
__global__ void k_conv(const bf16* __restrict__ XI, const float* hw, const float* hb,
                       const float* vw, const float* vb, bf16* __restrict__ XS,
                       bf16* __restrict__ XS2){
  int dir = blockIdx.z;
  int b = blockIdx.y;
  int bd = dir*BATCH + b;
  int l0 = blockIdx.x * 32;
  const bf16* XId = XI + (size_t)bd*LLEN*256;
  bf16* XSd = XS + (size_t)bd*LLEN*256;
  const float* cw = dir ? vw : hw;
  const float* cb = dir ? vb : hb;
  __shared__ float sxi[35][256];
  int tid = threadIdx.x;
  for (int r = 0; r < 35; r++){
    int l = l0 - 3 + r;
    sxi[r][tid] = (l >= 0) ? b2f(XId[(size_t)l*256 + tid]) : 0.f;
  }
  __syncthreads();
  float w0=cw[tid*4], w1=cw[tid*4+1], w2=cw[tid*4+2], w3=cw[tid*4+3];
  float bias = cb[tid];
  size_t x2base = ((size_t)bd*16 + (tid>>4))*LLEN;
  int c16 = tid & 15;
  for (int ll=0; ll<32; ll++){
    float acc = bias + w0*sxi[ll][tid] + w1*sxi[ll+1][tid] + w2*sxi[ll+2][tid] + w3*sxi[ll+3][tid];
    float s = acc / (1.f + __expf(-acc));
    bf16 sv = f2b(s);
    XSd[(size_t)(l0+ll)*256 + tid] = sv;
    XS2[(x2base + l0 + ll)*16 + c16] = sv;
  }
}

// ---------------- xproj fused: DBL tile in LDS -> dt(softplus)->DT2, B/C extract ----------------
__global__ void k_dbl(const bf16* __restrict__ XS, const float* __restrict__ hx,
                      const float* __restrict__ vx,
                      const float* hdw, const float* vdw, const float* hdb, const float* vdb,
                      bf16* __restrict__ DT2, float* __restrict__ Bf, float* __restrict__ Cf){
  int m0 = blockIdx.x*64;                      // 196 tiles; tile never crosses bd boundary (3136%64==0)
  int bd = m0 / LLEN;
  int l0m = m0 % LLEN;
  int dirq = bd >> 1;
  const float* W = dirq ? vx : hx;
  __shared__ __align__(16) float As[16][68];
  __shared__ float Ws[16][42];
  __shared__ float sdbl[64][41];
  int tid = threadIdx.x;
  int tx = tid & 7, ty = tid >> 3;             // tx: 8 groups of 5 cols, ty: 32 groups of 2 rows
  float acc[2][5] = {};
  for (int k0=0;k0<256;k0+=16){
    __syncthreads();
    #pragma unroll
    for (int r=0;r<4;r++){
      int idx = tid + r*256;
      int row = idx >> 4, k = idx & 15;
      As[k][row] = b2f(XS[(size_t)(m0+row)*256 + k0 + k]);
    }
    #pragma unroll
    for (int r=0;r<3;r++){
      int idx = tid + r*256;
      if (idx < 640){
        int o = idx >> 4, k = idx & 15;
        Ws[k][o] = W[o*256 + k0 + k];
      }
    }
    __syncthreads();
    #pragma unroll
    for (int kk=0;kk<16;kk++){
      float a0 = As[kk][ty*2], a1 = As[kk][ty*2+1];
      #pragma unroll
      for (int j=0;j<5;j++){
        float wv = Ws[kk][tx*5+j];
        acc[0][j] += a0*wv;
        acc[1][j] += a1*wv;
      }
    }
  }
  #pragma unroll
  for (int i=0;i<2;i++)
    #pragma unroll
    for (int j=0;j<5;j++)
      sdbl[ty*2+i][tx*5+j] = acc[i][j];
  __syncthreads();
  const float* dtw = dirq ? vdw : hdw;
  const float* dtb = dirq ? vdb : hdb;
  float w8[8];
  #pragma unroll
  for (int r=0;r<8;r++) w8[r] = dtw[tid*8+r];
  float biasv = dtb[tid];
  size_t d2base = ((size_t)bd*16 + (tid>>4))*LLEN + l0m;
  int c16 = tid & 15;
  for (int row=0; row<64; row++){
    float a = biasv;
    #pragma unroll
    for (int r=0;r<8;r++) a += sdbl[row][r]*w8[r];
    float sv = (a > 20.f) ? a : __logf(1.f + __expf(a));
    DT2[(d2base + row)*16 + c16] = f2b(sv);
  }
  #pragma unroll
  for (int r=0;r<8;r++){
    int idx = tid + r*256;                     // 2048 = 64 rows * 32 vals
    int row = idx >> 5, o = idx & 31;
    float v = sdbl[row][8+o];
    size_t rr = (size_t)(m0+row)*16;
    if (o < 16) Bf[rr + o] = v;
    else        Cf[rr + (o-16)] = v;
  }
}

// ---------------- chunked selective scan: pass 1 (local scan, P & h_end) ----------------
__global__ void k_scan1(const bf16* __restrict__ DT2, const bf16* __restrict__ XS2,
                        const float* __restrict__ Bc, const float* hA, const float* vA,
                        float* __restrict__ Pbuf, float* __restrict__ Hbuf){
  int bd = blockIdx.z;           // dir*2+b
  int g  = blockIdx.y;           // channel group 0..15
  int ck = blockIdx.x;           // chunk 0..48
  int l0 = ck*LC;
  const float* Bd = Bc + (size_t)bd*LLEN*16;
  const float* Alog = (bd >> 1) ? vA : hA;
  int tid = threadIdx.x;
  int dl = tid >> 4, n = tid & 15;
  int d = g*16 + dl;
  float A = -__expf(Alog[d*16+n]);
  __shared__ float sdt[LC][16], sxs[LC][16], sB[LC][16];
  size_t base2 = (((size_t)bd*16 + g)*LLEN + l0)*16;
  #pragma unroll
  for (int r=0;r<4;r++){
    int idx = tid + r*256;
    sdt[idx>>4][idx&15] = b2f(DT2[base2 + idx]);
    sxs[idx>>4][idx&15] = b2f(XS2[base2 + idx]);
    (&sB[0][0])[idx] = Bd[(size_t)l0*16 + idx];
  }
  __syncthreads();
  float h = 0.f, P = 1.f;
  #pragma unroll 8
  for (int i=0;i<LC;i++){
    float a = sdt[i][dl];
    float u = sxs[i][dl];
    float dA = __expf(a * A);
    h = dA*h + (a*u)*sB[i][n];
    P *= dA;
  }
  size_t sidx = (((size_t)bd*16 + g)*NCHUNK + ck)*256 + tid;
  Pbuf[sidx] = P;
  Hbuf[sidx] = h;
}

// ---------------- pass 2: sequential combine over chunks (in-place h_end -> h_init) ----------------
__global__ void k_scan2(const float* __restrict__ Pbuf, float* __restrict__ Hbuf){
  int q = blockIdx.x;            // bd*16+g, 0..63
  int tid = threadIdx.x;
  float carry = 0.f;
  for (int k=0;k<NCHUNK;k++){
    size_t idx = ((size_t)q*NCHUNK + k)*256 + tid;
    float Pv = Pbuf[idx];
    float He = Hbuf[idx];
    Hbuf[idx] = carry;           // h_init for chunk k
    carry = Pv*carry + He;
  }
}

// ---------------- pass 3: local scan from h_init, subchunked LDS reduce, emit y ----------------
__global__ void k_scan3(const bf16* __restrict__ DT2, const bf16* __restrict__ XS2,
                        const float* __restrict__ Bc, const float* __restrict__ Cc,
                        const float* hA, const float* vA,
                        const float* __restrict__ Hbuf, bf16* __restrict__ ys){
  int bd = blockIdx.z;
  int g  = blockIdx.y;
  int ck = blockIdx.x;
  int l0 = ck*LC;
  const float* Bd = Bc + (size_t)bd*LLEN*16;
  const float* Cd = Cc + (size_t)bd*LLEN*16;
  bf16* yd = ys + (size_t)bd*LLEN*256;
  const float* Alog = (bd >> 1) ? vA : hA;
  int tid = threadIdx.x;
  int dl = tid >> 4, n = tid & 15;
  float A = -__expf(Alog[(g*16+dl)*16+n]);
  __shared__ float sdt[LC][16], sxs[LC][16], sB[LC][16], sC[LC][16];
  __shared__ __align__(16) float sp2[16][276];   // 17.7 KB; subchunk partial products
  size_t base2 = (((size_t)bd*16 + g)*LLEN + l0)*16;
  #pragma unroll
  for (int r=0;r<4;r++){
    int idx = tid + r*256;
    sdt[idx>>4][idx&15] = b2f(DT2[base2 + idx]);
    sxs[idx>>4][idx&15] = b2f(XS2[base2 + idx]);
    (&sB[0][0])[idx] = Bd[(size_t)l0*16 + idx];
    (&sC[0][0])[idx] = Cd[(size_t)l0*16 + idx];
  }
  size_t sidx = (((size_t)bd*16 + g)*NCHUNK + ck)*256 + tid;
  float h = Hbuf[sidx];
  __syncthreads();
  int i_local = tid >> 4;        // reduce-phase: step within subchunk
  int c16 = tid & 15;            // reduce-phase: channel-in-group
  for (int i0=0; i0<LC; i0+=16){
    #pragma unroll
    for (int ii=0;ii<16;ii++){
      int i = i0 + ii;
      float a = sdt[i][dl];
      float u = sxs[i][dl];
      float dA = __expf(a * A);
      h = dA*h + (a*u)*sB[i][n];
      sp2[ii][tid] = h * sC[i][n];
    }
    __syncthreads();
    const float* row = &sp2[i_local][c16*16];
    float s = 0.f;
    #pragma unroll
    for (int k=0;k<4;k++){
      float4 v = *reinterpret_cast<const float4*>(row + k*4);
      s += v.x + v.y + v.z + v.w;
    }
    yd[(size_t)(l0+i0+i_local)*256 + g*16 + c16] = f2b(s);
    __syncthreads();
  }
}

// ---------------- out_proj GEMM (MFMA bf16) with fused YF = (ys+xs*D)*silu(z) at A-staging ----------------
__global__ void k_outgemm(const bf16* __restrict__ ys, const bf16* __restrict__ xs,
                          const bf16* __restrict__ Z, const float* __restrict__ hD,
                          const float* __restrict__ vD, const float* __restrict__ how,
                          const float* __restrict__ vow, bf16* __restrict__ OD){
  int dir = blockIdx.z;
  size_t slab = (size_t)dir*BATCH*LLEN*256;
  const float* W = dir ? vow : how;
  const float* Dw = dir ? vD : hD;
  bf16* od = OD + (size_t)dir*BATCH*LLEN*128;
  int m0 = blockIdx.x*64, n0 = blockIdx.y*64;
  __shared__ __align__(16) bf16 sA[64][136];
  __shared__ __align__(16) bf16 sW[64][136];
  int tid = threadIdx.x;
  int wv2 = tid >> 6, lane = tid & 63;
  int qd = lane >> 4, mr = lane & 15;
  frag_cd acc[4] = {};
  for (int kc=0; kc<256; kc+=128){
    __syncthreads();
    // stage A = YF for k-cols kc..kc+127
    #pragma unroll
    for (int r=0;r<4;r++){
      int idx = tid + r*256;
      int row = idx >> 4, c8 = (idx & 15)*8;
      size_t e = slab + (size_t)(m0+row)*256 + kc + c8;
      bf16 yb[8], xb[8], zb[8], ob[8];
      *reinterpret_cast<float4*>(yb) = *reinterpret_cast<const float4*>(&ys[e]);
      *reinterpret_cast<float4*>(xb) = *reinterpret_cast<const float4*>(&xs[e]);
      *reinterpret_cast<float4*>(zb) = *reinterpret_cast<const float4*>(&Z[e]);
      #pragma unroll
      for (int j=0;j<8;j++){
        float Dv = Dw[kc + c8 + j];
        float yv = b2f(yb[j]) + b2f(xb[j])*Dv;
        float zv = b2f(zb[j]);
        ob[j] = f2b(yv * (zv/(1.f+__expf(-zv))));
      }
      *reinterpret_cast<float4*>(&sA[row][c8]) = *reinterpret_cast<float4*>(ob);
    }
    // stage W rows n0..n0+63, k-cols kc..kc+127 (fp32 -> bf16)
    #pragma unroll
    for (int r=0;r<8;r++){
      int idx = tid + r*256;
      int row = idx >> 5, c4 = (idx & 31)*4;
      float4 w4 = *reinterpret_cast<const float4*>(&W[(size_t)(n0+row)*256 + kc + c4]);
      bf16 t4[4] = {f2b(w4.x), f2b(w4.y), f2b(w4.z), f2b(w4.w)};
      *reinterpret_cast<double*>(&sW[row][c4]) = *reinterpret_cast<double*>(t4);
    }
    __syncthreads();
    #pragma unroll
    for (int k0=0;k0<128;k0+=32){
      frag_ab af = *reinterpret_cast<frag_ab*>(&sA[wv2*16+mr][k0+qd*8]);
      #pragma unroll
      for (int t=0;t<4;t++){
        frag_ab bfr = *reinterpret_cast<frag_ab*>(&sW[t*16+mr][k0+qd*8]);
        acc[t] = __builtin_amdgcn_mfma_f32_16x16x32_bf16(af, bfr, acc[t], 0, 0, 0);
      }
    }
  }
  #pragma unroll
  for (int t=0;t<4;t++)
    #pragma unroll
    for (int r=0;r<4;r++){
      int row = m0 + wv2*16 + qd*4 + r;
      int col = n0 + t*16 + mr;
      od[(size_t)row*128 + col] = f2b(acc[t][r]);
    }
}

// ---------------- combine: fused += OH + OV^T; also emit per-(b,h,c) partial sums ----------------
__global__ void k_combine(const bf16* __restrict__ OD, float* __restrict__ fused,
                          float* __restrict__ BSUM){
  int h = blockIdx.x;            // 0..55
  int b = blockIdx.y;
  __shared__ float sfu[56][129];
  int tid = threadIdx.x;
  const bf16* od0 = OD + (size_t)b*LLEN*128;
  const bf16* od1 = OD + (size_t)(BATCH + b)*LLEN*128;
  #pragma unroll 4
  for (int it=0; it<28; it++){
    int idx = it*256 + tid;      // 0..7167
    int sp = idx >> 7, c = idx & 127;
    sfu[sp][c] = b2f(od0[(size_t)(h*56+sp)*128 + c]) + b2f(od1[(size_t)(sp*56+h)*128 + c]);
  }
  __syncthreads();
  int c = tid >> 1, half = tid & 1;
  float s = 0.f;
  size_t gbase = ((size_t)b*128 + c)*LLEN + h*56 + half*28;
  #pragma unroll
  for (int i=0;i<28;i++){
    float tot = fused[gbase+i] + sfu[half*28+i][c];
    fused[gbase+i] = tot;
    s += tot;
  }
  s += __shfl_xor(s, 1, 64);
  if (half == 0) BSUM[((size_t)b*56 + h)*128 + c] = s;
}

// ---------------- channel attention gate (reduces BSUM over h) ----------------
__global__ void k_gate(const float* __restrict__ BSUM, const float* fc1, const float* fc2,
                       float* __restrict__ gate){
  int b = blockIdx.x;
  __shared__ float ym[128], s1[32];
  int tid = threadIdx.x;         // 128 threads
  float s = 0.f;
  for (int h=0; h<56; h++) s += BSUM[((size_t)b*56 + h)*128 + tid];
  ym[tid] = s * (1.f/(float)LLEN);
  __syncthreads();
  if (tid < 32){
    float a = 0.f;
    for (int c=0;c<128;c++) a += ym[c]*fc1[tid*128+c];
    s1[tid] = fmaxf(a, 0.f);
  }
  __syncthreads();
  float a = 0.f;
  #pragma unroll
  for (int j=0;j<32;j++) a += s1[j]*fc2[tid*32+j];
  gate[b*128+tid] = 1.f/(1.f+__expf(-a));
}

// ---------------- final: out = fused * gate + x  (in-place over fused) ----------------
__global__ void k_final(float* __restrict__ fused, const float* __restrict__ gate,
                        const float* __restrict__ x, float* __restrict__ out){
  int i = blockIdx.x*256 + threadIdx.x;
  if (i >= BATCH*128*LLEN) return;
  int bc = i / LLEN;
  float v = fused[i]*gate[bc] + x[i];
  out[i] = v;
}

extern "C" void kernel_launch(void* const* d_in, const int* in_sizes, int n_in,
                              void* d_out, int out_size, void* d_ws, size_t ws_size,
                              hipStream_t stream) {
  const float* x      = (const float*)d_in[0];
  const float* nhw    = (const float*)d_in[1];
  const float* nhb    = (const float*)d_in[2];
  const float* nvw    = (const float*)d_in[3];
  const float* nvb    = (const float*)d_in[4];
  const float* dww    = (const float*)d_in[5];
  const float* dwb    = (const float*)d_in[6];
  const float* pww    = (const float*)d_in[7];
  const float* pwb    = (const float*)d_in[8];
  const float* h_inw  = (const float*)d_in[9];
  const float* h_cw   = (const float*)d_in[10];
  const float* h_cb   = (const float*)d_in[11];
  const float* h_xw   = (const float*)d_in[12];
  const float* h_dtw  = (const float*)d_in[13];
  const float* h_dtb  = (const float*)d_in[14];
  const float* h_Al   = (const float*)d_in[15];
  const float* h_D    = (const float*)d_in[16];
  const float* h_ow   = (const float*)d_in[17];
  const float* v_inw  = (const float*)d_in[18];
  const float* v_cw   = (const float*)d_in[19];
  const float* v_cb   = (const float*)d_in[20];
  const float* v_xw   = (const float*)d_in[21];
  const float* v_dtw  = (const float*)d_in[22];
  const float* v_dtb  = (const float*)d_in[23];
  const float* v_Al   = (const float*)d_in[24];
  const float* v_D    = (const float*)d_in[25];
  const float* v_ow   = (const float*)d_in[26];
  const float* fc1    = (const float*)d_in[27];
  const float* fc2    = (const float*)d_in[28];

  float* FUSED = (float*)d_out;   // FUSED lives in d_out; k_final is in-place elementwise
  float* out   = (float*)d_out;

  // Workspace layout (bytes), high-water ~37 MB. Stream-ordered-safe aliases:
  //  DT2 overlays TMP+XLN (both dead after k_inproj); OD overlays DT2 (dead after k_scan3)
  //  YS overlays XI (dead after k_conv);  Pbuf overlays YS head (dead before k_scan3 writes)
  char* base = (char*)d_ws;
  bf16*  TMP   = (bf16*)(base + 0);           // 1,605,632 B
  bf16*  XLN   = (bf16*)(base + 1605632);     // 3,211,264 B
  bf16*  DT2   = (bf16*)(base + 0);           // 6,422,528 B  [alias TMP+XLN; scan layout]
  bf16*  OD    = (bf16*)(base + 0);           // 3,211,264 B  [alias DT2; live after k_scan3]
  bf16*  XI    = (bf16*)(base + 6422528);     // 6,422,528 B
  bf16*  YS    = (bf16*)(base + 6422528);     // 6,422,528 B  [alias XI]
  float* Pbuf  = (float*)(base + 6422528);    // 3,211,264 B  [alias XI/YS head]
  bf16*  Z     = (bf16*)(base + 12845056);    // 6,422,528 B
  bf16*  XS    = (bf16*)(base + 19267584);    // 6,422,528 B
  float* Bf    = (float*)(base + 25690112);   //   802,816 B
  float* Cf    = (float*)(base + 26492928);   //   802,816 B
  float* Hbuf  = (float*)(base + 27295744);   // 3,211,264 B
  float* BSUM  = (float*)(base + 30507008);   //    57,344 B
  float* GATE  = (float*)(base + 30564352);   //     1,024 B
  bf16*  XS2   = (bf16*)(base + 30565376);    // 6,422,528 B  [scan layout copy of XS]

  k_dwconv_gelu<<<dim3(BATCH*128), dim3(256), 0, stream>>>(x, dww, dwb, TMP);
  k_pw_gemm<<<dim3(98,2,BATCH), dim3(256), 0, stream>>>(TMP, pww, pwb, FUSED);
  k_ln<<<dim3(56,BATCH), dim3(256), 0, stream>>>(x, nhw, nhb, nvw, nvb, XLN);
  k_inproj<<<dim3(98,8,2), dim3(256), 0, stream>>>(XLN, h_inw, v_inw, XI, Z);
  k_conv<<<dim3(98,BATCH,2), dim3(256), 0, stream>>>(XI, h_cw, h_cb, v_cw, v_cb, XS, XS2);
  k_dbl<<<dim3(196), dim3(256), 0, stream>>>(XS, h_xw, v_xw, h_dtw, v_dtw, h_dtb, v_dtb,
                                             DT2, Bf, Cf);
  k_scan1<<<dim3(NCHUNK,16,4), dim3(256), 0, stream>>>(DT2, XS2, Bf, h_Al, v_Al, Pbuf, Hbuf);
  k_scan2<<<dim3(64), dim3(256), 0, stream>>>(Pbuf, Hbuf);
  k_scan3<<<dim3(NCHUNK,16,4), dim3(256), 0, stream>>>(DT2, XS2, Bf, Cf, h_Al, v_Al, Hbuf, YS);
  k_outgemm<<<dim3(98,2,2), dim3(256), 0, stream>>>(YS, XS, Z, h_D, v_D, h_ow, v_ow, OD);
  k_combine<<<dim3(56,BATCH), dim3(256), 0, stream>>>(OD, FUSED, BSUM);
  k_gate<<<dim3(BATCH), dim3(128), 0, stream>>>(BSUM, fc1, fc2, GATE);
  k_final<<<dim3((BATCH*128*LLEN+255)/256), dim3(256), 0, stream>>>(FUSED, GATE, x, out);
}

// Round 12
// 257.656 us; speedup vs baseline: 2.0175x; 1.0841x over previous
//
#include <hip/hip_runtime.h>
#include <hip/hip_bf16.h>

typedef __hip_bfloat16 bf16;
__device__ __forceinline__ float b2f(bf16 v){ return __bfloat162float(v); }
__device__ __forceinline__ bf16 f2b(float v){ return __float2bfloat16(v); }

typedef __attribute__((ext_vector_type(8))) short frag_ab;   // 8 bf16 (4 VGPRs)
typedef __attribute__((ext_vector_type(4))) float frag_cd;   // 4 fp32 acc
typedef __attribute__((ext_vector_type(4))) short short4v;   // 8B

__device__ __forceinline__ frag_ab ld_frag_2xb64(const bf16* p){
  union { frag_ab f; short4v h[2]; } u;
  u.h[0] = *reinterpret_cast<const short4v*>(p);
  u.h[1] = *reinterpret_cast<const short4v*>(p+4);
  return u.f;
}

#define LLEN 3136
#define BATCH 2
#define NCHUNK 49
#define LC 64

// ---------------- dwconv 3x3 + gelu ----------------
__global__ void k_dwconv_gelu(const float* __restrict__ x, const float* __restrict__ dww,
                              const float* __restrict__ dwb, bf16* __restrict__ tmp){
  int bc = blockIdx.x;            // b*128 + c
  int c = bc & 127;
  const float* xp = x + (size_t)bc*LLEN;
  float w[9];
  #pragma unroll
  for (int i=0;i<9;i++) w[i] = dww[c*9+i];
  float bias = dwb[c];
  for (int p = threadIdx.x; p < LLEN; p += blockDim.x){
    int i = p/56, j = p%56;
    float acc = bias;
    #pragma unroll
    for (int a=0;a<3;a++){
      int ii = i + a - 1;
      if (ii < 0 || ii >= 56) continue;
      #pragma unroll
      for (int bb=0;bb<3;bb++){
        int jj = j + bb - 1;
        if (jj < 0 || jj >= 56) continue;
        acc += w[a*3+bb] * xp[ii*56+jj];
      }
    }
    float g = 0.5f*acc*(1.0f + erff(acc*0.70710678118654752f));
    tmp[(size_t)bc*LLEN + p] = f2b(g);
  }
}

// ---------------- pointwise conv GEMM (MFMA): C[m=outc][n=p] = pww[m][c] x tmp[c][p] ----------------
__global__ void k_pw_gemm(const bf16* __restrict__ tmp, const float* __restrict__ pww,
                          const float* __restrict__ pwb, float* __restrict__ fused){
  int b  = blockIdx.z;
  int p0 = blockIdx.x * 64;       // 49 p-tiles
  int m0 = blockIdx.y * 64;       // 2 out-channel halves
  const bf16* T = tmp + (size_t)b*128*LLEN;
  __shared__ __align__(16) bf16 sA[64][136];    // pww rows m0.., k=c (bf16)
  __shared__ __align__(16) bf16 sBt[64][132];   // [p][c] transposed tmp tile
  int tid = threadIdx.x;
  // stage A: 64 rows x 128 c, fp32->bf16
  #pragma unroll
  for (int r=0;r<8;r++){
    int idx = tid + r*256;
    int row = idx >> 5, c4 = (idx & 31)*4;
    float4 w4 = *reinterpret_cast<const float4*>(&pww[(size_t)(m0+row)*128 + c4]);
    bf16 t4[4] = {f2b(w4.x), f2b(w4.y), f2b(w4.z), f2b(w4.w)};
    *reinterpret_cast<double*>(&sA[row][c4]) = *reinterpret_cast<double*>(t4);
  }
  // stage Bt: tmp[c][p0+p] -> sBt[p][c]  (transposed scalar writes)
  #pragma unroll
  for (int r=0;r<8;r++){
    int idx = tid + r*256;
    int c = idx >> 4, p4 = (idx & 15)*4;
    union { double d; bf16 v[4]; } u;
    u.d = *reinterpret_cast<const double*>(&T[(size_t)c*LLEN + p0 + p4]);
    #pragma unroll
    for (int j=0;j<4;j++) sBt[p4+j][c] = u.v[j];
  }
  __syncthreads();
  int wv2 = tid >> 6, lane = tid & 63;
  int qd = lane >> 4, mr = lane & 15;
  frag_cd acc[4] = {};
  #pragma unroll
  for (int k0=0;k0<128;k0+=32){
    frag_ab af = *reinterpret_cast<frag_ab*>(&sA[wv2*16+mr][k0+qd*8]);
    #pragma unroll
    for (int t=0;t<4;t++){
      frag_ab bfr = ld_frag_2xb64(&sBt[t*16+mr][k0+qd*8]);
      acc[t] = __builtin_amdgcn_mfma_f32_16x16x32_bf16(af, bfr, acc[t], 0, 0, 0);
    }
  }
  #pragma unroll
  for (int t=0;t<4;t++)
    #pragma unroll
    for (int r=0;r<4;r++){
      int m = m0 + wv2*16 + qd*4 + r;        // out channel
      int p = p0 + t*16 + mr;                // spatial
      fused[((size_t)b*128 + m)*LLEN + p] = acc[t][r] + pwb[m];
    }
}

// ---------------- LayerNorm over C, write both direction orderings (bf16) ----------------
__global__ void k_ln(const float* __restrict__ x, const float* nhw_, const float* nhb_,
                     const float* nvw_, const float* nvb_, bf16* __restrict__ xln){
  __shared__ float sx[128][57];
  __shared__ float smean[56], srstd[56];
  __shared__ float wh[128], bh[128], wv_[128], bv_[128];
  int h = blockIdx.x; int b = blockIdx.y;
  int tid = threadIdx.x;
  if (tid < 128){ wh[tid]=nhw_[tid]; bh[tid]=nhb_[tid];
                  wv_[tid]=nvw_[tid]; bv_[tid]=nvb_[tid]; }
  for (int idx = tid; idx < 128*56; idx += 256){
    int c = idx / 56, w = idx % 56;
    sx[c][w] = x[((size_t)(b*128+c))*LLEN + h*56 + w];
  }
  __syncthreads();
  if (tid < 56){
    float s=0.f, s2=0.f;
    for (int c=0;c<128;c++){ float v = sx[c][tid]; s+=v; s2+=v*v; }
    float m = s*(1.f/128.f);
    float var = s2*(1.f/128.f) - m*m;
    smean[tid]=m; srstd[tid]=rsqrtf(var+1e-5f);
  }
  __syncthreads();
  bf16* outh = xln;
  bf16* outv = xln + (size_t)BATCH*LLEN*128;
  for (int idx = tid; idx < 56*128; idx += 256){
    int w = idx >> 7, c = idx & 127;
    float v = (sx[c][w]-smean[w])*srstd[w];
    outh[((size_t)b*LLEN + h*56 + w)*128 + c] = f2b(v*wh[c]+bh[c]);
    outv[((size_t)b*LLEN + w*56 + h)*128 + c] = f2b(v*wv_[c]+bv_[c]);
  }
}

// ---------------- in_proj GEMM (MFMA bf16): 64x64 tile, K=128 fully LDS-resident ----------------
__global__ void k_inproj(const bf16* __restrict__ xln, const float* __restrict__ hw,
                         const float* __restrict__ vw, bf16* __restrict__ XI, bf16* __restrict__ Z){
  int dir = blockIdx.z;
  const bf16* A = xln + (size_t)dir*BATCH*LLEN*128;
  const float* W = dir ? vw : hw;
  int m0 = blockIdx.x*64, n0 = blockIdx.y*64;
  __shared__ __align__(16) bf16 sA[64][136];
  __shared__ __align__(16) bf16 sW[64][136];
  int tid = threadIdx.x;
  #pragma unroll
  for (int r=0;r<4;r++){
    int idx = tid + r*256;
    int row = idx >> 4, c8 = (idx & 15)*8;
    *reinterpret_cast<float4*>(&sA[row][c8]) =
        *reinterpret_cast<const float4*>(&A[(size_t)(m0+row)*128 + c8]);
  }
  #pragma unroll
  for (int r=0;r<8;r++){
    int idx = tid + r*256;
    int row = idx >> 5, c4 = (idx & 31)*4;
    float4 w4 = *reinterpret_cast<const float4*>(&W[(size_t)(n0+row)*128 + c4]);
    bf16 t4[4] = {f2b(w4.x), f2b(w4.y), f2b(w4.z), f2b(w4.w)};
    *reinterpret_cast<double*>(&sW[row][c4]) = *reinterpret_cast<double*>(t4);
  }
  __syncthreads();
  int wv2 = tid >> 6, lane = tid & 63;
  int qd = lane >> 4, mr = lane & 15;
  frag_cd acc[4] = {};
  #pragma unroll
  for (int k0=0;k0<128;k0+=32){
    frag_ab af = *reinterpret_cast<frag_ab*>(&sA[wv2*16+mr][k0+qd*8]);
    #pragma unroll
    for (int t=0;t<4;t++){
      frag_ab bfr = *reinterpret_cast<frag_ab*>(&sW[t*16+mr][k0+qd*8]);
      acc[t] = __builtin_amdgcn_mfma_f32_16x16x32_bf16(af, bfr, acc[t], 0, 0, 0);
    }
  }
  bf16* dst = (n0 < 256) ? XI : Z;
  int nb = n0 & 255;
  size_t dslab = (size_t)dir*BATCH*LLEN*256;
  #pragma unroll
  for (int t=0;t<4;t++)
    #pragma unroll
    for (int r=0;r<4;r++){
      int row = m0 + wv2*16 + qd*4 + r;
      int col = nb + t*16 + mr;
      dst[dslab + (size_t)row*256 + col] = f2b(acc[t][r]);
    }
}

// ---------------- causal depthwise conv1d(k=4) + silu; writes XS2 (scan layout) only ----------------
__global__ void k_conv(const bf16* __restrict__ XI, const float* hw, const float* hb,
                       const float* vw, const float* vb, bf16* __restrict__ XS2){
  int dir = blockIdx.z;
  int b = blockIdx.y;
  int bd = dir*BATCH + b;
  int l0 = blockIdx.x * 32;
  const bf16* XId = XI + (size_t)bd*LLEN*256;
  const float* cw = dir ? vw : hw;
  const float* cb = dir ? vb : hb;
  __shared__ float sxi[35][256];
  int tid = threadIdx.x;
  for (int r = 0; r < 35; r++){
    int l = l0 - 3 + r;
    sxi[r][tid] = (l >= 0) ? b2f(XId[(size_t)l*256 + tid]) : 0.f;
  }
  __syncthreads();
  float w0=cw[tid*4], w1=cw[tid*4+1], w2=cw[tid*4+2], w3=cw[tid*4+3];
  float bias = cb[tid];
  size_t x2base = ((size_t)bd*16 + (tid>>4))*LLEN;
  int c16 = tid & 15;
  for (int ll=0; ll<32; ll++){
    float acc = bias + w0*sxi[ll][tid] + w1*sxi[ll+1][tid] + w2*sxi[ll+2][tid] + w3*sxi[ll+3][tid];
    float s = acc / (1.f + __expf(-acc));
    XS2[(x2base + l0 + ll)*16 + c16] = f2b(s);
  }
}

// ---------------- xproj fused (MFMA): DBL tile -> dt(softplus)->DT2, B/C extract ----------------
// M=12544 (64-row tiles), N=40 padded to 48, K=256; A from XS2 (scan layout)
__global__ void k_dbl(const bf16* __restrict__ XS2, const float* __restrict__ hx,
                      const float* __restrict__ vx,
                      const float* hdw, const float* vdw, const float* hdb, const float* vdb,
                      bf16* __restrict__ DT2, float* __restrict__ Bf, float* __restrict__ Cf){
  int m0 = blockIdx.x*64;                      // 196 tiles; never crosses bd boundary
  int bd = m0 / LLEN;
  int l0m = m0 % LLEN;
  int dirq = bd >> 1;
  const float* W = dirq ? vx : hx;
  __shared__ __align__(16) bf16 sA[64][264];   // 33.8 KB
  __shared__ __align__(16) bf16 sW[48][264];   // 25.3 KB (rows 40..47 zero)
  __shared__ float sdbl[64][49];               // 12.5 KB
  int tid = threadIdx.x;
  // stage A from XS2: 64 rows x 256 k, 16B chunks
  #pragma unroll
  for (int r=0;r<8;r++){
    int idx = tid + r*256;
    int row = idx >> 5, c8 = (idx & 31)*8;
    size_t src = (((size_t)bd*16 + (c8>>4))*LLEN + l0m + row)*16 + (c8&15);
    *reinterpret_cast<float4*>(&sA[row][c8]) =
        *reinterpret_cast<const float4*>(&XS2[src]);
  }
  // stage W (40x256 fp32 -> bf16; pad rows 40..47 with zeros)
  #pragma unroll
  for (int r=0;r<12;r++){
    int idx = tid + r*256;                     // 3072 = 48*64 chunks of 4
    int row = idx >> 6, c4 = (idx & 63)*4;
    bf16 t4[4] = {f2b(0.f), f2b(0.f), f2b(0.f), f2b(0.f)};
    if (row < 40){
      float4 w4 = *reinterpret_cast<const float4*>(&W[(size_t)row*256 + c4]);
      t4[0]=f2b(w4.x); t4[1]=f2b(w4.y); t4[2]=f2b(w4.z); t4[3]=f2b(w4.w);
    }
    *reinterpret_cast<double*>(&sW[row][c4]) = *reinterpret_cast<double*>(t4);
  }
  __syncthreads();
  int wv2 = tid >> 6, lane = tid & 63;
  int qd = lane >> 4, mr = lane & 15;
  frag_cd acc[3] = {};
  #pragma unroll
  for (int k0=0;k0<256;k0+=32){
    frag_ab af = *reinterpret_cast<frag_ab*>(&sA[wv2*16+mr][k0+qd*8]);
    #pragma unroll
    for (int t=0;t<3;t++){
      frag_ab bfr = *reinterpret_cast<frag_ab*>(&sW[t*16+mr][k0+qd*8]);
      acc[t] = __builtin_amdgcn_mfma_f32_16x16x32_bf16(af, bfr, acc[t], 0, 0, 0);
    }
  }
  #pragma unroll
  for (int t=0;t<3;t++)
    #pragma unroll
    for (int r=0;r<4;r++){
      int col = t*16 + mr;
      if (col < 40) sdbl[wv2*16 + qd*4 + r][col] = acc[t][r];
    }
  __syncthreads();
  // dt = softplus(dbl[:8] @ dtw^T + dtb) -> DT2 scan layout
  const float* dtw = dirq ? vdw : hdw;
  const float* dtb = dirq ? vdb : hdb;
  float w8[8];
  #pragma unroll
  for (int r=0;r<8;r++) w8[r] = dtw[tid*8+r];
  float biasv = dtb[tid];
  size_t d2base = ((size_t)bd*16 + (tid>>4))*LLEN + l0m;
  int c16 = tid & 15;
  for (int row=0; row<64; row++){
    float a = biasv;
    #pragma unroll
    for (int r=0;r<8;r++) a += sdbl[row][r]*w8[r];
    float sv = (a > 20.f) ? a : __logf(1.f + __expf(a));
    DT2[(d2base + row)*16 + c16] = f2b(sv);
  }
  #pragma unroll
  for (int r=0;r<8;r++){
    int idx = tid + r*256;                     // 2048 = 64 rows * 32 vals
    int row = idx >> 5, o = idx & 31;
    float v = sdbl[row][8+o];
    size_t rr = (size_t)(m0+row)*16;
    if (o < 16) Bf[rr + o] = v;
    else        Cf[rr + (o-16)] = v;
  }
}

// ---------------- chunked selective scan: pass 1 (local scan, P & h_end) ----------------
__global__ void k_scan1(const bf16* __restrict__ DT2, const bf16* __restrict__ XS2,
                        const float* __restrict__ Bc, const float* hA, const float* vA,
                        float* __restrict__ Pbuf, float* __restrict__ Hbuf){
  int bd = blockIdx.z;           // dir*2+b
  int g  = blockIdx.y;           // channel group 0..15
  int ck = blockIdx.x;           // chunk 0..48
  int l0 = ck*LC;
  const float* Bd = Bc + (size_t)bd*LLEN*16;
  const float* Alog = (bd >> 1) ? vA : hA;
  int tid = threadIdx.x;
  int dl = tid >> 4, n = tid & 15;
  int d = g*16 + dl;
  float A = -__expf(Alog[d*16+n]);
  __shared__ float sdt[LC][16], sxs[LC][16], sB[LC][16];
  size_t base2 = (((size_t)bd*16 + g)*LLEN + l0)*16;
  #pragma unroll
  for (int r=0;r<4;r++){
    int idx = tid + r*256;
    sdt[idx>>4][idx&15] = b2f(DT2[base2 + idx]);
    sxs[idx>>4][idx&15] = b2f(XS2[base2 + idx]);
    (&sB[0][0])[idx] = Bd[(size_t)l0*16 + idx];
  }
  __syncthreads();
  float h = 0.f, P = 1.f;
  #pragma unroll 8
  for (int i=0;i<LC;i++){
    float a = sdt[i][dl];
    float u = sxs[i][dl];
    float dA = __expf(a * A);
    h = dA*h + (a*u)*sB[i][n];
    P *= dA;
  }
  size_t sidx = (((size_t)bd*16 + g)*NCHUNK + ck)*256 + tid;
  Pbuf[sidx] = P;
  Hbuf[sidx] = h;
}

// ---------------- pass 2: sequential combine over chunks (in-place h_end -> h_init) ----------------
__global__ void k_scan2(const float* __restrict__ Pbuf, float* __restrict__ Hbuf){
  int q = blockIdx.x;            // bd*16+g, 0..63
  int tid = threadIdx.x;
  float carry = 0.f;
  for (int k=0;k<NCHUNK;k++){
    size_t idx = ((size_t)q*NCHUNK + k)*256 + tid;
    float Pv = Pbuf[idx];
    float He = Hbuf[idx];
    Hbuf[idx] = carry;           // h_init for chunk k
    carry = Pv*carry + He;
  }
}

// ---------------- pass 3: local scan from h_init, subchunked LDS reduce, emit y ----------------
__global__ void k_scan3(const bf16* __restrict__ DT2, const bf16* __restrict__ XS2,
                        const float* __restrict__ Bc, const float* __restrict__ Cc,
                        const float* hA, const float* vA,
                        const float* __restrict__ Hbuf, bf16* __restrict__ ys){
  int bd = blockIdx.z;
  int g  = blockIdx.y;
  int ck = blockIdx.x;
  int l0 = ck*LC;
  const float* Bd = Bc + (size_t)bd*LLEN*16;
  const float* Cd = Cc + (size_t)bd*LLEN*16;
  bf16* yd = ys + (size_t)bd*LLEN*256;
  const float* Alog = (bd >> 1) ? vA : hA;
  int tid = threadIdx.x;
  int dl = tid >> 4, n = tid & 15;
  float A = -__expf(Alog[(g*16+dl)*16+n]);
  __shared__ float sdt[LC][16], sxs[LC][16], sB[LC][16], sC[LC][16];
  __shared__ __align__(16) float sp2[16][276];   // 17.7 KB; subchunk partial products
  size_t base2 = (((size_t)bd*16 + g)*LLEN + l0)*16;
  #pragma unroll
  for (int r=0;r<4;r++){
    int idx = tid + r*256;
    sdt[idx>>4][idx&15] = b2f(DT2[base2 + idx]);
    sxs[idx>>4][idx&15] = b2f(XS2[base2 + idx]);
    (&sB[0][0])[idx] = Bd[(size_t)l0*16 + idx];
    (&sC[0][0])[idx] = Cd[(size_t)l0*16 + idx];
  }
  size_t sidx = (((size_t)bd*16 + g)*NCHUNK + ck)*256 + tid;
  float h = Hbuf[sidx];
  __syncthreads();
  int i_local = tid >> 4;        // reduce-phase: step within subchunk
  int c16 = tid & 15;            // reduce-phase: channel-in-group
  for (int i0=0; i0<LC; i0+=16){
    #pragma unroll
    for (int ii=0;ii<16;ii++){
      int i = i0 + ii;
      float a = sdt[i][dl];
      float u = sxs[i][dl];
      float dA = __expf(a * A);
      h = dA*h + (a*u)*sB[i][n];
      sp2[ii][tid] = h * sC[i][n];
    }
    __syncthreads();
    const float* row = &sp2[i_local][c16*16];
    float s = 0.f;
    #pragma unroll
    for (int k=0;k<4;k++){
      float4 v = *reinterpret_cast<const float4*>(row + k*4);
      s += v.x + v.y + v.z + v.w;
    }
    yd[(size_t)(l0+i0+i_local)*256 + g*16 + c16] = f2b(s);
    __syncthreads();
  }
}

// ---------------- out_proj GEMM (MFMA bf16) with fused YF = (ys+xs*D)*silu(z) at A-staging ----------------
__global__ void k_outgemm(const bf16* __restrict__ ys, const bf16* __restrict__ XS2,
                          const bf16* __restrict__ Z, const float* __restrict__ hD,
                          const float* __restrict__ vD, const float* __restrict__ how,
                          const float* __restrict__ vow, bf16* __restrict__ OD){
  int dir = blockIdx.z;
  size_t slab = (size_t)dir*BATCH*LLEN*256;
  const float* W = dir ? vow : how;
  const float* Dw = dir ? vD : hD;
  bf16* od = OD + (size_t)dir*BATCH*LLEN*128;
  int m0 = blockIdx.x*64, n0 = blockIdx.y*64;
  int bd = dir*2 + m0/LLEN;      // constant per block (3136 % 64 == 0)
  int lbase = m0 % LLEN;
  __shared__ __align__(16) bf16 sA[64][136];
  __shared__ __align__(16) bf16 sW[64][136];
  int tid = threadIdx.x;
  int wv2 = tid >> 6, lane = tid & 63;
  int qd = lane >> 4, mr = lane & 15;
  frag_cd acc[4] = {};
  for (int kc=0; kc<256; kc+=128){
    __syncthreads();
    // stage A = YF for k-cols kc..kc+127 (xs read from scan-layout XS2)
    #pragma unroll
    for (int r=0;r<4;r++){
      int idx = tid + r*256;
      int row = idx >> 4, c8 = (idx & 15)*8;
      int k = kc + c8;
      size_t e = slab + (size_t)(m0+row)*256 + k;
      size_t e2 = (((size_t)bd*16 + (k>>4))*LLEN + lbase + row)*16 + (k&15);
      bf16 yb[8], xb[8], zb[8], ob[8];
      *reinterpret_cast<float4*>(yb) = *reinterpret_cast<const float4*>(&ys[e]);
      *reinterpret_cast<float4*>(xb) = *reinterpret_cast<const float4*>(&XS2[e2]);
      *reinterpret_cast<float4*>(zb) = *reinterpret_cast<const float4*>(&Z[e]);
      #pragma unroll
      for (int j=0;j<8;j++){
        float Dv = Dw[k + j];
        float yv = b2f(yb[j]) + b2f(xb[j])*Dv;
        float zv = b2f(zb[j]);
        ob[j] = f2b(yv * (zv/(1.f+__expf(-zv))));
      }
      *reinterpret_cast<float4*>(&sA[row][c8]) = *reinterpret_cast<float4*>(ob);
    }
    // stage W rows n0..n0+63, k-cols kc..kc+127 (fp32 -> bf16)
    #pragma unroll
    for (int r=0;r<8;r++){
      int idx = tid + r*256;
      int row = idx >> 5, c4 = (idx & 31)*4;
      float4 w4 = *reinterpret_cast<const float4*>(&W[(size_t)(n0+row)*256 + kc + c4]);
      bf16 t4[4] = {f2b(w4.x), f2b(w4.y), f2b(w4.z), f2b(w4.w)};
      *reinterpret_cast<double*>(&sW[row][c4]) = *reinterpret_cast<double*>(t4);
    }
    __syncthreads();
    #pragma unroll
    for (int k0=0;k0<128;k0+=32){
      frag_ab af = *reinterpret_cast<frag_ab*>(&sA[wv2*16+mr][k0+qd*8]);
      #pragma unroll
      for (int t=0;t<4;t++){
        frag_ab bfr = *reinterpret_cast<frag_ab*>(&sW[t*16+mr][k0+qd*8]);
        acc[t] = __builtin_amdgcn_mfma_f32_16x16x32_bf16(af, bfr, acc[t], 0, 0, 0);
      }
    }
  }
  #pragma unroll
  for (int t=0;t<4;t++)
    #pragma unroll
    for (int r=0;r<4;r++){
      int row = m0 + wv2*16 + qd*4 + r;
      int col = n0 + t*16 + mr;
      od[(size_t)row*128 + col] = f2b(acc[t][r]);
    }
}

// ---------------- combine: fused += OH + OV^T; also emit per-(b,h,c) partial sums ----------------
__global__ void k_combine(const bf16* __restrict__ OD, float* __restrict__ fused,
                          float* __restrict__ BSUM){
  int h = blockIdx.x;            // 0..55
  int b = blockIdx.y;
  __shared__ float sfu[56][129];
  int tid = threadIdx.x;
  const bf16* od0 = OD + (size_t)b*LLEN*128;
  const bf16* od1 = OD + (size_t)(BATCH + b)*LLEN*128;
  #pragma unroll 4
  for (int it=0; it<28; it++){
    int idx = it*256 + tid;      // 0..7167
    int sp = idx >> 7, c = idx & 127;
    sfu[sp][c] = b2f(od0[(size_t)(h*56+sp)*128 + c]) + b2f(od1[(size_t)(sp*56+h)*128 + c]);
  }
  __syncthreads();
  int c = tid >> 1, half = tid & 1;
  float s = 0.f;
  size_t gbase = ((size_t)b*128 + c)*LLEN + h*56 + half*28;
  #pragma unroll
  for (int i=0;i<28;i++){
    float tot = fused[gbase+i] + sfu[half*28+i][c];
    fused[gbase+i] = tot;
    s += tot;
  }
  s += __shfl_xor(s, 1, 64);
  if (half == 0) BSUM[((size_t)b*56 + h)*128 + c] = s;
}

// ---------------- channel attention gate (reduces BSUM over h) ----------------
__global__ void k_gate(const float* __restrict__ BSUM, const float* fc1, const float* fc2,
                       float* __restrict__ gate){
  int b = blockIdx.x;
  __shared__ float ym[128], s1[32];
  int tid = threadIdx.x;         // 128 threads
  float s = 0.f;
  for (int h=0; h<56; h++) s += BSUM[((size_t)b*56 + h)*128 + tid];
  ym[tid] = s * (1.f/(float)LLEN);
  __syncthreads();
  if (tid < 32){
    float a = 0.f;
    for (int c=0;c<128;c++) a += ym[c]*fc1[tid*128+c];
    s1[tid] = fmaxf(a, 0.f);
  }
  __syncthreads();
  float a = 0.f;
  #pragma unroll
  for (int j=0;j<32;j++) a += s1[j]*fc2[tid*32+j];
  gate[b*128+tid] = 1.f/(1.f+__expf(-a));
}

// ---------------- final: out = fused * gate + x  (in-place over fused) ----------------
__global__ void k_final(float* __restrict__ fused, const float* __restrict__ gate,
                        const float* __restrict__ x, float* __restrict__ out){
  int i = blockIdx.x*256 + threadIdx.x;
  if (i >= BATCH*128*LLEN) return;
  int bc = i / LLEN;
  float v = fused[i]*gate[bc] + x[i];
  out[i] = v;
}

extern "C" void kernel_launch(void* const* d_in, const int* in_sizes, int n_in,
                              void* d_out, int out_size, void* d_ws, size_t ws_size,
                              hipStream_t stream) {
  const float* x      = (const float*)d_in[0];
  const float* nhw    = (const float*)d_in[1];
  const float* nhb    = (const float*)d_in[2];
  const float* nvw    = (const float*)d_in[3];
  const float* nvb    = (const float*)d_in[4];
  const float* dww    = (const float*)d_in[5];
  const float* dwb    = (const float*)d_in[6];
  const float* pww    = (const float*)d_in[7];
  const float* pwb    = (const float*)d_in[8];
  const float* h_inw  = (const float*)d_in[9];
  const float* h_cw   = (const float*)d_in[10];
  const float* h_cb   = (const float*)d_in[11];
  const float* h_xw   = (const float*)d_in[12];
  const float* h_dtw  = (const float*)d_in[13];
  const float* h_dtb  = (const float*)d_in[14];
  const float* h_Al   = (const float*)d_in[15];
  const float* h_D    = (const float*)d_in[16];
  const float* h_ow   = (const float*)d_in[17];
  const float* v_inw  = (const float*)d_in[18];
  const float* v_cw   = (const float*)d_in[19];
  const float* v_cb   = (const float*)d_in[20];
  const float* v_xw   = (const float*)d_in[21];
  const float* v_dtw  = (const float*)d_in[22];
  const float* v_dtb  = (const float*)d_in[23];
  const float* v_Al   = (const float*)d_in[24];
  const float* v_D    = (const float*)d_in[25];
  const float* v_ow   = (const float*)d_in[26];
  const float* fc1    = (const float*)d_in[27];
  const float* fc2    = (const float*)d_in[28];

  float* FUSED = (float*)d_out;   // FUSED lives in d_out; k_final is in-place elementwise
  float* out   = (float*)d_out;

  // Workspace layout (bytes), high-water ~30.6 MB. Stream-ordered-safe aliases:
  //  DT2 overlays TMP+XLN (both dead after k_inproj/k_pw); OD overlays DT2 (dead after k_scan3)
  //  YS overlays XI (dead after k_conv);  Pbuf overlays YS head (dead before k_scan3 writes)
  char* base = (char*)d_ws;
  bf16*  TMP   = (bf16*)(base + 0);           // 1,605,632 B
  bf16*  XLN   = (bf16*)(base + 1605632);     // 3,211,264 B
  bf16*  DT2   = (bf16*)(base + 0);           // 6,422,528 B  [alias TMP+XLN; scan layout]
  bf16*  OD    = (bf16*)(base + 0);           // 3,211,264 B  [alias DT2; live after k_scan3]
  bf16*  XI    = (bf16*)(base + 6422528);     // 6,422,528 B
  bf16*  YS    = (bf16*)(base + 6422528);     // 6,422,528 B  [alias XI]
  float* Pbuf  = (float*)(base + 6422528);    // 3,211,264 B  [alias XI/YS head]
  bf16*  Z     = (bf16*)(base + 12845056);    // 6,422,528 B
  bf16*  XS2   = (bf16*)(base + 19267584);    // 6,422,528 B  [scan layout; replaces XS]
  float* Bf    = (float*)(base + 25690112);   //   802,816 B
  float* Cf    = (float*)(base + 26492928);   //   802,816 B
  float* Hbuf  = (float*)(base + 27295744);   // 3,211,264 B
  float* BSUM  = (float*)(base + 30507008);   //    57,344 B
  float* GATE  = (float*)(base + 30564352);   //     1,024 B

  k_dwconv_gelu<<<dim3(BATCH*128), dim3(256), 0, stream>>>(x, dww, dwb, TMP);
  k_pw_gemm<<<dim3(49,2,BATCH), dim3(256), 0, stream>>>(TMP, pww, pwb, FUSED);
  k_ln<<<dim3(56,BATCH), dim3(256), 0, stream>>>(x, nhw, nhb, nvw, nvb, XLN);
  k_inproj<<<dim3(98,8,2), dim3(256), 0, stream>>>(XLN, h_inw, v_inw, XI, Z);
  k_conv<<<dim3(98,BATCH,2), dim3(256), 0, stream>>>(XI, h_cw, h_cb, v_cw, v_cb, XS2);
  k_dbl<<<dim3(196), dim3(256), 0, stream>>>(XS2, h_xw, v_xw, h_dtw, v_dtw, h_dtb, v_dtb,
                                             DT2, Bf, Cf);
  k_scan1<<<dim3(NCHUNK,16,4), dim3(256), 0, stream>>>(DT2, XS2, Bf, h_Al, v_Al, Pbuf, Hbuf);
  k_scan2<<<dim3(64), dim3(256), 0, stream>>>(Pbuf, Hbuf);
  k_scan3<<<dim3(NCHUNK,16,4), dim3(256), 0, stream>>>(DT2, XS2, Bf, Cf, h_Al, v_Al, Hbuf, YS);
  k_outgemm<<<dim3(98,2,2), dim3(256), 0, stream>>>(YS, XS2, Z, h_D, v_D, h_ow, v_ow, OD);
  k_combine<<<dim3(56,BATCH), dim3(256), 0, stream>>>(OD, FUSED, BSUM);
  k_gate<<<dim3(BATCH), dim3(128), 0, stream>>>(BSUM, fc1, fc2, GATE);
  k_final<<<dim3((BATCH*128*LLEN+255)/256), dim3(256), 0, stream>>>(FUSED, GATE, x, out);
}

// Round 13
// 257.285 us; speedup vs baseline: 2.0204x; 1.0014x over previous
//
#include <hip/hip_runtime.h>
#include <hip/hip_bf16.h>

typedef __hip_bfloat16 bf16;
__device__ __forceinline__ float b2f(bf16 v){ return __bfloat162float(v); }
__device__ __forceinline__ bf16 f2b(float v){ return __float2bfloat16(v); }

typedef __attribute__((ext_vector_type(8))) short frag_ab;   // 8 bf16 (4 VGPRs)
typedef __attribute__((ext_vector_type(4))) float frag_cd;   // 4 fp32 acc
typedef __attribute__((ext_vector_type(4))) short short4v;   // 8B

__device__ __forceinline__ frag_ab ld_frag_2xb64(const bf16* p){
  union { frag_ab f; short4v h[2]; } u;
  u.h[0] = *reinterpret_cast<const short4v*>(p);
  u.h[1] = *reinterpret_cast<const short4v*>(p+4);
  return u.f;
}

#define LLEN 3136
#define BATCH 2
#define NCHUNK 49
#define LC 64

// ---------------- dwconv 3x3 + gelu (4-way spatial split; also zeroes YMEAN) ----------------
__global__ void k_dwconv_gelu(const float* __restrict__ x, const float* __restrict__ dww,
                              const float* __restrict__ dwb, bf16* __restrict__ tmp,
                              float* __restrict__ YMEAN){
  int bc = blockIdx.x;            // b*128 + c
  int c = bc & 127;
  if (bc == 0 && blockIdx.y == 0 && threadIdx.x < 256) YMEAN[threadIdx.x] = 0.f;
  const float* xp = x + (size_t)bc*LLEN;
  float w[9];
  #pragma unroll
  for (int i=0;i<9;i++) w[i] = dww[c*9+i];
  float bias = dwb[c];
  int pstart = blockIdx.y * 784;
  int pend = pstart + 784;
  for (int p = pstart + threadIdx.x; p < pend; p += 256){
    int i = p/56, j = p%56;
    float acc = bias;
    #pragma unroll
    for (int a=0;a<3;a++){
      int ii = i + a - 1;
      if (ii < 0 || ii >= 56) continue;
      #pragma unroll
      for (int bb=0;bb<3;bb++){
        int jj = j + bb - 1;
        if (jj < 0 || jj >= 56) continue;
        acc += w[a*3+bb] * xp[ii*56+jj];
      }
    }
    float g = 0.5f*acc*(1.0f + erff(acc*0.70710678118654752f));
    tmp[(size_t)bc*LLEN + p] = f2b(g);
  }
}

// ---------------- pointwise conv GEMM (MFMA): C[m=outc][n=p] = pww[m][c] x tmp[c][p] ----------------
__global__ void k_pw_gemm(const bf16* __restrict__ tmp, const float* __restrict__ pww,
                          const float* __restrict__ pwb, float* __restrict__ fused){
  int b  = blockIdx.z;
  int p0 = blockIdx.x * 64;       // 49 p-tiles
  int m0 = blockIdx.y * 64;       // 2 out-channel halves
  const bf16* T = tmp + (size_t)b*128*LLEN;
  __shared__ __align__(16) bf16 sA[64][136];    // pww rows m0.., k=c (bf16)
  __shared__ __align__(16) bf16 sBt[64][132];   // [p][c] transposed tmp tile
  int tid = threadIdx.x;
  #pragma unroll
  for (int r=0;r<8;r++){
    int idx = tid + r*256;
    int row = idx >> 5, c4 = (idx & 31)*4;
    float4 w4 = *reinterpret_cast<const float4*>(&pww[(size_t)(m0+row)*128 + c4]);
    bf16 t4[4] = {f2b(w4.x), f2b(w4.y), f2b(w4.z), f2b(w4.w)};
    *reinterpret_cast<double*>(&sA[row][c4]) = *reinterpret_cast<double*>(t4);
  }
  #pragma unroll
  for (int r=0;r<8;r++){
    int idx = tid + r*256;
    int c = idx >> 4, p4 = (idx & 15)*4;
    union { double d; bf16 v[4]; } u;
    u.d = *reinterpret_cast<const double*>(&T[(size_t)c*LLEN + p0 + p4]);
    #pragma unroll
    for (int j=0;j<4;j++) sBt[p4+j][c] = u.v[j];
  }
  __syncthreads();
  int wv2 = tid >> 6, lane = tid & 63;
  int qd = lane >> 4, mr = lane & 15;
  frag_cd acc[4] = {};
  #pragma unroll
  for (int k0=0;k0<128;k0+=32){
    frag_ab af = *reinterpret_cast<frag_ab*>(&sA[wv2*16+mr][k0+qd*8]);
    #pragma unroll
    for (int t=0;t<4;t++){
      frag_ab bfr = ld_frag_2xb64(&sBt[t*16+mr][k0+qd*8]);
      acc[t] = __builtin_amdgcn_mfma_f32_16x16x32_bf16(af, bfr, acc[t], 0, 0, 0);
    }
  }
  #pragma unroll
  for (int t=0;t<4;t++)
    #pragma unroll
    for (int r=0;r<4;r++){
      int m = m0 + wv2*16 + qd*4 + r;        // out channel
      int p = p0 + t*16 + mr;                // spatial
      fused[((size_t)b*128 + m)*LLEN + p] = acc[t][r] + pwb[m];
    }
}

// ---------------- LayerNorm over C, write both direction orderings (bf16) ----------------
__global__ void k_ln(const float* __restrict__ x, const float* nhw_, const float* nhb_,
                     const float* nvw_, const float* nvb_, bf16* __restrict__ xln){
  __shared__ float sx[128][57];
  __shared__ float smean[56], srstd[56];
  __shared__ float wh[128], bh[128], wv_[128], bv_[128];
  int h = blockIdx.x; int b = blockIdx.y;
  int tid = threadIdx.x;
  if (tid < 128){ wh[tid]=nhw_[tid]; bh[tid]=nhb_[tid];
                  wv_[tid]=nvw_[tid]; bv_[tid]=nvb_[tid]; }
  for (int idx = tid; idx < 128*56; idx += 256){
    int c = idx / 56, w = idx % 56;
    sx[c][w] = x[((size_t)(b*128+c))*LLEN + h*56 + w];
  }
  __syncthreads();
  if (tid < 56){
    float s=0.f, s2=0.f;
    for (int c=0;c<128;c++){ float v = sx[c][tid]; s+=v; s2+=v*v; }
    float m = s*(1.f/128.f);
    float var = s2*(1.f/128.f) - m*m;
    smean[tid]=m; srstd[tid]=rsqrtf(var+1e-5f);
  }
  __syncthreads();
  bf16* outh = xln;
  bf16* outv = xln + (size_t)BATCH*LLEN*128;
  for (int idx = tid; idx < 56*128; idx += 256){
    int w = idx >> 7, c = idx & 127;
    float v = (sx[c][w]-smean[w])*srstd[w];
    outh[((size_t)b*LLEN + h*56 + w)*128 + c] = f2b(v*wh[c]+bh[c]);
    outv[((size_t)b*LLEN + w*56 + h)*128 + c] = f2b(v*wv_[c]+bv_[c]);
  }
}

// ---------------- in_proj GEMM (MFMA bf16): 64x64 tile, K=128 fully LDS-resident ----------------
__global__ void k_inproj(const bf16* __restrict__ xln, const float* __restrict__ hw,
                         const float* __restrict__ vw, bf16* __restrict__ XI, bf16* __restrict__ Z){
  int dir = blockIdx.z;
  const bf16* A = xln + (size_t)dir*BATCH*LLEN*128;
  const float* W = dir ? vw : hw;
  int m0 = blockIdx.x*64, n0 = blockIdx.y*64;
  __shared__ __align__(16) bf16 sA[64][136];
  __shared__ __align__(16) bf16 sW[64][136];
  int tid = threadIdx.x;
  #pragma unroll
  for (int r=0;r<4;r++){
    int idx = tid + r*256;
    int row = idx >> 4, c8 = (idx & 15)*8;
    *reinterpret_cast<float4*>(&sA[row][c8]) =
        *reinterpret_cast<const float4*>(&A[(size_t)(m0+row)*128 + c8]);
  }
  #pragma unroll
  for (int r=0;r<8;r++){
    int idx = tid + r*256;
    int row = idx >> 5, c4 = (idx & 31)*4;
    float4 w4 = *reinterpret_cast<const float4*>(&W[(size_t)(n0+row)*128 + c4]);
    bf16 t4[4] = {f2b(w4.x), f2b(w4.y), f2b(w4.z), f2b(w4.w)};
    *reinterpret_cast<double*>(&sW[row][c4]) = *reinterpret_cast<double*>(t4);
  }
  __syncthreads();
  int wv2 = tid >> 6, lane = tid & 63;
  int qd = lane >> 4, mr = lane & 15;
  frag_cd acc[4] = {};
  #pragma unroll
  for (int k0=0;k0<128;k0+=32){
    frag_ab af = *reinterpret_cast<frag_ab*>(&sA[wv2*16+mr][k0+qd*8]);
    #pragma unroll
    for (int t=0;t<4;t++){
      frag_ab bfr = *reinterpret_cast<frag_ab*>(&sW[t*16+mr][k0+qd*8]);
      acc[t] = __builtin_amdgcn_mfma_f32_16x16x32_bf16(af, bfr, acc[t], 0, 0, 0);
    }
  }
  bf16* dst = (n0 < 256) ? XI : Z;
  int nb = n0 & 255;
  size_t dslab = (size_t)dir*BATCH*LLEN*256;
  #pragma unroll
  for (int t=0;t<4;t++)
    #pragma unroll
    for (int r=0;r<4;r++){
      int row = m0 + wv2*16 + qd*4 + r;
      int col = nb + t*16 + mr;
      dst[dslab + (size_t)row*256 + col] = f2b(acc[t][r]);
    }
}

// ---------------- causal depthwise conv1d(k=4) + silu; writes XS2 (scan layout) only ----------------
__global__ void k_conv(const bf16* __restrict__ XI, const float* hw, const float* hb,
                       const float* vw, const float* vb, bf16* __restrict__ XS2){
  int dir = blockIdx.z;
  int b = blockIdx.y;
  int bd = dir*BATCH + b;
  int l0 = blockIdx.x * 32;
  const bf16* XId = XI + (size_t)bd*LLEN*256;
  const float* cw = dir ? vw : hw;
  const float* cb = dir ? vb : hb;
  __shared__ float sxi[35][256];
  int tid = threadIdx.x;
  for (int r = 0; r < 35; r++){
    int l = l0 - 3 + r;
    sxi[r][tid] = (l >= 0) ? b2f(XId[(size_t)l*256 + tid]) : 0.f;
  }
  __syncthreads();
  float w0=cw[tid*4], w1=cw[tid*4+1], w2=cw[tid*4+2], w3=cw[tid*4+3];
  float bias = cb[tid];
  size_t x2base = ((size_t)bd*16 + (tid>>4))*LLEN;
  int c16 = tid & 15;
  for (int ll=0; ll<32; ll++){
    float acc = bias + w0*sxi[ll][tid] + w1*sxi[ll+1][tid] + w2*sxi[ll+2][tid] + w3*sxi[ll+3][tid];
    float s = acc / (1.f + __expf(-acc));
    XS2[(x2base + l0 + ll)*16 + c16] = f2b(s);
  }
}

// ---------------- xproj fused (MFMA): DBL -> dt->DT2, B/C extract, + FUSED SCAN PASS 1 ----------------
// Tile = 64 rows of one bd = exactly one scan chunk with all 256 channels resident.
__global__ void k_dbl(const bf16* __restrict__ XS2, const float* __restrict__ hx,
                      const float* __restrict__ vx,
                      const float* hdw, const float* vdw, const float* hdb, const float* vdb,
                      const float* hA, const float* vA,
                      bf16* __restrict__ DT2, float* __restrict__ Bf, float* __restrict__ Cf,
                      float* __restrict__ Pbuf, float* __restrict__ Hbuf){
  int m0 = blockIdx.x*64;                      // 196 tiles; never crosses bd boundary
  int bd = m0 / LLEN;
  int l0m = m0 % LLEN;
  int ck = l0m / LC;
  int dirq = bd >> 1;
  const float* W = dirq ? vx : hx;
  __shared__ __align__(16) bf16 sA[64][264];   // 33.8 KB (xs, stays live for scan)
  __shared__ __align__(16) bf16 sW[48][264];   // 25.3 KB (rows 40..47 zero)
  __shared__ float sdbl[64][49];               // 12.5 KB (B at [row][8+n], stays live)
  int tid = threadIdx.x;
  // stage A from XS2: 64 rows x 256 k, 16B chunks
  #pragma unroll
  for (int r=0;r<8;r++){
    int idx = tid + r*256;
    int row = idx >> 5, c8 = (idx & 31)*8;
    size_t src = (((size_t)bd*16 + (c8>>4))*LLEN + l0m + row)*16 + (c8&15);
    *reinterpret_cast<float4*>(&sA[row][c8]) =
        *reinterpret_cast<const float4*>(&XS2[src]);
  }
  // stage W (40x256 fp32 -> bf16; pad rows 40..47 with zeros)
  #pragma unroll
  for (int r=0;r<12;r++){
    int idx = tid + r*256;                     // 3072 = 48*64 chunks of 4
    int row = idx >> 6, c4 = (idx & 63)*4;
    bf16 t4[4] = {f2b(0.f), f2b(0.f), f2b(0.f), f2b(0.f)};
    if (row < 40){
      float4 w4 = *reinterpret_cast<const float4*>(&W[(size_t)row*256 + c4]);
      t4[0]=f2b(w4.x); t4[1]=f2b(w4.y); t4[2]=f2b(w4.z); t4[3]=f2b(w4.w);
    }
    *reinterpret_cast<double*>(&sW[row][c4]) = *reinterpret_cast<double*>(t4);
  }
  __syncthreads();
  int wv2 = tid >> 6, lane = tid & 63;
  int qd = lane >> 4, mr = lane & 15;
  frag_cd acc[3] = {};
  #pragma unroll
  for (int k0=0;k0<256;k0+=32){
    frag_ab af = *reinterpret_cast<frag_ab*>(&sA[wv2*16+mr][k0+qd*8]);
    #pragma unroll
    for (int t=0;t<3;t++){
      frag_ab bfr = *reinterpret_cast<frag_ab*>(&sW[t*16+mr][k0+qd*8]);
      acc[t] = __builtin_amdgcn_mfma_f32_16x16x32_bf16(af, bfr, acc[t], 0, 0, 0);
    }
  }
  #pragma unroll
  for (int t=0;t<3;t++)
    #pragma unroll
    for (int r=0;r<4;r++){
      int col = t*16 + mr;
      if (col < 40) sdbl[wv2*16 + qd*4 + r][col] = acc[t][r];
    }
  __syncthreads();
  // dt = softplus(dbl[:8] @ dtw^T + dtb) -> DT2; fused local scan (states (d=tid, n))
  const float* dtw = dirq ? vdw : hdw;
  const float* dtb = dirq ? vdb : hdb;
  const float* Alog = dirq ? vA : hA;
  float w8[8];
  #pragma unroll
  for (int r=0;r<8;r++) w8[r] = dtw[tid*8+r];
  float biasv = dtb[tid];
  float Aq[16];
  #pragma unroll
  for (int n=0;n<16;n++) Aq[n] = -__expf(Alog[tid*16+n]);
  float hst[16] = {};
  float Pst[16];
  #pragma unroll
  for (int n=0;n<16;n++) Pst[n] = 1.f;
  size_t d2base = ((size_t)bd*16 + (tid>>4))*LLEN + l0m;
  int c16 = tid & 15;
  for (int row=0; row<64; row++){
    float a = biasv;
    #pragma unroll
    for (int r=0;r<8;r++) a += sdbl[row][r]*w8[r];
    float sv = (a > 20.f) ? a : __logf(1.f + __expf(a));
    bf16 svb16 = f2b(sv);
    DT2[(d2base + row)*16 + c16] = svb16;
    float svb = b2f(svb16);                    // match scan3's bf16-rounded dt
    float u = b2f(sA[row][tid]);
    float au = svb*u;
    #pragma unroll
    for (int n=0;n<16;n++){
      float dA = __expf(svb * Aq[n]);
      hst[n] = dA*hst[n] + au*sdbl[row][8+n];
      Pst[n] *= dA;
    }
  }
  size_t pbase = (((size_t)bd*16 + (tid>>4))*NCHUNK + ck)*256 + (size_t)(tid&15)*16;
  #pragma unroll
  for (int n=0;n<16;n++){ Pbuf[pbase+n] = Pst[n]; Hbuf[pbase+n] = hst[n]; }
  // B, C extraction (row-major [global row][16])
  #pragma unroll
  for (int r=0;r<8;r++){
    int idx = tid + r*256;                     // 2048 = 64 rows * 32 vals
    int row = idx >> 5, o = idx & 31;
    float v = sdbl[row][8+o];
    size_t rr = (size_t)(m0+row)*16;
    if (o < 16) Bf[rr + o] = v;
    else        Cf[rr + (o-16)] = v;
  }
}

// ---------------- pass 2: sequential combine over chunks (in-place h_end -> h_init) ----------------
__global__ void k_scan2(const float* __restrict__ Pbuf, float* __restrict__ Hbuf){
  int q = blockIdx.x;            // bd*16+g, 0..63
  int tid = threadIdx.x;
  float carry = 0.f;
  for (int k=0;k<NCHUNK;k++){
    size_t idx = ((size_t)q*NCHUNK + k)*256 + tid;
    float Pv = Pbuf[idx];
    float He = Hbuf[idx];
    Hbuf[idx] = carry;           // h_init for chunk k
    carry = Pv*carry + He;
  }
}

// ---------------- pass 3: local scan from h_init, subchunked LDS reduce, emit y ----------------
__global__ void k_scan3(const bf16* __restrict__ DT2, const bf16* __restrict__ XS2,
                        const float* __restrict__ Bc, const float* __restrict__ Cc,
                        const float* hA, const float* vA,
                        const float* __restrict__ Hbuf, bf16* __restrict__ ys){
  int bd = blockIdx.z;
  int g  = blockIdx.y;
  int ck = blockIdx.x;
  int l0 = ck*LC;
  const float* Bd = Bc + (size_t)bd*LLEN*16;
  const float* Cd = Cc + (size_t)bd*LLEN*16;
  bf16* yd = ys + (size_t)bd*LLEN*256;
  const float* Alog = (bd >> 1) ? vA : hA;
  int tid = threadIdx.x;
  int dl = tid >> 4, n = tid & 15;
  float A = -__expf(Alog[(g*16+dl)*16+n]);
  __shared__ float sdt[LC][16], sxs[LC][16], sB[LC][16], sC[LC][16];
  __shared__ __align__(16) float sp2[16][276];   // 17.7 KB; subchunk partial products
  size_t base2 = (((size_t)bd*16 + g)*LLEN + l0)*16;
  #pragma unroll
  for (int r=0;r<4;r++){
    int idx = tid + r*256;
    sdt[idx>>4][idx&15] = b2f(DT2[base2 + idx]);
    sxs[idx>>4][idx&15] = b2f(XS2[base2 + idx]);
    (&sB[0][0])[idx] = Bd[(size_t)l0*16 + idx];
    (&sC[0][0])[idx] = Cd[(size_t)l0*16 + idx];
  }
  size_t sidx = (((size_t)bd*16 + g)*NCHUNK + ck)*256 + tid;
  float h = Hbuf[sidx];
  __syncthreads();
  int i_local = tid >> 4;        // reduce-phase: step within subchunk
  int c16 = tid & 15;            // reduce-phase: channel-in-group
  for (int i0=0; i0<LC; i0+=16){
    #pragma unroll
    for (int ii=0;ii<16;ii++){
      int i = i0 + ii;
      float a = sdt[i][dl];
      float u = sxs[i][dl];
      float dA = __expf(a * A);
      h = dA*h + (a*u)*sB[i][n];
      sp2[ii][tid] = h * sC[i][n];
    }
    __syncthreads();
    const float* row = &sp2[i_local][c16*16];
    float s = 0.f;
    #pragma unroll
    for (int k=0;k<4;k++){
      float4 v = *reinterpret_cast<const float4*>(row + k*4);
      s += v.x + v.y + v.z + v.w;
    }
    yd[(size_t)(l0+i0+i_local)*256 + g*16 + c16] = f2b(s);
    __syncthreads();
  }
}

// ---------------- out_proj GEMM (MFMA bf16) with fused YF = (ys+xs*D)*silu(z) at A-staging ----------------
__global__ void k_outgemm(const bf16* __restrict__ ys, const bf16* __restrict__ XS2,
                          const bf16* __restrict__ Z, const float* __restrict__ hD,
                          const float* __restrict__ vD, const float* __restrict__ how,
                          const float* __restrict__ vow, bf16* __restrict__ OD){
  int dir = blockIdx.z;
  size_t slab = (size_t)dir*BATCH*LLEN*256;
  const float* W = dir ? vow : how;
  const float* Dw = dir ? vD : hD;
  bf16* od = OD + (size_t)dir*BATCH*LLEN*128;
  int m0 = blockIdx.x*64, n0 = blockIdx.y*64;
  int bd = dir*2 + m0/LLEN;      // constant per block (3136 % 64 == 0)
  int lbase = m0 % LLEN;
  __shared__ __align__(16) bf16 sA[64][136];
  __shared__ __align__(16) bf16 sW[64][136];
  int tid = threadIdx.x;
  int wv2 = tid >> 6, lane = tid & 63;
  int qd = lane >> 4, mr = lane & 15;
  frag_cd acc[4] = {};
  for (int kc=0; kc<256; kc+=128){
    __syncthreads();
    #pragma unroll
    for (int r=0;r<4;r++){
      int idx = tid + r*256;
      int row = idx >> 4, c8 = (idx & 15)*8;
      int k = kc + c8;
      size_t e = slab + (size_t)(m0+row)*256 + k;
      size_t e2 = (((size_t)bd*16 + (k>>4))*LLEN + lbase + row)*16 + (k&15);
      bf16 yb[8], xb[8], zb[8], ob[8];
      *reinterpret_cast<float4*>(yb) = *reinterpret_cast<const float4*>(&ys[e]);
      *reinterpret_cast<float4*>(xb) = *reinterpret_cast<const float4*>(&XS2[e2]);
      *reinterpret_cast<float4*>(zb) = *reinterpret_cast<const float4*>(&Z[e]);
      #pragma unroll
      for (int j=0;j<8;j++){
        float Dv = Dw[k + j];
        float yv = b2f(yb[j]) + b2f(xb[j])*Dv;
        float zv = b2f(zb[j]);
        ob[j] = f2b(yv * (zv/(1.f+__expf(-zv))));
      }
      *reinterpret_cast<float4*>(&sA[row][c8]) = *reinterpret_cast<float4*>(ob);
    }
    #pragma unroll
    for (int r=0;r<8;r++){
      int idx = tid + r*256;
      int row = idx >> 5, c4 = (idx & 31)*4;
      float4 w4 = *reinterpret_cast<const float4*>(&W[(size_t)(n0+row)*256 + kc + c4]);
      bf16 t4[4] = {f2b(w4.x), f2b(w4.y), f2b(w4.z), f2b(w4.w)};
      *reinterpret_cast<double*>(&sW[row][c4]) = *reinterpret_cast<double*>(t4);
    }
    __syncthreads();
    #pragma unroll
    for (int k0=0;k0<128;k0+=32){
      frag_ab af = *reinterpret_cast<frag_ab*>(&sA[wv2*16+mr][k0+qd*8]);
      #pragma unroll
      for (int t=0;t<4;t++){
        frag_ab bfr = *reinterpret_cast<frag_ab*>(&sW[t*16+mr][k0+qd*8]);
        acc[t] = __builtin_amdgcn_mfma_f32_16x16x32_bf16(af, bfr, acc[t], 0, 0, 0);
      }
    }
  }
  #pragma unroll
  for (int t=0;t<4;t++)
    #pragma unroll
    for (int r=0;r<4;r++){
      int row = m0 + wv2*16 + qd*4 + r;
      int col = n0 + t*16 + mr;
      od[(size_t)row*128 + col] = f2b(acc[t][r]);
    }
}

// ---------------- combine: fused += OH + OV^T; atomically accumulate YMEAN ----------------
__global__ void k_combine(const bf16* __restrict__ OD, float* __restrict__ fused,
                          float* __restrict__ YMEAN){
  int h = blockIdx.x;            // 0..55
  int b = blockIdx.y;
  __shared__ float sfu[56][129];
  int tid = threadIdx.x;
  const bf16* od0 = OD + (size_t)b*LLEN*128;
  const bf16* od1 = OD + (size_t)(BATCH + b)*LLEN*128;
  #pragma unroll 4
  for (int it=0; it<28; it++){
    int idx = it*256 + tid;      // 0..7167
    int sp = idx >> 7, c = idx & 127;
    sfu[sp][c] = b2f(od0[(size_t)(h*56+sp)*128 + c]) + b2f(od1[(size_t)(sp*56+h)*128 + c]);
  }
  __syncthreads();
  int c = tid >> 1, half = tid & 1;
  float s = 0.f;
  size_t gbase = ((size_t)b*128 + c)*LLEN + h*56 + half*28;
  #pragma unroll
  for (int i=0;i<28;i++){
    float tot = fused[gbase+i] + sfu[half*28+i][c];
    fused[gbase+i] = tot;
    s += tot;
  }
  s += __shfl_xor(s, 1, 64);
  if (half == 0) atomicAdd(&YMEAN[b*128 + c], s);
}

// ---------------- channel attention gate ----------------
__global__ void k_gate(const float* __restrict__ YMEAN, const float* fc1, const float* fc2,
                       float* __restrict__ gate){
  int b = blockIdx.x;
  __shared__ float ym[128], s1[32];
  int tid = threadIdx.x;         // 128 threads
  ym[tid] = YMEAN[b*128 + tid] * (1.f/(float)LLEN);
  __syncthreads();
  if (tid < 32){
    float a = 0.f;
    for (int c=0;c<128;c++) a += ym[c]*fc1[tid*128+c];
    s1[tid] = fmaxf(a, 0.f);
  }
  __syncthreads();
  float a = 0.f;
  #pragma unroll
  for (int j=0;j<32;j++) a += s1[j]*fc2[tid*32+j];
  gate[b*128+tid] = 1.f/(1.f+__expf(-a));
}

// ---------------- final: out = fused * gate + x  (in-place over fused) ----------------
__global__ void k_final(float* __restrict__ fused, const float* __restrict__ gate,
                        const float* __restrict__ x, float* __restrict__ out){
  int i = blockIdx.x*256 + threadIdx.x;
  if (i >= BATCH*128*LLEN) return;
  int bc = i / LLEN;
  float v = fused[i]*gate[bc] + x[i];
  out[i] = v;
}

extern "C" void kernel_launch(void* const* d_in, const int* in_sizes, int n_in,
                              void* d_out, int out_size, void* d_ws, size_t ws_size,
                              hipStream_t stream) {
  const float* x      = (const float*)d_in[0];
  const float* nhw    = (const float*)d_in[1];
  const float* nhb    = (const float*)d_in[2];
  const float* nvw    = (const float*)d_in[3];
  const float* nvb    = (const float*)d_in[4];
  const float* dww    = (const float*)d_in[5];
  const float* dwb    = (const float*)d_in[6];
  const float* pww    = (const float*)d_in[7];
  const float* pwb    = (const float*)d_in[8];
  const float* h_inw  = (const float*)d_in[9];
  const float* h_cw   = (const float*)d_in[10];
  const float* h_cb   = (const float*)d_in[11];
  const float* h_xw   = (const float*)d_in[12];
  const float* h_dtw  = (const float*)d_in[13];
  const float* h_dtb  = (const float*)d_in[14];
  const float* h_Al   = (const float*)d_in[15];
  const float* h_D    = (const float*)d_in[16];
  const float* h_ow   = (const float*)d_in[17];
  const float* v_inw  = (const float*)d_in[18];
  const float* v_cw   = (const float*)d_in[19];
  const float* v_cb   = (const float*)d_in[20];
  const float* v_xw   = (const float*)d_in[21];
  const float* v_dtw  = (const float*)d_in[22];
  const float* v_dtb  = (const float*)d_in[23];
  const float* v_Al   = (const float*)d_in[24];
  const float* v_D    = (const float*)d_in[25];
  const float* v_ow   = (const float*)d_in[26];
  const float* fc1    = (const float*)d_in[27];
  const float* fc2    = (const float*)d_in[28];

  float* FUSED = (float*)d_out;   // FUSED lives in d_out; k_final is in-place elementwise
  float* out   = (float*)d_out;

  // Workspace layout (bytes), high-water ~30.6 MB. Stream-ordered-safe aliases:
  //  DT2 overlays TMP+XLN (both dead after k_inproj/k_pw); OD overlays DT2 (dead after k_scan3)
  //  YS overlays XI (dead after k_conv);  Pbuf overlays YS head (dead before k_scan3 writes)
  char* base = (char*)d_ws;
  bf16*  TMP   = (bf16*)(base + 0);           // 1,605,632 B
  bf16*  XLN   = (bf16*)(base + 1605632);     // 3,211,264 B
  bf16*  DT2   = (bf16*)(base + 0);           // 6,422,528 B  [alias TMP+XLN; scan layout]
  bf16*  OD    = (bf16*)(base + 0);           // 3,211,264 B  [alias DT2; live after k_scan3]
  bf16*  XI    = (bf16*)(base + 6422528);     // 6,422,528 B
  bf16*  YS    = (bf16*)(base + 6422528);     // 6,422,528 B  [alias XI]
  float* Pbuf  = (float*)(base + 6422528);    // 3,211,264 B  [alias XI/YS head]
  bf16*  Z     = (bf16*)(base + 12845056);    // 6,422,528 B
  bf16*  XS2   = (bf16*)(base + 19267584);    // 6,422,528 B  [scan layout]
  float* Bf    = (float*)(base + 25690112);   //   802,816 B
  float* Cf    = (float*)(base + 26492928);   //   802,816 B
  float* Hbuf  = (float*)(base + 27295744);   // 3,211,264 B
  float* YMEAN = (float*)(base + 30507008);   //     1,024 B
  float* GATE  = (float*)(base + 30564352);   //     1,024 B

  k_dwconv_gelu<<<dim3(BATCH*128,4), dim3(256), 0, stream>>>(x, dww, dwb, TMP, YMEAN);
  k_pw_gemm<<<dim3(49,2,BATCH), dim3(256), 0, stream>>>(TMP, pww, pwb, FUSED);
  k_ln<<<dim3(56,BATCH), dim3(256), 0, stream>>>(x, nhw, nhb, nvw, nvb, XLN);
  k_inproj<<<dim3(98,8,2), dim3(256), 0, stream>>>(XLN, h_inw, v_inw, XI, Z);
  k_conv<<<dim3(98,BATCH,2), dim3(256), 0, stream>>>(XI, h_cw, h_cb, v_cw, v_cb, XS2);
  k_dbl<<<dim3(196), dim3(256), 0, stream>>>(XS2, h_xw, v_xw, h_dtw, v_dtw, h_dtb, v_dtb,
                                             h_Al, v_Al, DT2, Bf, Cf, Pbuf, Hbuf);
  k_scan2<<<dim3(64), dim3(256), 0, stream>>>(Pbuf, Hbuf);
  k_scan3<<<dim3(NCHUNK,16,4), dim3(256), 0, stream>>>(DT2, XS2, Bf, Cf, h_Al, v_Al, Hbuf, YS);
  k_outgemm<<<dim3(98,2,2), dim3(256), 0, stream>>>(YS, XS2, Z, h_D, v_D, h_ow, v_ow, OD);
  k_combine<<<dim3(56,BATCH), dim3(256), 0, stream>>>(OD, FUSED, YMEAN);
  k_gate<<<dim3(BATCH), dim3(128), 0, stream>>>(YMEAN, fc1, fc2, GATE);
  k_final<<<dim3((BATCH*128*LLEN+255)/256), dim3(256), 0, stream>>>(FUSED, GATE, x, out);
}